// Round 1
// baseline (1195.779 us; speedup 1.0000x reference)
//
#include <hip/hip_runtime.h>
#include <math.h>

// Problem constants
// n=2, C=288, h=w=64 -> hw=4096; kv stride 2 -> h_kv=w_kv=32 -> pkv=1024
// M=9 heads, d=32
#define NB     2
#define CDIM   288
#define HW     4096
#define HDIM   64
#define WDIM   64
#define PKV    1024
#define HKV    32
#define WKV    32
#define MHEAD  9
#define DHEAD  32

// ---------------------------------------------------------------------------
// Generic W(288xC) @ X(nxCxHW-with-gather) GEMM: OUT[n][o][j] = sum_c W[o][c]*X[n][c][pos(j)]
// mode 0: J=4096, pos=j (Q). mode 1: J=1024, pos=128*(j>>5)+2*(j&31) (K/V via x_kv gather)
__global__ void gemm_wx(const float* __restrict__ W, const float* __restrict__ X,
                        float* __restrict__ OUT, int J, int mode) {
    int n  = blockIdx.z;
    int o0 = blockIdx.y * 16;
    int j0 = blockIdx.x * 16;
    int tx = threadIdx.x, ty = threadIdx.y;
    __shared__ float Wt[16][17];
    __shared__ float Xt[16][17];
    int j   = j0 + tx;
    int pos = (mode == 0) ? j : (128 * (j >> 5) + 2 * (j & 31));
    const float* Xn = X + (size_t)n * CDIM * HW;
    float acc = 0.f;
    for (int c0 = 0; c0 < CDIM; c0 += 16) {
        Wt[ty][tx] = W[(o0 + ty) * CDIM + c0 + tx];
        Xt[ty][tx] = Xn[(size_t)(c0 + ty) * HW + pos];
        __syncthreads();
#pragma unroll
        for (int kk = 0; kk < 16; ++kk) acc += Wt[ty][kk] * Xt[kk][tx];
        __syncthreads();
    }
    OUT[((size_t)n * CDIM + o0 + ty) * J + j] = acc;
}

// ---------------------------------------------------------------------------
// Positional factors: PF[m][a][b][dd] = inv_sqrt2 * sum_f emb[a][b][f] * W[m*32+dd][f]
// emb[f<72] = sin((a-2b)/1000^(f/72)), emb[72+f] = cos(...)
__global__ void pf_kernel(const float* __restrict__ Wx, const float* __restrict__ Wy,
                          float* __restrict__ PFX, float* __restrict__ PFY) {
    int b    = blockIdx.x;          // 2*64*32 blocks
    int axis = b >> 11;             // 0 -> x (uses w,v), 1 -> y (uses h,u)
    int a    = (b >> 5) & 63;
    int bb   = b & 31;
    __shared__ float emb[144];
    int tid = threadIdx.x;          // 256
    float diff = (float)(a - 2 * bb);   // POS_MAG = 1
    if (tid < 72) {
        float dm = expf(6.9077552789821368f * ((float)tid * (1.f / 72.f))); // 1000^(f/72)
        float t  = diff / dm;
        emb[tid]      = sinf(t);
        emb[72 + tid] = cosf(t);
    }
    __syncthreads();
    const float* W  = axis ? Wy : Wx;
    float*       PF = axis ? PFY : PFX;
    const float inv_sqrt2 = 0.70710678118654752f;
    for (int o = tid; o < CDIM; o += 256) {
        const float* wr = W + (size_t)o * 144;
        float s = 0.f;
#pragma unroll 8
        for (int f = 0; f < 144; ++f) s += emb[f] * wr[f];
        int m = o >> 5, dd = o & 31;
        PF[(((size_t)(m * 64 + a) * 32 + bb) * 32) + dd] = s * inv_sqrt2;
    }
}

// ---------------------------------------------------------------------------
// context[n][o] = mean_hw Q[n][o][hw]
__global__ void ctx_kernel(const float* __restrict__ Q, float* __restrict__ CTX) {
    int bid = blockIdx.x;                    // n*288+o, 576 blocks
    const float* q = Q + (size_t)bid * HW;
    int tid = threadIdx.x;                   // 256
    float s = 0.f;
    for (int j = tid; j < HW; j += 256) s += q[j];
    for (int off = 32; off > 0; off >>= 1) s += __shfl_xor(s, off, 64);
    __shared__ float red[4];
    if ((tid & 63) == 0) red[tid >> 6] = s;
    __syncthreads();
    if (tid == 0) CTX[bid] = (red[0] + red[1] + red[2] + red[3]) * (1.f / 4096.f);
}

// mix_w[n][m] = softmax_m( ctx[n] . Wc[m] + bc[m] )
__global__ void mixw_kernel(const float* __restrict__ CTX, const float* __restrict__ Wc,
                            const float* __restrict__ bc, float* __restrict__ MIXW) {
    __shared__ float lg[18];
    int tid = threadIdx.x;   // 64
    if (tid < 18) {
        int n = tid / 9, j = tid % 9;
        float s = bc[j];
        for (int o = 0; o < CDIM; ++o) s += CTX[n * CDIM + o] * Wc[j * CDIM + o];
        lg[tid] = s;
    }
    __syncthreads();
    if (tid < 2) {
        float mx = -1e30f;
        for (int j = 0; j < 9; ++j) mx = fmaxf(mx, lg[tid * 9 + j]);
        float e[9], sm = 0.f;
        for (int j = 0; j < 9; ++j) { e[j] = __expf(lg[tid * 9 + j] - mx); sm += e[j]; }
        for (int j = 0; j < 9; ++j) MIXW[tid * 9 + j] = e[j] / sm;
    }
}

// ---------------------------------------------------------------------------
// Fused attention: one block per query position. Computes the mix-weighted
// attention row (over 9 heads, 1024 kv) without materializing per-head energy.
__global__ __launch_bounds__(256) void attn_kernel(
        const float* __restrict__ Q, const float* __restrict__ K,
        const float* __restrict__ PFX, const float* __restrict__ PFY,
        const float* __restrict__ MIXW, float* __restrict__ ATTN) {
    int nb = blockIdx.x;           // 8192
    int n  = nb >> 12;
    int i  = nb & 4095;
    int hq = i >> 6, wq = i & 63;
    int tid = threadIdx.x;         // 256

    __shared__ float qm[32];
    __shared__ float ex[32];
    __shared__ float ey[32];
    __shared__ float acc[1024];
    __shared__ float red[8];

    for (int p = tid; p < 1024; p += 256) acc[p] = 0.f;

    const float* Qn = Q + (size_t)n * CDIM * HW;
    const float* Kn = K + (size_t)n * CDIM * PKV;

    for (int m = 0; m < MHEAD; ++m) {
        __syncthreads();
        if (tid < 32) qm[tid] = Qn[(size_t)(m * 32 + tid) * HW + i];
        __syncthreads();
        if (tid < 32) {
            const float* pf = PFX + (((size_t)(m * 64 + wq) * 32 + tid) * 32);
            float s = 0.f;
#pragma unroll
            for (int dd = 0; dd < 32; ++dd) s += qm[dd] * pf[dd];
            ex[tid] = s;
        } else if (tid < 64) {
            int u = tid - 32;
            const float* pf = PFY + (((size_t)(m * 64 + hq) * 32 + u) * 32);
            float s = 0.f;
#pragma unroll
            for (int dd = 0; dd < 32; ++dd) s += qm[dd] * pf[dd];
            ey[u] = s;
        }
        __syncthreads();
        float e[4];
        float mx = -1e30f;
#pragma unroll
        for (int r = 0; r < 4; ++r) {
            int p = tid + r * 256;
            const float* Kp = Kn + (size_t)(m * 32) * PKV + p;
            float s = 0.f;
#pragma unroll
            for (int dd = 0; dd < 32; ++dd) s += qm[dd] * Kp[(size_t)dd * PKV];
            s += ex[p & 31] + ey[p >> 5];
            e[r] = s;
            mx = fmaxf(mx, s);
        }
        for (int off = 32; off > 0; off >>= 1) mx = fmaxf(mx, __shfl_xor(mx, off, 64));
        int wid = tid >> 6;
        if ((tid & 63) == 0) red[wid] = mx;
        __syncthreads();
        float bm = fmaxf(fmaxf(red[0], red[1]), fmaxf(red[2], red[3]));
        float sum = 0.f;
#pragma unroll
        for (int r = 0; r < 4; ++r) { e[r] = __expf(e[r] - bm); sum += e[r]; }
        for (int off = 32; off > 0; off >>= 1) sum += __shfl_xor(sum, off, 64);
        if ((tid & 63) == 0) red[4 + wid] = sum;
        __syncthreads();
        float bs = red[4] + red[5] + red[6] + red[7];
        float wm = MIXW[n * 9 + m] / bs;
#pragma unroll
        for (int r = 0; r < 4; ++r) acc[tid + r * 256] += e[r] * wm;
    }
    __syncthreads();
    float* outp = ATTN + ((size_t)n * HW + i) * PKV;
    for (int p = tid; p < 1024; p += 256) outp[p] = acc[p];
}

// ---------------------------------------------------------------------------
// MID[n][o][i] = sum_p V[n][o][p] * ATTN[n][i][p]
__global__ void gemm_av(const float* __restrict__ V, const float* __restrict__ A,
                        float* __restrict__ OUT) {
    int n  = blockIdx.z;
    int o0 = blockIdx.y * 16;
    int i0 = blockIdx.x * 16;
    int tx = threadIdx.x, ty = threadIdx.y;
    __shared__ float Vt[16][17];
    __shared__ float At[16][17];
    const float* Vn = V + (size_t)n * CDIM * PKV;
    const float* An = A + (size_t)n * HW * PKV;
    float acc = 0.f;
    for (int p0 = 0; p0 < PKV; p0 += 16) {
        Vt[ty][tx] = Vn[(size_t)(o0 + ty) * PKV + p0 + tx];
        At[ty][tx] = An[(size_t)(i0 + ty) * PKV + p0 + tx];
        __syncthreads();
#pragma unroll
        for (int kk = 0; kk < 16; ++kk) acc += Vt[ty][kk] * At[tx][kk];
        __syncthreads();
    }
    OUT[((size_t)n * CDIM + o0 + ty) * HW + i0 + tx] = acc;
}

// ---------------------------------------------------------------------------
// Final: OUT[n][o][i] = gamma * ( sum_c Wproj[o][c]*MID[n][c][i] + bproj[o] ) + x[n][o][i]
__global__ void gemm_proj(const float* __restrict__ W, const float* __restrict__ MID,
                          const float* __restrict__ bproj, const float* __restrict__ x,
                          const float* __restrict__ gamma, float* __restrict__ OUT) {
    int n  = blockIdx.z;
    int o0 = blockIdx.y * 16;
    int j0 = blockIdx.x * 16;
    int tx = threadIdx.x, ty = threadIdx.y;
    __shared__ float Wt[16][17];
    __shared__ float Xt[16][17];
    const float* Mn = MID + (size_t)n * CDIM * HW;
    float acc = 0.f;
    for (int c0 = 0; c0 < CDIM; c0 += 16) {
        Wt[ty][tx] = W[(o0 + ty) * CDIM + c0 + tx];
        Xt[ty][tx] = Mn[(size_t)(c0 + ty) * HW + j0 + tx];
        __syncthreads();
#pragma unroll
        for (int kk = 0; kk < 16; ++kk) acc += Wt[ty][kk] * Xt[kk][tx];
        __syncthreads();
    }
    size_t idx = ((size_t)n * CDIM + o0 + ty) * HW + j0 + tx;
    float r = acc + bproj[o0 + ty];
    OUT[idx] = gamma[0] * r + x[idx];
}

// ---------------------------------------------------------------------------
extern "C" void kernel_launch(void* const* d_in, const int* in_sizes, int n_in,
                              void* d_out, int out_size, void* d_ws, size_t ws_size,
                              hipStream_t stream) {
    const float* x     = (const float*)d_in[0];
    const float* Wq    = (const float*)d_in[1];
    const float* Wk    = (const float*)d_in[2];
    const float* Wv    = (const float*)d_in[3];
    const float* Wx    = (const float*)d_in[4];
    const float* Wy    = (const float*)d_in[5];
    const float* Wproj = (const float*)d_in[6];
    const float* bproj = (const float*)d_in[7];
    const float* Wc    = (const float*)d_in[8];
    const float* bc    = (const float*)d_in[9];
    const float* gamma = (const float*)d_in[10];
    float* out = (float*)d_out;

    float* ws = (float*)d_ws;
    size_t off = 0;
    float* Q    = ws + off; off += (size_t)NB * CDIM * HW;    // 2,359,296
    float* K    = ws + off; off += (size_t)NB * CDIM * PKV;   //   589,824
    float* V    = ws + off; off += (size_t)NB * CDIM * PKV;   //   589,824
    float* PFX  = ws + off; off += (size_t)MHEAD * 64 * 32 * 32; // 589,824
    float* PFY  = ws + off; off += (size_t)MHEAD * 64 * 32 * 32; // 589,824
    float* CTX  = ws + off; off += NB * CDIM;                 //       576
    float* MIXW = ws + off; off += 32;                        //        32
    float* ATTN = ws + off; off += (size_t)NB * HW * PKV;     // 8,388,608
    float* MID  = ws + off; off += (size_t)NB * CDIM * HW;    // 2,359,296

    dim3 blk16(16, 16);

    // Q = Wq @ x
    gemm_wx<<<dim3(HW / 16, CDIM / 16, NB), blk16, 0, stream>>>(Wq, x, Q, HW, 0);
    // K = Wk @ x_kv ; V = Wv @ x_kv
    gemm_wx<<<dim3(PKV / 16, CDIM / 16, NB), blk16, 0, stream>>>(Wk, x, K, PKV, 1);
    gemm_wx<<<dim3(PKV / 16, CDIM / 16, NB), blk16, 0, stream>>>(Wv, x, V, PKV, 1);
    // positional factors
    pf_kernel<<<2 * 64 * 32, 256, 0, stream>>>(Wx, Wy, PFX, PFY);
    // context + mix weights
    ctx_kernel<<<NB * CDIM, 256, 0, stream>>>(Q, CTX);
    mixw_kernel<<<1, 64, 0, stream>>>(CTX, Wc, bc, MIXW);
    // fused attention -> mixed attn rows
    attn_kernel<<<NB * HW, 256, 0, stream>>>(Q, K, PFX, PFY, MIXW, ATTN);
    // MID = V @ ATTN^T
    gemm_av<<<dim3(HW / 16, CDIM / 16, NB), blk16, 0, stream>>>(V, ATTN, MID);
    // OUT = gamma*(Wproj@MID + bproj) + x
    gemm_proj<<<dim3(HW / 16, CDIM / 16, NB), blk16, 0, stream>>>(Wproj, MID, bproj, x, gamma, out);
}

// Round 2
// 636.853 us; speedup vs baseline: 1.8776x; 1.8776x over previous
//
#include <hip/hip_runtime.h>
#include <math.h>

// n=2, C=288, h=w=64 -> hw=4096; kv stride 2 -> 32x32 -> pkv=1024; M=9 heads, d=32
#define NB     2
#define CDIM   288
#define HW     4096
#define PKV    1024
#define MHEAD  9
#define DHEAD  32

// ---------------------------------------------------------------------------
// Blocked GEMM 32x128 tile, 4x4 per thread, TK=16.
// gemm_q: OUT[n][o][j] = sum_c W[o][c] * X[n][c][j]   (M=288,N=4096,K=288)
__global__ __launch_bounds__(256) void gemm_q(const float* __restrict__ W,
        const float* __restrict__ X, float* __restrict__ OUT) {
    int n  = blockIdx.z;
    int o0 = blockIdx.y * 32;
    int j0 = blockIdx.x * 128;
    int tid = threadIdx.x;
    int a = tid >> 5, b = tid & 31;
    __shared__ float Wt[16][36];
    __shared__ float Xt[16][128];
    const float* Xn = X + (size_t)n * CDIM * HW;
    float acc[4][4] = {};
    int wr = tid >> 3, wc = tid & 7;
    int xk = tid >> 4, xc = (tid & 15) * 8;
    for (int c0 = 0; c0 < CDIM; c0 += 16) {
        float2 wv = *(const float2*)&W[(o0 + wr) * CDIM + c0 + 2 * wc];
        Wt[2 * wc][wr] = wv.x; Wt[2 * wc + 1][wr] = wv.y;
        const float* xs = &Xn[(size_t)(c0 + xk) * HW + j0 + xc];
        *(float4*)&Xt[xk][xc]     = *(const float4*)&xs[0];
        *(float4*)&Xt[xk][xc + 4] = *(const float4*)&xs[4];
        __syncthreads();
#pragma unroll
        for (int kk = 0; kk < 16; ++kk) {
            float4 w4 = *(const float4*)&Wt[kk][4 * a];
            float4 x4 = *(const float4*)&Xt[kk][4 * b];
            acc[0][0] += w4.x * x4.x; acc[0][1] += w4.x * x4.y; acc[0][2] += w4.x * x4.z; acc[0][3] += w4.x * x4.w;
            acc[1][0] += w4.y * x4.x; acc[1][1] += w4.y * x4.y; acc[1][2] += w4.y * x4.z; acc[1][3] += w4.y * x4.w;
            acc[2][0] += w4.z * x4.x; acc[2][1] += w4.z * x4.y; acc[2][2] += w4.z * x4.z; acc[2][3] += w4.z * x4.w;
            acc[3][0] += w4.w * x4.x; acc[3][1] += w4.w * x4.y; acc[3][2] += w4.w * x4.z; acc[3][3] += w4.w * x4.w;
        }
        __syncthreads();
    }
#pragma unroll
    for (int i = 0; i < 4; ++i) {
        float4 st = { acc[i][0], acc[i][1], acc[i][2], acc[i][3] };
        *(float4*)&OUT[((size_t)(n * CDIM) + o0 + 4 * a + i) * HW + j0 + 4 * b] = st;
    }
}

// K and V fused: B = x_kv gather (pos = 128*(j>>5)+2*(j&31)), N=1024, K=288
__global__ __launch_bounds__(256) void gemm_kv(const float* __restrict__ Wk,
        const float* __restrict__ Wv, const float* __restrict__ X,
        float* __restrict__ Kout, float* __restrict__ Vout) {
    int n  = blockIdx.z;
    int o0 = blockIdx.y * 32;
    int j0 = blockIdx.x * 128;
    int tid = threadIdx.x;
    int a = tid >> 5, b = tid & 31;
    __shared__ float Wt[2][16][36];
    __shared__ float Xt[16][128];
    const float* Xn = X + (size_t)n * CDIM * HW;
    float acck[4][4] = {};
    float accv[4][4] = {};
    int wr = tid >> 3, wc = tid & 7;
    int xk = tid >> 4, xc = (tid & 15) * 8;
    for (int c0 = 0; c0 < CDIM; c0 += 16) {
        float2 kw = *(const float2*)&Wk[(o0 + wr) * CDIM + c0 + 2 * wc];
        float2 vw = *(const float2*)&Wv[(o0 + wr) * CDIM + c0 + 2 * wc];
        Wt[0][2 * wc][wr] = kw.x; Wt[0][2 * wc + 1][wr] = kw.y;
        Wt[1][2 * wc][wr] = vw.x; Wt[1][2 * wc + 1][wr] = vw.y;
        const float* xrow = &Xn[(size_t)(c0 + xk) * HW];
#pragma unroll
        for (int l = 0; l < 8; ++l) {
            int j = j0 + xc + l;
            int pos = ((j >> 5) << 7) + ((j & 31) << 1);
            Xt[xk][xc + l] = xrow[pos];
        }
        __syncthreads();
#pragma unroll
        for (int kk = 0; kk < 16; ++kk) {
            float4 k4 = *(const float4*)&Wt[0][kk][4 * a];
            float4 v4 = *(const float4*)&Wt[1][kk][4 * a];
            float4 x4 = *(const float4*)&Xt[kk][4 * b];
            acck[0][0] += k4.x * x4.x; acck[0][1] += k4.x * x4.y; acck[0][2] += k4.x * x4.z; acck[0][3] += k4.x * x4.w;
            acck[1][0] += k4.y * x4.x; acck[1][1] += k4.y * x4.y; acck[1][2] += k4.y * x4.z; acck[1][3] += k4.y * x4.w;
            acck[2][0] += k4.z * x4.x; acck[2][1] += k4.z * x4.y; acck[2][2] += k4.z * x4.z; acck[2][3] += k4.z * x4.w;
            acck[3][0] += k4.w * x4.x; acck[3][1] += k4.w * x4.y; acck[3][2] += k4.w * x4.z; acck[3][3] += k4.w * x4.w;
            accv[0][0] += v4.x * x4.x; accv[0][1] += v4.x * x4.y; accv[0][2] += v4.x * x4.z; accv[0][3] += v4.x * x4.w;
            accv[1][0] += v4.y * x4.x; accv[1][1] += v4.y * x4.y; accv[1][2] += v4.y * x4.z; accv[1][3] += v4.y * x4.w;
            accv[2][0] += v4.z * x4.x; accv[2][1] += v4.z * x4.y; accv[2][2] += v4.z * x4.z; accv[2][3] += v4.z * x4.w;
            accv[3][0] += v4.w * x4.x; accv[3][1] += v4.w * x4.y; accv[3][2] += v4.w * x4.z; accv[3][3] += v4.w * x4.w;
        }
        __syncthreads();
    }
#pragma unroll
    for (int i = 0; i < 4; ++i) {
        size_t row = ((size_t)(n * CDIM) + o0 + 4 * a + i) * PKV + j0 + 4 * b;
        float4 sk = { acck[i][0], acck[i][1], acck[i][2], acck[i][3] };
        float4 sv = { accv[i][0], accv[i][1], accv[i][2], accv[i][3] };
        *(float4*)&Kout[row] = sk;
        *(float4*)&Vout[row] = sv;
    }
}

// MID[n][o][i] = sum_p V[n][o][p] * ATTN[n][i][p]   (M=288,N=4096,K=1024)
__global__ __launch_bounds__(256) void gemm_av(const float* __restrict__ V,
        const float* __restrict__ A, float* __restrict__ OUT) {
    int n  = blockIdx.z;
    int o0 = blockIdx.y * 32;
    int i0 = blockIdx.x * 128;
    int tid = threadIdx.x;
    int a = tid >> 5, b = tid & 31;
    __shared__ float Wt[16][36];
    __shared__ float Xt[16][132];
    const float* Vn = V + (size_t)n * CDIM * PKV;
    const float* An = A + (size_t)n * HW * PKV;
    float acc[4][4] = {};
    int wr = tid >> 3, wc = tid & 7;
    int nn = tid >> 1, pc = (tid & 1) * 8;
    for (int p0 = 0; p0 < PKV; p0 += 16) {
        float2 wv = *(const float2*)&Vn[(size_t)(o0 + wr) * PKV + p0 + 2 * wc];
        Wt[2 * wc][wr] = wv.x; Wt[2 * wc + 1][wr] = wv.y;
        const float* as = &An[(size_t)(i0 + nn) * PKV + p0 + pc];
        float4 a0 = *(const float4*)&as[0];
        float4 a1 = *(const float4*)&as[4];
        Xt[pc + 0][nn] = a0.x; Xt[pc + 1][nn] = a0.y; Xt[pc + 2][nn] = a0.z; Xt[pc + 3][nn] = a0.w;
        Xt[pc + 4][nn] = a1.x; Xt[pc + 5][nn] = a1.y; Xt[pc + 6][nn] = a1.z; Xt[pc + 7][nn] = a1.w;
        __syncthreads();
#pragma unroll
        for (int kk = 0; kk < 16; ++kk) {
            float4 w4 = *(const float4*)&Wt[kk][4 * a];
            float4 x4 = *(const float4*)&Xt[kk][4 * b];
            acc[0][0] += w4.x * x4.x; acc[0][1] += w4.x * x4.y; acc[0][2] += w4.x * x4.z; acc[0][3] += w4.x * x4.w;
            acc[1][0] += w4.y * x4.x; acc[1][1] += w4.y * x4.y; acc[1][2] += w4.y * x4.z; acc[1][3] += w4.y * x4.w;
            acc[2][0] += w4.z * x4.x; acc[2][1] += w4.z * x4.y; acc[2][2] += w4.z * x4.z; acc[2][3] += w4.z * x4.w;
            acc[3][0] += w4.w * x4.x; acc[3][1] += w4.w * x4.y; acc[3][2] += w4.w * x4.z; acc[3][3] += w4.w * x4.w;
        }
        __syncthreads();
    }
#pragma unroll
    for (int i = 0; i < 4; ++i) {
        float4 st = { acc[i][0], acc[i][1], acc[i][2], acc[i][3] };
        *(float4*)&OUT[((size_t)(n * CDIM) + o0 + 4 * a + i) * HW + i0 + 4 * b] = st;
    }
}

// OUT[n][o][j] = gamma*(sum_c Wproj[o][c]*MID[n][c][j] + bproj[o]) + x[n][o][j]
__global__ __launch_bounds__(256) void gemm_proj(const float* __restrict__ W,
        const float* __restrict__ MID, const float* __restrict__ bproj,
        const float* __restrict__ x, const float* __restrict__ gamma,
        float* __restrict__ OUT) {
    int n  = blockIdx.z;
    int o0 = blockIdx.y * 32;
    int j0 = blockIdx.x * 128;
    int tid = threadIdx.x;
    int a = tid >> 5, b = tid & 31;
    __shared__ float Wt[16][36];
    __shared__ float Xt[16][128];
    const float* Mn = MID + (size_t)n * CDIM * HW;
    float acc[4][4] = {};
    int wr = tid >> 3, wc = tid & 7;
    int xk = tid >> 4, xc = (tid & 15) * 8;
    for (int c0 = 0; c0 < CDIM; c0 += 16) {
        float2 wv = *(const float2*)&W[(o0 + wr) * CDIM + c0 + 2 * wc];
        Wt[2 * wc][wr] = wv.x; Wt[2 * wc + 1][wr] = wv.y;
        const float* xs = &Mn[(size_t)(c0 + xk) * HW + j0 + xc];
        *(float4*)&Xt[xk][xc]     = *(const float4*)&xs[0];
        *(float4*)&Xt[xk][xc + 4] = *(const float4*)&xs[4];
        __syncthreads();
#pragma unroll
        for (int kk = 0; kk < 16; ++kk) {
            float4 w4 = *(const float4*)&Wt[kk][4 * a];
            float4 x4 = *(const float4*)&Xt[kk][4 * b];
            acc[0][0] += w4.x * x4.x; acc[0][1] += w4.x * x4.y; acc[0][2] += w4.x * x4.z; acc[0][3] += w4.x * x4.w;
            acc[1][0] += w4.y * x4.x; acc[1][1] += w4.y * x4.y; acc[1][2] += w4.y * x4.z; acc[1][3] += w4.y * x4.w;
            acc[2][0] += w4.z * x4.x; acc[2][1] += w4.z * x4.y; acc[2][2] += w4.z * x4.z; acc[2][3] += w4.z * x4.w;
            acc[3][0] += w4.w * x4.x; acc[3][1] += w4.w * x4.y; acc[3][2] += w4.w * x4.z; acc[3][3] += w4.w * x4.w;
        }
        __syncthreads();
    }
    float g = gamma[0];
#pragma unroll
    for (int i = 0; i < 4; ++i) {
        size_t idx = ((size_t)(n * CDIM) + o0 + 4 * a + i) * HW + j0 + 4 * b;
        float bb = bproj[o0 + 4 * a + i];
        float4 xv = *(const float4*)&x[idx];
        float4 st;
        st.x = g * (acc[i][0] + bb) + xv.x;
        st.y = g * (acc[i][1] + bb) + xv.y;
        st.z = g * (acc[i][2] + bb) + xv.z;
        st.w = g * (acc[i][3] + bb) + xv.w;
        *(float4*)&OUT[idx] = st;
    }
}

// ---------------------------------------------------------------------------
// Positional factors: PF[m][a][b][dd] = inv_sqrt2 * sum_f emb[a][b][f] * W[m*32+dd][f]
__global__ void pf_kernel(const float* __restrict__ Wx, const float* __restrict__ Wy,
                          float* __restrict__ PFX, float* __restrict__ PFY) {
    int b    = blockIdx.x;          // 2*64*32 blocks
    int axis = b >> 11;
    int a    = (b >> 5) & 63;
    int bb   = b & 31;
    __shared__ float emb[144];
    int tid = threadIdx.x;          // 256
    float diff = (float)(a - 2 * bb);
    if (tid < 72) {
        float dm = expf(6.9077552789821368f * ((float)tid * (1.f / 72.f)));
        float t  = diff / dm;
        emb[tid]      = sinf(t);
        emb[72 + tid] = cosf(t);
    }
    __syncthreads();
    const float* W  = axis ? Wy : Wx;
    float*       PF = axis ? PFY : PFX;
    const float inv_sqrt2 = 0.70710678118654752f;
    for (int o = tid; o < CDIM; o += 256) {
        const float* wr = W + (size_t)o * 144;
        float s = 0.f;
#pragma unroll 8
        for (int f = 0; f < 144; ++f) s += emb[f] * wr[f];
        int m = o >> 5, dd = o & 31;
        PF[(((size_t)(m * 64 + a) * 32 + bb) * 32) + dd] = s * inv_sqrt2;
    }
}

// context[n][o] = mean_hw Q[n][o][hw]
__global__ void ctx_kernel(const float* __restrict__ Q, float* __restrict__ CTX) {
    int bid = blockIdx.x;
    const float* q = Q + (size_t)bid * HW;
    int tid = threadIdx.x;
    float s = 0.f;
    for (int j = tid; j < HW; j += 256) s += q[j];
    for (int off = 32; off > 0; off >>= 1) s += __shfl_xor(s, off, 64);
    __shared__ float red[4];
    if ((tid & 63) == 0) red[tid >> 6] = s;
    __syncthreads();
    if (tid == 0) CTX[bid] = (red[0] + red[1] + red[2] + red[3]) * (1.f / 4096.f);
}

__global__ void mixw_kernel(const float* __restrict__ CTX, const float* __restrict__ Wc,
                            const float* __restrict__ bc, float* __restrict__ MIXW) {
    __shared__ float lg[18];
    int tid = threadIdx.x;
    if (tid < 18) {
        int n = tid / 9, j = tid % 9;
        float s = bc[j];
        for (int o = 0; o < CDIM; ++o) s += CTX[n * CDIM + o] * Wc[j * CDIM + o];
        lg[tid] = s;
    }
    __syncthreads();
    if (tid < 2) {
        float mx = -1e30f;
        for (int j = 0; j < 9; ++j) mx = fmaxf(mx, lg[tid * 9 + j]);
        float e[9], sm = 0.f;
        for (int j = 0; j < 9; ++j) { e[j] = __expf(lg[tid * 9 + j] - mx); sm += e[j]; }
        for (int j = 0; j < 9; ++j) MIXW[tid * 9 + j] = e[j] / sm;
    }
}

// ---------------------------------------------------------------------------
// Fused attention v2: 16 queries per block, K staged in LDS, 4q x 16p register
// tile per thread, wave-level softmax (each wave owns whole kv rows).
__global__ __launch_bounds__(256, 2) void attn_v2(
        const float* __restrict__ Q, const float* __restrict__ K,
        const float* __restrict__ PFX, const float* __restrict__ PFY,
        const float* __restrict__ MIXW, float* __restrict__ ATTN) {
    int n   = blockIdx.x >> 8;
    int i0  = (blockIdx.x & 255) * 16;
    int hq  = i0 >> 6;          // same for all 16 queries (16 | 64)
    int wq0 = i0 & 63;
    int tid = threadIdx.x;
    int pg  = tid & 63;         // p-group: 4 consecutive kv within 256-chunk
    int qg  = tid >> 6;         // 0..3 -> queries 4qg..4qg+3

    __shared__ float  qt[16][33];
    __shared__ float  ext[16][32];
    __shared__ float  eyt[16][32];
    __shared__ float4 Kt[32][64];   // [dd][p4], 32 KB

    float accr[4][16];
#pragma unroll
    for (int qq = 0; qq < 4; ++qq)
#pragma unroll
        for (int cj = 0; cj < 16; ++cj) accr[qq][cj] = 0.f;

    const float* Qn = Q + (size_t)n * CDIM * HW;
    const float* Kn = K + (size_t)n * CDIM * PKV;

    for (int m = 0; m < MHEAD; ++m) {
        __syncthreads();
        {   // load 16x32 query tile
            int q = tid & 15, dd0 = tid >> 4;
            qt[q][dd0]      = Qn[(size_t)(m * 32 + dd0) * HW + i0 + q];
            qt[q][dd0 + 16] = Qn[(size_t)(m * 32 + dd0 + 16) * HW + i0 + q];
        }
        __syncthreads();
        // ex / ey: 1024 dots of 32, 4 per thread
#pragma unroll
        for (int rr = 0; rr < 4; ++rr) {
            int idx = tid + rr * 256;
            const float* pf;
            int q, uv;
            if (idx < 512) { q = idx >> 5; uv = idx & 31;
                pf = PFX + (((size_t)(m * 64 + wq0 + q) * 32) + uv) * 32;
            } else { int id2 = idx - 512; q = id2 >> 5; uv = id2 & 31;
                pf = PFY + (((size_t)(m * 64 + hq) * 32) + uv) * 32;
            }
            const float4* pf4 = (const float4*)pf;
            float s = 0.f;
#pragma unroll
            for (int d4 = 0; d4 < 8; ++d4) {
                float4 p = pf4[d4];
                s += qt[q][4 * d4 + 0] * p.x + qt[q][4 * d4 + 1] * p.y
                   + qt[q][4 * d4 + 2] * p.z + qt[q][4 * d4 + 3] * p.w;
            }
            if (idx < 512) ext[q][uv] = s; else eyt[q][uv] = s;
        }

        float ev[4][16];
#pragma unroll
        for (int qq = 0; qq < 4; ++qq)
#pragma unroll
            for (int cj = 0; cj < 16; ++cj) ev[qq][cj] = 0.f;

#pragma unroll
        for (int c = 0; c < 4; ++c) {   // kv chunks of 256
            __syncthreads();
            {   // stage K chunk: 2048 float4 / 256 threads
#pragma unroll
                for (int l = 0; l < 8; ++l) {
                    int fi = l * 256 + tid;
                    int dd = fi >> 6, c4 = fi & 63;
                    Kt[dd][c4] = *(const float4*)&Kn[(size_t)(m * 32 + dd) * PKV + c * 256 + 4 * c4];
                }
            }
            __syncthreads();
#pragma unroll
            for (int dd = 0; dd < 32; ++dd) {
                float4 kv = Kt[dd][pg];
#pragma unroll
                for (int qq = 0; qq < 4; ++qq) {
                    float qv = qt[4 * qg + qq][dd];
                    ev[qq][c * 4 + 0] += qv * kv.x;
                    ev[qq][c * 4 + 1] += qv * kv.y;
                    ev[qq][c * 4 + 2] += qv * kv.z;
                    ev[qq][c * 4 + 3] += qv * kv.w;
                }
            }
        }
        __syncthreads();

        float wmx = MIXW[n * 9 + m];
#pragma unroll
        for (int qq = 0; qq < 4; ++qq) {
            int q = 4 * qg + qq;
            float exv[4];
#pragma unroll
            for (int j = 0; j < 4; ++j) exv[j] = ext[q][(4 * pg + j) & 31];
            float mx = -1e30f;
#pragma unroll
            for (int c = 0; c < 4; ++c)
#pragma unroll
                for (int j = 0; j < 4; ++j) {
                    float t = ev[qq][c * 4 + j] + exv[j] + eyt[q][c * 8 + ((4 * pg + j) >> 5)];
                    ev[qq][c * 4 + j] = t;
                    mx = fmaxf(mx, t);
                }
#pragma unroll
            for (int off = 32; off > 0; off >>= 1) mx = fmaxf(mx, __shfl_xor(mx, off, 64));
            float sm = 0.f;
#pragma unroll
            for (int cj = 0; cj < 16; ++cj) {
                float e = __expf(ev[qq][cj] - mx);
                ev[qq][cj] = e; sm += e;
            }
#pragma unroll
            for (int off = 32; off > 0; off >>= 1) sm += __shfl_xor(sm, off, 64);
            float sc = wmx / sm;
#pragma unroll
            for (int cj = 0; cj < 16; ++cj) accr[qq][cj] += ev[qq][cj] * sc;
        }
    }
    // write mixed attention rows
#pragma unroll
    for (int qq = 0; qq < 4; ++qq) {
        float* orow = ATTN + ((size_t)(n * HW) + i0 + 4 * qg + qq) * PKV;
#pragma unroll
        for (int c = 0; c < 4; ++c) {
            float4 st = { accr[qq][c * 4 + 0], accr[qq][c * 4 + 1],
                          accr[qq][c * 4 + 2], accr[qq][c * 4 + 3] };
            *(float4*)&orow[c * 256 + 4 * pg] = st;
        }
    }
}

// ---------------------------------------------------------------------------
extern "C" void kernel_launch(void* const* d_in, const int* in_sizes, int n_in,
                              void* d_out, int out_size, void* d_ws, size_t ws_size,
                              hipStream_t stream) {
    const float* x     = (const float*)d_in[0];
    const float* Wq    = (const float*)d_in[1];
    const float* Wk    = (const float*)d_in[2];
    const float* Wv    = (const float*)d_in[3];
    const float* Wx    = (const float*)d_in[4];
    const float* Wy    = (const float*)d_in[5];
    const float* Wproj = (const float*)d_in[6];
    const float* bproj = (const float*)d_in[7];
    const float* Wc    = (const float*)d_in[8];
    const float* bc    = (const float*)d_in[9];
    const float* gamma = (const float*)d_in[10];
    float* out = (float*)d_out;

    float* ws = (float*)d_ws;
    size_t off = 0;
    float* Q    = ws + off; off += (size_t)NB * CDIM * HW;
    float* K    = ws + off; off += (size_t)NB * CDIM * PKV;
    float* V    = ws + off; off += (size_t)NB * CDIM * PKV;
    float* PFX  = ws + off; off += (size_t)MHEAD * 64 * 32 * 32;
    float* PFY  = ws + off; off += (size_t)MHEAD * 64 * 32 * 32;
    float* CTX  = ws + off; off += NB * CDIM;
    float* MIXW = ws + off; off += 32;
    float* ATTN = ws + off; off += (size_t)NB * HW * PKV;
    float* MID  = ws + off; off += (size_t)NB * CDIM * HW;

    gemm_q<<<dim3(HW / 128, CDIM / 32, NB), 256, 0, stream>>>(Wq, x, Q);
    gemm_kv<<<dim3(PKV / 128, CDIM / 32, NB), 256, 0, stream>>>(Wk, Wv, x, K, V);
    pf_kernel<<<2 * 64 * 32, 256, 0, stream>>>(Wx, Wy, PFX, PFY);
    ctx_kernel<<<NB * CDIM, 256, 0, stream>>>(Q, CTX);
    mixw_kernel<<<1, 64, 0, stream>>>(CTX, Wc, bc, MIXW);
    attn_v2<<<NB * HW / 16, 256, 0, stream>>>(Q, K, PFX, PFY, MIXW, ATTN);
    gemm_av<<<dim3(HW / 128, CDIM / 32, NB), 256, 0, stream>>>(V, ATTN, MID);
    gemm_proj<<<dim3(HW / 128, CDIM / 32, NB), 256, 0, stream>>>(Wproj, MID, bproj, x, gamma, out);
}

// Round 3
// 445.213 us; speedup vs baseline: 2.6859x; 1.4304x over previous
//
#include <hip/hip_runtime.h>
#include <math.h>

// n=2, C=288, h=w=64 -> hw=4096; kv stride 2 -> 32x32 -> pkv=1024; M=9 heads, d=32
#define NB     2
#define CDIM   288
#define HW     4096
#define PKV    1024
#define MHEAD  9
#define DHEAD  32

typedef __attribute__((ext_vector_type(8))) short bf16x8;
typedef __attribute__((ext_vector_type(4))) float f32x4;

__device__ inline unsigned short f2bf(float x) {
    unsigned int u = __float_as_uint(x);
    u = (u + 0x7fffu + ((u >> 16) & 1u)) >> 16;
    return (unsigned short)u;
}

// ---------------------------------------------------------------------------
// gemm_q: Qf[(n*9+m)*4096 + j][d] (bf16) = sum_c Wq[m*32+d][c] * X[n][c][j]
__global__ __launch_bounds__(256) void gemm_q(const float* __restrict__ W,
        const float* __restrict__ X, unsigned short* __restrict__ Qf) {
    int n  = blockIdx.z;
    int o0 = blockIdx.y * 32;
    int j0 = blockIdx.x * 128;
    int tid = threadIdx.x;
    int a = tid >> 5, b = tid & 31;
    __shared__ float Wt[16][36];
    __shared__ float Xt[16][128];
    const float* Xn = X + (size_t)n * CDIM * HW;
    float acc[4][4] = {};
    int wr = tid >> 3, wc = tid & 7;
    int xk = tid >> 4, xc = (tid & 15) * 8;
    for (int c0 = 0; c0 < CDIM; c0 += 16) {
        float2 wv = *(const float2*)&W[(o0 + wr) * CDIM + c0 + 2 * wc];
        Wt[2 * wc][wr] = wv.x; Wt[2 * wc + 1][wr] = wv.y;
        const float* xs = &Xn[(size_t)(c0 + xk) * HW + j0 + xc];
        *(float4*)&Xt[xk][xc]     = *(const float4*)&xs[0];
        *(float4*)&Xt[xk][xc + 4] = *(const float4*)&xs[4];
        __syncthreads();
#pragma unroll
        for (int kk = 0; kk < 16; ++kk) {
            float4 w4 = *(const float4*)&Wt[kk][4 * a];
            float4 x4 = *(const float4*)&Xt[kk][4 * b];
            acc[0][0] += w4.x * x4.x; acc[0][1] += w4.x * x4.y; acc[0][2] += w4.x * x4.z; acc[0][3] += w4.x * x4.w;
            acc[1][0] += w4.y * x4.x; acc[1][1] += w4.y * x4.y; acc[1][2] += w4.y * x4.z; acc[1][3] += w4.y * x4.w;
            acc[2][0] += w4.z * x4.x; acc[2][1] += w4.z * x4.y; acc[2][2] += w4.z * x4.z; acc[2][3] += w4.z * x4.w;
            acc[3][0] += w4.w * x4.x; acc[3][1] += w4.w * x4.y; acc[3][2] += w4.w * x4.z; acc[3][3] += w4.w * x4.w;
        }
        __syncthreads();
    }
#pragma unroll
    for (int i2 = 0; i2 < 4; ++i2) {
        int o = o0 + 4 * a + i2;
        int m = o >> 5, d = o & 31;
        size_t base = ((size_t)(n * MHEAD + m) * HW + j0 + 4 * b) * 32 + d;
#pragma unroll
        for (int jj = 0; jj < 4; ++jj)
            Qf[base + (size_t)jj * 32] = f2bf(acc[i2][jj]);
    }
}

// gemm_kv: Kf bf16 [(n*9+m)*1024 + p][d]; V fp32 [n][o][p]. x_kv gather.
__global__ __launch_bounds__(256) void gemm_kv(const float* __restrict__ Wk,
        const float* __restrict__ Wv, const float* __restrict__ X,
        unsigned short* __restrict__ Kf, float* __restrict__ Vout) {
    int n  = blockIdx.z;
    int o0 = blockIdx.y * 32;
    int j0 = blockIdx.x * 128;
    int tid = threadIdx.x;
    int a = tid >> 5, b = tid & 31;
    __shared__ float Wt[2][16][36];
    __shared__ float Xt[16][128];
    const float* Xn = X + (size_t)n * CDIM * HW;
    float acck[4][4] = {};
    float accv[4][4] = {};
    int wr = tid >> 3, wc = tid & 7;
    int xk = tid >> 4, xc = (tid & 15) * 8;
    for (int c0 = 0; c0 < CDIM; c0 += 16) {
        float2 kw = *(const float2*)&Wk[(o0 + wr) * CDIM + c0 + 2 * wc];
        float2 vw = *(const float2*)&Wv[(o0 + wr) * CDIM + c0 + 2 * wc];
        Wt[0][2 * wc][wr] = kw.x; Wt[0][2 * wc + 1][wr] = kw.y;
        Wt[1][2 * wc][wr] = vw.x; Wt[1][2 * wc + 1][wr] = vw.y;
        const float* xrow = &Xn[(size_t)(c0 + xk) * HW];
#pragma unroll
        for (int l = 0; l < 8; ++l) {
            int j = j0 + xc + l;
            int pos = ((j >> 5) << 7) + ((j & 31) << 1);
            Xt[xk][xc + l] = xrow[pos];
        }
        __syncthreads();
#pragma unroll
        for (int kk = 0; kk < 16; ++kk) {
            float4 k4 = *(const float4*)&Wt[0][kk][4 * a];
            float4 v4 = *(const float4*)&Wt[1][kk][4 * a];
            float4 x4 = *(const float4*)&Xt[kk][4 * b];
            acck[0][0] += k4.x * x4.x; acck[0][1] += k4.x * x4.y; acck[0][2] += k4.x * x4.z; acck[0][3] += k4.x * x4.w;
            acck[1][0] += k4.y * x4.x; acck[1][1] += k4.y * x4.y; acck[1][2] += k4.y * x4.z; acck[1][3] += k4.y * x4.w;
            acck[2][0] += k4.z * x4.x; acck[2][1] += k4.z * x4.y; acck[2][2] += k4.z * x4.z; acck[2][3] += k4.z * x4.w;
            acck[3][0] += k4.w * x4.x; acck[3][1] += k4.w * x4.y; acck[3][2] += k4.w * x4.z; acck[3][3] += k4.w * x4.w;
            accv[0][0] += v4.x * x4.x; accv[0][1] += v4.x * x4.y; accv[0][2] += v4.x * x4.z; accv[0][3] += v4.x * x4.w;
            accv[1][0] += v4.y * x4.x; accv[1][1] += v4.y * x4.y; accv[1][2] += v4.y * x4.z; accv[1][3] += v4.y * x4.w;
            accv[2][0] += v4.z * x4.x; accv[2][1] += v4.z * x4.y; accv[2][2] += v4.z * x4.z; accv[2][3] += v4.z * x4.w;
            accv[3][0] += v4.w * x4.x; accv[3][1] += v4.w * x4.y; accv[3][2] += v4.w * x4.z; accv[3][3] += v4.w * x4.w;
        }
        __syncthreads();
    }
#pragma unroll
    for (int i2 = 0; i2 < 4; ++i2) {
        int o = o0 + 4 * a + i2;
        int m = o >> 5, d = o & 31;
        size_t kbase = ((size_t)(n * MHEAD + m) * PKV + j0 + 4 * b) * 32 + d;
#pragma unroll
        for (int jj = 0; jj < 4; ++jj)
            Kf[kbase + (size_t)jj * 32] = f2bf(acck[i2][jj]);
        size_t vrow = ((size_t)(n * CDIM) + o) * PKV + j0 + 4 * b;
        float4 sv = { accv[i2][0], accv[i2][1], accv[i2][2], accv[i2][3] };
        *(float4*)&Vout[vrow] = sv;
    }
}

// MID[n][o][i] = sum_p V[n][o][p] * ATTN[n][i][p]
__global__ __launch_bounds__(256) void gemm_av(const float* __restrict__ V,
        const float* __restrict__ A, float* __restrict__ OUT) {
    int n  = blockIdx.z;
    int o0 = blockIdx.y * 32;
    int i0 = blockIdx.x * 128;
    int tid = threadIdx.x;
    int a = tid >> 5, b = tid & 31;
    __shared__ float Wt[16][36];
    __shared__ float Xt[16][132];
    const float* Vn = V + (size_t)n * CDIM * PKV;
    const float* An = A + (size_t)n * HW * PKV;
    float acc[4][4] = {};
    int wr = tid >> 3, wc = tid & 7;
    int nn = tid >> 1, pc = (tid & 1) * 8;
    for (int p0 = 0; p0 < PKV; p0 += 16) {
        float2 wv = *(const float2*)&Vn[(size_t)(o0 + wr) * PKV + p0 + 2 * wc];
        Wt[2 * wc][wr] = wv.x; Wt[2 * wc + 1][wr] = wv.y;
        const float* as = &An[(size_t)(i0 + nn) * PKV + p0 + pc];
        float4 a0 = *(const float4*)&as[0];
        float4 a1 = *(const float4*)&as[4];
        Xt[pc + 0][nn] = a0.x; Xt[pc + 1][nn] = a0.y; Xt[pc + 2][nn] = a0.z; Xt[pc + 3][nn] = a0.w;
        Xt[pc + 4][nn] = a1.x; Xt[pc + 5][nn] = a1.y; Xt[pc + 6][nn] = a1.z; Xt[pc + 7][nn] = a1.w;
        __syncthreads();
#pragma unroll
        for (int kk = 0; kk < 16; ++kk) {
            float4 w4 = *(const float4*)&Wt[kk][4 * a];
            float4 x4 = *(const float4*)&Xt[kk][4 * b];
            acc[0][0] += w4.x * x4.x; acc[0][1] += w4.x * x4.y; acc[0][2] += w4.x * x4.z; acc[0][3] += w4.x * x4.w;
            acc[1][0] += w4.y * x4.x; acc[1][1] += w4.y * x4.y; acc[1][2] += w4.y * x4.z; acc[1][3] += w4.y * x4.w;
            acc[2][0] += w4.z * x4.x; acc[2][1] += w4.z * x4.y; acc[2][2] += w4.z * x4.z; acc[2][3] += w4.z * x4.w;
            acc[3][0] += w4.w * x4.x; acc[3][1] += w4.w * x4.y; acc[3][2] += w4.w * x4.z; acc[3][3] += w4.w * x4.w;
        }
        __syncthreads();
    }
#pragma unroll
    for (int i = 0; i < 4; ++i) {
        float4 st = { acc[i][0], acc[i][1], acc[i][2], acc[i][3] };
        *(float4*)&OUT[((size_t)(n * CDIM) + o0 + 4 * a + i) * HW + i0 + 4 * b] = st;
    }
}

// OUT[n][o][j] = gamma*(sum_c Wproj[o][c]*MID[n][c][j] + bproj[o]) + x[n][o][j]
__global__ __launch_bounds__(256) void gemm_proj(const float* __restrict__ W,
        const float* __restrict__ MID, const float* __restrict__ bproj,
        const float* __restrict__ x, const float* __restrict__ gamma,
        float* __restrict__ OUT) {
    int n  = blockIdx.z;
    int o0 = blockIdx.y * 32;
    int j0 = blockIdx.x * 128;
    int tid = threadIdx.x;
    int a = tid >> 5, b = tid & 31;
    __shared__ float Wt[16][36];
    __shared__ float Xt[16][128];
    const float* Mn = MID + (size_t)n * CDIM * HW;
    float acc[4][4] = {};
    int wr = tid >> 3, wc = tid & 7;
    int xk = tid >> 4, xc = (tid & 15) * 8;
    for (int c0 = 0; c0 < CDIM; c0 += 16) {
        float2 wv = *(const float2*)&W[(o0 + wr) * CDIM + c0 + 2 * wc];
        Wt[2 * wc][wr] = wv.x; Wt[2 * wc + 1][wr] = wv.y;
        const float* xs = &Mn[(size_t)(c0 + xk) * HW + j0 + xc];
        *(float4*)&Xt[xk][xc]     = *(const float4*)&xs[0];
        *(float4*)&Xt[xk][xc + 4] = *(const float4*)&xs[4];
        __syncthreads();
#pragma unroll
        for (int kk = 0; kk < 16; ++kk) {
            float4 w4 = *(const float4*)&Wt[kk][4 * a];
            float4 x4 = *(const float4*)&Xt[kk][4 * b];
            acc[0][0] += w4.x * x4.x; acc[0][1] += w4.x * x4.y; acc[0][2] += w4.x * x4.z; acc[0][3] += w4.x * x4.w;
            acc[1][0] += w4.y * x4.x; acc[1][1] += w4.y * x4.y; acc[1][2] += w4.y * x4.z; acc[1][3] += w4.y * x4.w;
            acc[2][0] += w4.z * x4.x; acc[2][1] += w4.z * x4.y; acc[2][2] += w4.z * x4.z; acc[2][3] += w4.z * x4.w;
            acc[3][0] += w4.w * x4.x; acc[3][1] += w4.w * x4.y; acc[3][2] += w4.w * x4.z; acc[3][3] += w4.w * x4.w;
        }
        __syncthreads();
    }
    float g = gamma[0];
#pragma unroll
    for (int i = 0; i < 4; ++i) {
        size_t idx = ((size_t)(n * CDIM) + o0 + 4 * a + i) * HW + j0 + 4 * b;
        float bb = bproj[o0 + 4 * a + i];
        float4 xv = *(const float4*)&x[idx];
        float4 st;
        st.x = g * (acc[i][0] + bb) + xv.x;
        st.y = g * (acc[i][1] + bb) + xv.y;
        st.z = g * (acc[i][2] + bb) + xv.z;
        st.w = g * (acc[i][3] + bb) + xv.w;
        *(float4*)&OUT[idx] = st;
    }
}

// ---------------------------------------------------------------------------
// Positional factors (fp32): PF[((m*64+a)*32+b)*32+d]
__global__ void pf_kernel(const float* __restrict__ Wx, const float* __restrict__ Wy,
                          float* __restrict__ PFX, float* __restrict__ PFY) {
    int b    = blockIdx.x;          // 2*64*32 blocks
    int axis = b >> 11;
    int a    = (b >> 5) & 63;
    int bb   = b & 31;
    __shared__ float emb[144];
    int tid = threadIdx.x;          // 256
    float diff = (float)(a - 2 * bb);
    if (tid < 72) {
        float dm = expf(6.9077552789821368f * ((float)tid * (1.f / 72.f)));
        float t  = diff / dm;
        emb[tid]      = sinf(t);
        emb[72 + tid] = cosf(t);
    }
    __syncthreads();
    const float* W  = axis ? Wy : Wx;
    float*       PF = axis ? PFY : PFX;
    const float inv_sqrt2 = 0.70710678118654752f;
    for (int o = tid; o < CDIM; o += 256) {
        const float* wr = W + (size_t)o * 144;
        float s = 0.f;
#pragma unroll 8
        for (int f = 0; f < 144; ++f) s += emb[f] * wr[f];
        int m = o >> 5, dd = o & 31;
        PF[(((size_t)(m * 64 + a) * 32 + bb) * 32) + dd] = s * inv_sqrt2;
    }
}

// meanx[n][c] = mean over hw of x   (context = Wq @ meanx, mean commutes)
__global__ void meanx_kernel(const float* __restrict__ X, float* __restrict__ MX) {
    int bid = blockIdx.x;                    // 576
    const float* xr = X + (size_t)bid * HW;
    int tid = threadIdx.x;
    float s = 0.f;
    for (int j = tid; j < HW; j += 256) s += xr[j];
    for (int off = 32; off > 0; off >>= 1) s += __shfl_xor(s, off, 64);
    __shared__ float red[4];
    if ((tid & 63) == 0) red[tid >> 6] = s;
    __syncthreads();
    if (tid == 0) MX[bid] = (red[0] + red[1] + red[2] + red[3]) * (1.f / 4096.f);
}

// single block: ctx = Wq @ meanx; logits = ctx @ Wc^T + bc; softmax -> MIXW
__global__ void mixw2_kernel(const float* __restrict__ Wq, const float* __restrict__ MX,
                             const float* __restrict__ Wc, const float* __restrict__ bc,
                             float* __restrict__ MIXW) {
    __shared__ float ctx_s[NB * CDIM];
    __shared__ float lg[18];
    int tid = threadIdx.x;   // 256
    for (int p = tid; p < NB * CDIM; p += 256) {
        int n = p / CDIM, o = p % CDIM;
        const float* wr = Wq + (size_t)o * CDIM;
        const float* mx = MX + n * CDIM;
        float s = 0.f;
        for (int c = 0; c < CDIM; c += 4) {
            float4 w4 = *(const float4*)&wr[c];
            float4 m4 = *(const float4*)&mx[c];
            s += w4.x * m4.x + w4.y * m4.y + w4.z * m4.z + w4.w * m4.w;
        }
        ctx_s[p] = s;
    }
    __syncthreads();
    if (tid < 18) {
        int n = tid / 9, j = tid % 9;
        float s = bc[j];
        for (int o = 0; o < CDIM; ++o) s += ctx_s[n * CDIM + o] * Wc[j * CDIM + o];
        lg[tid] = s;
    }
    __syncthreads();
    if (tid < 2) {
        float mx = -1e30f;
        for (int j = 0; j < 9; ++j) mx = fmaxf(mx, lg[tid * 9 + j]);
        float e[9], sm = 0.f;
        for (int j = 0; j < 9; ++j) { e[j] = __expf(lg[tid * 9 + j] - mx); sm += e[j]; }
        for (int j = 0; j < 9; ++j) MIXW[tid * 9 + j] = e[j] / sm;
    }
}

// ---------------------------------------------------------------------------
// MFMA attention: 16 queries/block, 9 heads serial, 1024 kv. No-max softmax
// (energies bounded ~|60| << 88, fp32 exp safe). mfma_f32_16x16x32_bf16, K=32=d.
// Wave wv handles kv range [wv*256, wv*256+256) = 16 tiles of 16.
__global__ __launch_bounds__(256) void attn_v3(
        const unsigned short* __restrict__ Qf, const unsigned short* __restrict__ Kf,
        const float* __restrict__ PFX, const float* __restrict__ PFY,
        const float* __restrict__ MIXW, float* __restrict__ ATTN) {
    int n    = blockIdx.x >> 8;
    int i0   = (blockIdx.x & 255) * 16;
    int hq   = i0 >> 6;
    int wq0  = i0 & 63;
    int tid  = threadIdx.x;
    int wv   = tid >> 6;
    int lane = tid & 63;
    int lq   = lane & 15;
    int quad = lane >> 4;

    __shared__ float ext_s[16][33];
    __shared__ float eyt_s[16][33];
    __shared__ float ws_s[4][16];
    __shared__ float ltot_s[16];

    float mixed[16][4];
#pragma unroll
    for (int t = 0; t < 16; ++t)
#pragma unroll
        for (int j = 0; j < 4; ++j) mixed[t][j] = 0.f;

    for (int m = 0; m < MHEAD; ++m) {
        const unsigned short* Qm = Qf + ((size_t)(n * MHEAD + m) * HW + i0) * 32;
        const unsigned short* Km = Kf + ((size_t)(n * MHEAD + m) * PKV) * 32;

        // --- ex/ey: thread t -> q = t&15, uv group t>>4 (uv<32: ex, else ey)
        {
            int qh  = tid & 15;
            int uvg = tid >> 4;
            float qv[32];
            const unsigned int* qr = (const unsigned int*)(Qm + (size_t)qh * 32);
#pragma unroll
            for (int kk = 0; kk < 16; ++kk) {
                unsigned int u2 = qr[kk];
                qv[2 * kk]     = __uint_as_float(u2 << 16);
                qv[2 * kk + 1] = __uint_as_float(u2 & 0xffff0000u);
            }
#pragma unroll
            for (int k = 0; k < 4; ++k) {
                int uv = uvg * 4 + k;
                const float* pf = (uv < 32)
                    ? (PFX + ((size_t)(m * 64 + wq0 + qh) * 32 + uv) * 32)
                    : (PFY + ((size_t)(m * 64 + hq) * 32 + (uv - 32)) * 32);
                float s = 0.f;
#pragma unroll
                for (int d4 = 0; d4 < 8; ++d4) {
                    float4 p = ((const float4*)pf)[d4];
                    s += qv[4 * d4] * p.x + qv[4 * d4 + 1] * p.y
                       + qv[4 * d4 + 2] * p.z + qv[4 * d4 + 3] * p.w;
                }
                if (uv < 32) ext_s[qh][uv] = s;
                else         eyt_s[qh][uv - 32] = s;
            }
        }
        __syncthreads();

        // --- A fragment (same for all waves): A[m=lq][k=quad*8+j]
        bf16x8 afrag = *(const bf16x8*)(Qm + (size_t)lq * 32 + quad * 8);

        float exA[4], exB[4];
#pragma unroll
        for (int j = 0; j < 4; ++j) {
            exA[j] = ext_s[quad * 4 + j][lq];
            exB[j] = ext_s[quad * 4 + j][16 + lq];
        }

        // --- QK^T for this wave's 256 kv: 16 MFMAs
        f32x4 acc[16];
#pragma unroll
        for (int t = 0; t < 16; ++t) acc[t] = (f32x4){0.f, 0.f, 0.f, 0.f};
        {
            bf16x8 bf[8];
#pragma unroll
            for (int t = 0; t < 8; ++t)
                bf[t] = *(const bf16x8*)(Km + (size_t)(wv * 256 + t * 16 + lq) * 32 + quad * 8);
#pragma unroll
            for (int t = 0; t < 8; ++t)
                acc[t] = __builtin_amdgcn_mfma_f32_16x16x32_bf16(afrag, bf[t], acc[t], 0, 0, 0);
#pragma unroll
            for (int t = 0; t < 8; ++t)
                bf[t] = *(const bf16x8*)(Km + (size_t)(wv * 256 + (t + 8) * 16 + lq) * 32 + quad * 8);
#pragma unroll
            for (int t = 0; t < 8; ++t)
                acc[t + 8] = __builtin_amdgcn_mfma_f32_16x16x32_bf16(afrag, bf[t], acc[t + 8], 0, 0, 0);
        }

        // --- exp + row sums (C layout: row = quad*4+j, col = lq)
        float rs[4] = {0.f, 0.f, 0.f, 0.f};
#pragma unroll
        for (int tp = 0; tp < 8; ++tp) {
            int u = wv * 8 + tp;
            float ey0[4];
#pragma unroll
            for (int j = 0; j < 4; ++j) ey0[j] = eyt_s[quad * 4 + j][u];
#pragma unroll
            for (int half = 0; half < 2; ++half) {
                int t = tp * 2 + half;
#pragma unroll
                for (int j = 0; j < 4; ++j) {
                    float e = __expf(acc[t][j] + (half ? exB[j] : exA[j]) + ey0[j]);
                    rs[j] += e;
                    acc[t][j] = e;
                }
            }
        }
#pragma unroll
        for (int j = 0; j < 4; ++j) {
            rs[j] += __shfl_xor(rs[j], 1, 64);
            rs[j] += __shfl_xor(rs[j], 2, 64);
            rs[j] += __shfl_xor(rs[j], 4, 64);
            rs[j] += __shfl_xor(rs[j], 8, 64);
        }
        if (lq == 0) {
#pragma unroll
            for (int j = 0; j < 4; ++j) ws_s[wv][quad * 4 + j] = rs[j];
        }
        __syncthreads();
        if (tid < 16) ltot_s[tid] = ws_s[0][tid] + ws_s[1][tid] + ws_s[2][tid] + ws_s[3][tid];
        __syncthreads();

        float wm = MIXW[n * MHEAD + m];
        float fct[4];
#pragma unroll
        for (int j = 0; j < 4; ++j) fct[j] = wm / ltot_s[quad * 4 + j];
#pragma unroll
        for (int t = 0; t < 16; ++t)
#pragma unroll
            for (int j = 0; j < 4; ++j) mixed[t][j] += acc[t][j] * fct[j];
    }

    // --- write mixed attention rows
    float* An = ATTN + ((size_t)n * HW + i0) * PKV;
#pragma unroll
    for (int j = 0; j < 4; ++j) {
        float* rp = An + (size_t)(quad * 4 + j) * PKV + wv * 256 + lq;
#pragma unroll
        for (int t = 0; t < 16; ++t) rp[t * 16] = mixed[t][j];
    }
}

// ---------------------------------------------------------------------------
extern "C" void kernel_launch(void* const* d_in, const int* in_sizes, int n_in,
                              void* d_out, int out_size, void* d_ws, size_t ws_size,
                              hipStream_t stream) {
    const float* x     = (const float*)d_in[0];
    const float* Wq    = (const float*)d_in[1];
    const float* Wk    = (const float*)d_in[2];
    const float* Wv    = (const float*)d_in[3];
    const float* Wx    = (const float*)d_in[4];
    const float* Wy    = (const float*)d_in[5];
    const float* Wproj = (const float*)d_in[6];
    const float* bproj = (const float*)d_in[7];
    const float* Wc    = (const float*)d_in[8];
    const float* bc    = (const float*)d_in[9];
    const float* gamma = (const float*)d_in[10];
    float* out = (float*)d_out;

    float* ws = (float*)d_ws;
    size_t off = 0;
    unsigned short* Qf = (unsigned short*)(ws + off); off += (size_t)NB * MHEAD * HW * 32 / 2;   // bf16
    unsigned short* Kf = (unsigned short*)(ws + off); off += (size_t)NB * MHEAD * PKV * 32 / 2;  // bf16
    float* V    = ws + off; off += (size_t)NB * CDIM * PKV;
    float* PFX  = ws + off; off += (size_t)MHEAD * 64 * 32 * 32;
    float* PFY  = ws + off; off += (size_t)MHEAD * 64 * 32 * 32;
    float* MX   = ws + off; off += NB * CDIM;
    float* MIXW = ws + off; off += 32;
    float* ATTN = ws + off; off += (size_t)NB * HW * PKV;
    float* MID  = ws + off; off += (size_t)NB * CDIM * HW;

    gemm_q<<<dim3(HW / 128, CDIM / 32, NB), 256, 0, stream>>>(Wq, x, Qf);
    gemm_kv<<<dim3(PKV / 128, CDIM / 32, NB), 256, 0, stream>>>(Wk, Wv, x, Kf, V);
    pf_kernel<<<2 * 64 * 32, 256, 0, stream>>>(Wx, Wy, PFX, PFY);
    meanx_kernel<<<NB * CDIM, 256, 0, stream>>>(x, MX);
    mixw2_kernel<<<1, 256, 0, stream>>>(Wq, MX, Wc, bc, MIXW);
    attn_v3<<<NB * HW / 16, 256, 0, stream>>>(Qf, Kf, PFX, PFY, MIXW, ATTN);
    gemm_av<<<dim3(HW / 128, CDIM / 32, NB), 256, 0, stream>>>(V, ATTN, MID);
    gemm_proj<<<dim3(HW / 128, CDIM / 32, NB), 256, 0, stream>>>(Wproj, MID, bproj, x, gamma, out);
}

// Round 4
// 398.416 us; speedup vs baseline: 3.0013x; 1.1175x over previous
//
#include <hip/hip_runtime.h>
#include <math.h>

// n=2, C=288, h=w=64 -> hw=4096; kv stride 2 -> 32x32 -> pkv=1024; M=9 heads, d=32
#define NB     2
#define CDIM   288
#define HW     4096
#define PKV    1024
#define MHEAD  9
#define DHEAD  32

typedef __attribute__((ext_vector_type(8))) short bf16x8;
typedef __attribute__((ext_vector_type(4))) float f32x4;

__device__ inline unsigned short f2bf(float x) {
    unsigned int u = __float_as_uint(x);
    u = (u + 0x7fffu + ((u >> 16) & 1u)) >> 16;
    return (unsigned short)u;
}

// ---------------------------------------------------------------------------
// gemm_q: Qf[(n*9+m)*4096 + j][d] (bf16) = sum_c Wq[m*32+d][c] * X[n][c][j]
__global__ __launch_bounds__(256) void gemm_q(const float* __restrict__ W,
        const float* __restrict__ X, unsigned short* __restrict__ Qf) {
    int n  = blockIdx.z;
    int o0 = blockIdx.y * 32;
    int j0 = blockIdx.x * 128;
    int tid = threadIdx.x;
    int a = tid >> 5, b = tid & 31;
    __shared__ float Wt[16][36];
    __shared__ float Xt[16][128];
    const float* Xn = X + (size_t)n * CDIM * HW;
    float acc[4][4] = {};
    int wr = tid >> 3, wc = tid & 7;
    int xk = tid >> 4, xc = (tid & 15) * 8;
    for (int c0 = 0; c0 < CDIM; c0 += 16) {
        float2 wv = *(const float2*)&W[(o0 + wr) * CDIM + c0 + 2 * wc];
        Wt[2 * wc][wr] = wv.x; Wt[2 * wc + 1][wr] = wv.y;
        const float* xs = &Xn[(size_t)(c0 + xk) * HW + j0 + xc];
        *(float4*)&Xt[xk][xc]     = *(const float4*)&xs[0];
        *(float4*)&Xt[xk][xc + 4] = *(const float4*)&xs[4];
        __syncthreads();
#pragma unroll
        for (int kk = 0; kk < 16; ++kk) {
            float4 w4 = *(const float4*)&Wt[kk][4 * a];
            float4 x4 = *(const float4*)&Xt[kk][4 * b];
            acc[0][0] += w4.x * x4.x; acc[0][1] += w4.x * x4.y; acc[0][2] += w4.x * x4.z; acc[0][3] += w4.x * x4.w;
            acc[1][0] += w4.y * x4.x; acc[1][1] += w4.y * x4.y; acc[1][2] += w4.y * x4.z; acc[1][3] += w4.y * x4.w;
            acc[2][0] += w4.z * x4.x; acc[2][1] += w4.z * x4.y; acc[2][2] += w4.z * x4.z; acc[2][3] += w4.z * x4.w;
            acc[3][0] += w4.w * x4.x; acc[3][1] += w4.w * x4.y; acc[3][2] += w4.w * x4.z; acc[3][3] += w4.w * x4.w;
        }
        __syncthreads();
    }
#pragma unroll
    for (int i2 = 0; i2 < 4; ++i2) {
        int o = o0 + 4 * a + i2;
        int m = o >> 5, d = o & 31;
        size_t base = ((size_t)(n * MHEAD + m) * HW + j0 + 4 * b) * 32 + d;
#pragma unroll
        for (int jj = 0; jj < 4; ++jj)
            Qf[base + (size_t)jj * 32] = f2bf(acc[i2][jj]);
    }
}

// gemm_kv: Kf bf16 [(n*9+m)*1024 + p][d]; Vb bf16 [n][o][p]. x_kv gather.
__global__ __launch_bounds__(256) void gemm_kv(const float* __restrict__ Wk,
        const float* __restrict__ Wv, const float* __restrict__ X,
        unsigned short* __restrict__ Kf, unsigned short* __restrict__ Vb) {
    int n  = blockIdx.z;
    int o0 = blockIdx.y * 32;
    int j0 = blockIdx.x * 128;
    int tid = threadIdx.x;
    int a = tid >> 5, b = tid & 31;
    __shared__ float Wt[2][16][36];
    __shared__ float Xt[16][128];
    const float* Xn = X + (size_t)n * CDIM * HW;
    float acck[4][4] = {};
    float accv[4][4] = {};
    int wr = tid >> 3, wc = tid & 7;
    int xk = tid >> 4, xc = (tid & 15) * 8;
    for (int c0 = 0; c0 < CDIM; c0 += 16) {
        float2 kw = *(const float2*)&Wk[(o0 + wr) * CDIM + c0 + 2 * wc];
        float2 vw = *(const float2*)&Wv[(o0 + wr) * CDIM + c0 + 2 * wc];
        Wt[0][2 * wc][wr] = kw.x; Wt[0][2 * wc + 1][wr] = kw.y;
        Wt[1][2 * wc][wr] = vw.x; Wt[1][2 * wc + 1][wr] = vw.y;
        const float* xrow = &Xn[(size_t)(c0 + xk) * HW];
#pragma unroll
        for (int l = 0; l < 8; ++l) {
            int j = j0 + xc + l;
            int pos = ((j >> 5) << 7) + ((j & 31) << 1);
            Xt[xk][xc + l] = xrow[pos];
        }
        __syncthreads();
#pragma unroll
        for (int kk = 0; kk < 16; ++kk) {
            float4 k4 = *(const float4*)&Wt[0][kk][4 * a];
            float4 v4 = *(const float4*)&Wt[1][kk][4 * a];
            float4 x4 = *(const float4*)&Xt[kk][4 * b];
            acck[0][0] += k4.x * x4.x; acck[0][1] += k4.x * x4.y; acck[0][2] += k4.x * x4.z; acck[0][3] += k4.x * x4.w;
            acck[1][0] += k4.y * x4.x; acck[1][1] += k4.y * x4.y; acck[1][2] += k4.y * x4.z; acck[1][3] += k4.y * x4.w;
            acck[2][0] += k4.z * x4.x; acck[2][1] += k4.z * x4.y; acck[2][2] += k4.z * x4.z; acck[2][3] += k4.z * x4.w;
            acck[3][0] += k4.w * x4.x; acck[3][1] += k4.w * x4.y; acck[3][2] += k4.w * x4.z; acck[3][3] += k4.w * x4.w;
            accv[0][0] += v4.x * x4.x; accv[0][1] += v4.x * x4.y; accv[0][2] += v4.x * x4.z; accv[0][3] += v4.x * x4.w;
            accv[1][0] += v4.y * x4.x; accv[1][1] += v4.y * x4.y; accv[1][2] += v4.y * x4.z; accv[1][3] += v4.y * x4.w;
            accv[2][0] += v4.z * x4.x; accv[2][1] += v4.z * x4.y; accv[2][2] += v4.z * x4.z; accv[2][3] += v4.z * x4.w;
            accv[3][0] += v4.w * x4.x; accv[3][1] += v4.w * x4.y; accv[3][2] += v4.w * x4.z; accv[3][3] += v4.w * x4.w;
        }
        __syncthreads();
    }
#pragma unroll
    for (int i2 = 0; i2 < 4; ++i2) {
        int o = o0 + 4 * a + i2;
        int m = o >> 5, d = o & 31;
        size_t kbase = ((size_t)(n * MHEAD + m) * PKV + j0 + 4 * b) * 32 + d;
#pragma unroll
        for (int jj = 0; jj < 4; ++jj)
            Kf[kbase + (size_t)jj * 32] = f2bf(acck[i2][jj]);
        size_t vrow = ((size_t)(n * CDIM) + o) * PKV + j0 + 4 * b;
        ushort4 sv = { f2bf(accv[i2][0]), f2bf(accv[i2][1]), f2bf(accv[i2][2]), f2bf(accv[i2][3]) };
        *(ushort4*)&Vb[vrow] = sv;
    }
}

// ---------------------------------------------------------------------------
// gemm_av MFMA: MIDb[n][i][o] (bf16, o contig) = sum_p ATTNb[i][p] * Vb[o][p]
// A-frag: ATTN rows (p contig); B-frag: V rows (p contig). No LDS.
__global__ __launch_bounds__(256) void gemm_av_mfma(const unsigned short* __restrict__ Vb,
        const unsigned short* __restrict__ Ab, unsigned short* __restrict__ MIDb) {
    int n    = blockIdx.z;
    int o0   = blockIdx.y * 48;
    int i0   = blockIdx.x * 64 + (threadIdx.x >> 6) * 16;
    int lane = threadIdx.x & 63;
    int lq = lane & 15, quad = lane >> 4;
    const unsigned short* Arow = Ab + ((size_t)(n * HW) + i0 + lq) * PKV + quad * 8;
    const unsigned short* V0   = Vb + ((size_t)(n * CDIM) + o0 + lq) * PKV + quad * 8;
    f32x4 acc[3] = {};
#pragma unroll 2
    for (int p0 = 0; p0 < PKV; p0 += 32) {
        bf16x8 af = *(const bf16x8*)(Arow + p0);
        bf16x8 b0 = *(const bf16x8*)(V0 + p0);
        bf16x8 b1 = *(const bf16x8*)(V0 + (size_t)16 * PKV + p0);
        bf16x8 b2 = *(const bf16x8*)(V0 + (size_t)32 * PKV + p0);
        acc[0] = __builtin_amdgcn_mfma_f32_16x16x32_bf16(af, b0, acc[0], 0, 0, 0);
        acc[1] = __builtin_amdgcn_mfma_f32_16x16x32_bf16(af, b1, acc[1], 0, 0, 0);
        acc[2] = __builtin_amdgcn_mfma_f32_16x16x32_bf16(af, b2, acc[2], 0, 0, 0);
    }
#pragma unroll
    for (int ot = 0; ot < 3; ++ot)
#pragma unroll
        for (int r = 0; r < 4; ++r) {
            int i = i0 + quad * 4 + r;
            int o = o0 + ot * 16 + lq;
            MIDb[((size_t)(n * HW) + i) * CDIM + o] = f2bf(acc[ot][r]);
        }
}

// gemm_proj MFMA: OUT[n][o][j] = g*(sum_c Wb[o][c]*MIDb[j][c] + bproj[o]) + x[n][o][j]
__global__ __launch_bounds__(256) void gemm_proj_mfma(const unsigned short* __restrict__ Wb,
        const unsigned short* __restrict__ MIDb, const float* __restrict__ bproj,
        const float* __restrict__ x, const float* __restrict__ gamma,
        float* __restrict__ OUT) {
    int n    = blockIdx.z;
    int o0   = blockIdx.y * 16;
    int j0   = blockIdx.x * 256 + (threadIdx.x >> 6) * 64;
    int lane = threadIdx.x & 63;
    int lq = lane & 15, quad = lane >> 4;
    const unsigned short* Wrow = Wb + (size_t)(o0 + lq) * CDIM + quad * 8;
    const unsigned short* M0   = MIDb + ((size_t)(n * HW) + j0 + lq) * CDIM + quad * 8;
    f32x4 acc[4] = {};
#pragma unroll
    for (int c0 = 0; c0 < CDIM; c0 += 32) {
        bf16x8 af = *(const bf16x8*)(Wrow + c0);
        bf16x8 b0 = *(const bf16x8*)(M0 + c0);
        bf16x8 b1 = *(const bf16x8*)(M0 + (size_t)16 * CDIM + c0);
        bf16x8 b2 = *(const bf16x8*)(M0 + (size_t)32 * CDIM + c0);
        bf16x8 b3 = *(const bf16x8*)(M0 + (size_t)48 * CDIM + c0);
        acc[0] = __builtin_amdgcn_mfma_f32_16x16x32_bf16(af, b0, acc[0], 0, 0, 0);
        acc[1] = __builtin_amdgcn_mfma_f32_16x16x32_bf16(af, b1, acc[1], 0, 0, 0);
        acc[2] = __builtin_amdgcn_mfma_f32_16x16x32_bf16(af, b2, acc[2], 0, 0, 0);
        acc[3] = __builtin_amdgcn_mfma_f32_16x16x32_bf16(af, b3, acc[3], 0, 0, 0);
    }
    float g = gamma[0];
#pragma unroll
    for (int jt = 0; jt < 4; ++jt)
#pragma unroll
        for (int r = 0; r < 4; ++r) {
            int o = o0 + quad * 4 + r;
            size_t idx = ((size_t)(n * CDIM) + o) * HW + j0 + jt * 16 + lq;
            OUT[idx] = g * (acc[jt][r] + bproj[o]) + x[idx];
        }
}

// fp32 -> bf16 convert (for Wproj)
__global__ void wcvt(const float* __restrict__ W, unsigned short* __restrict__ Wb, int nEl) {
    int i = blockIdx.x * 256 + threadIdx.x;
    if (i < nEl) Wb[i] = f2bf(W[i]);
}

// ---------------------------------------------------------------------------
// Positional factors (fp32): PF[((m*64+a)*32+b)*32+d]
__global__ void pf_kernel(const float* __restrict__ Wx, const float* __restrict__ Wy,
                          float* __restrict__ PFX, float* __restrict__ PFY) {
    int b    = blockIdx.x;          // 2*64*32 blocks
    int axis = b >> 11;
    int a    = (b >> 5) & 63;
    int bb   = b & 31;
    __shared__ float emb[144];
    int tid = threadIdx.x;          // 256
    float diff = (float)(a - 2 * bb);
    if (tid < 72) {
        float dm = expf(6.9077552789821368f * ((float)tid * (1.f / 72.f)));
        float t  = diff / dm;
        emb[tid]      = sinf(t);
        emb[72 + tid] = cosf(t);
    }
    __syncthreads();
    const float* W  = axis ? Wy : Wx;
    float*       PF = axis ? PFY : PFX;
    const float inv_sqrt2 = 0.70710678118654752f;
    for (int o = tid; o < CDIM; o += 256) {
        const float* wr = W + (size_t)o * 144;
        float s = 0.f;
#pragma unroll 8
        for (int f = 0; f < 144; ++f) s += emb[f] * wr[f];
        int m = o >> 5, dd = o & 31;
        PF[(((size_t)(m * 64 + a) * 32 + bb) * 32) + dd] = s * inv_sqrt2;
    }
}

// meanx[n][c] = mean over hw of x   (context = Wq @ meanx, mean commutes)
__global__ void meanx_kernel(const float* __restrict__ X, float* __restrict__ MX) {
    int bid = blockIdx.x;                    // 576
    const float* xr = X + (size_t)bid * HW;
    int tid = threadIdx.x;
    float s = 0.f;
    for (int j = tid; j < HW; j += 256) s += xr[j];
    for (int off = 32; off > 0; off >>= 1) s += __shfl_xor(s, off, 64);
    __shared__ float red[4];
    if ((tid & 63) == 0) red[tid >> 6] = s;
    __syncthreads();
    if (tid == 0) MX[bid] = (red[0] + red[1] + red[2] + red[3]) * (1.f / 4096.f);
}

// single block: ctx = Wq @ meanx; logits = ctx @ Wc^T + bc; softmax -> MIXW
__global__ void mixw2_kernel(const float* __restrict__ Wq, const float* __restrict__ MX,
                             const float* __restrict__ Wc, const float* __restrict__ bc,
                             float* __restrict__ MIXW) {
    __shared__ float ctx_s[NB * CDIM];
    __shared__ float lg[18];
    int tid = threadIdx.x;   // 256
    for (int p = tid; p < NB * CDIM; p += 256) {
        int n = p / CDIM, o = p % CDIM;
        const float* wr = Wq + (size_t)o * CDIM;
        const float* mx = MX + n * CDIM;
        float s = 0.f;
        for (int c = 0; c < CDIM; c += 4) {
            float4 w4 = *(const float4*)&wr[c];
            float4 m4 = *(const float4*)&mx[c];
            s += w4.x * m4.x + w4.y * m4.y + w4.z * m4.z + w4.w * m4.w;
        }
        ctx_s[p] = s;
    }
    __syncthreads();
    if (tid < 18) {
        int n = tid / 9, j = tid % 9;
        float s = bc[j];
        for (int o = 0; o < CDIM; ++o) s += ctx_s[n * CDIM + o] * Wc[j * CDIM + o];
        lg[tid] = s;
    }
    __syncthreads();
    if (tid < 2) {
        float mx = -1e30f;
        for (int j = 0; j < 9; ++j) mx = fmaxf(mx, lg[tid * 9 + j]);
        float e[9], sm = 0.f;
        for (int j = 0; j < 9; ++j) { e[j] = __expf(lg[tid * 9 + j] - mx); sm += e[j]; }
        for (int j = 0; j < 9; ++j) MIXW[tid * 9 + j] = e[j] / sm;
    }
}

// ---------------------------------------------------------------------------
// MFMA attention: 16 queries/block, 9 heads serial, 1024 kv. No-max softmax.
// Output ATTNb bf16 [i][p] (A-fragment layout for gemm_av).
__global__ __launch_bounds__(256) void attn_v3(
        const unsigned short* __restrict__ Qf, const unsigned short* __restrict__ Kf,
        const float* __restrict__ PFX, const float* __restrict__ PFY,
        const float* __restrict__ MIXW, unsigned short* __restrict__ ATTNb) {
    int n    = blockIdx.x >> 8;
    int i0   = (blockIdx.x & 255) * 16;
    int hq   = i0 >> 6;
    int wq0  = i0 & 63;
    int tid  = threadIdx.x;
    int wv   = tid >> 6;
    int lane = tid & 63;
    int lq   = lane & 15;
    int quad = lane >> 4;

    __shared__ float ext_s[16][33];
    __shared__ float eyt_s[16][33];
    __shared__ float ws_s[4][16];
    __shared__ float ltot_s[16];

    float mixed[16][4];
#pragma unroll
    for (int t = 0; t < 16; ++t)
#pragma unroll
        for (int j = 0; j < 4; ++j) mixed[t][j] = 0.f;

    for (int m = 0; m < MHEAD; ++m) {
        const unsigned short* Qm = Qf + ((size_t)(n * MHEAD + m) * HW + i0) * 32;
        const unsigned short* Km = Kf + ((size_t)(n * MHEAD + m) * PKV) * 32;

        // --- ex/ey: thread t -> q = t&15, uv group t>>4 (uv<32: ex, else ey)
        {
            int qh  = tid & 15;
            int uvg = tid >> 4;
            float qv[32];
            const unsigned int* qr = (const unsigned int*)(Qm + (size_t)qh * 32);
#pragma unroll
            for (int kk = 0; kk < 16; ++kk) {
                unsigned int u2 = qr[kk];
                qv[2 * kk]     = __uint_as_float(u2 << 16);
                qv[2 * kk + 1] = __uint_as_float(u2 & 0xffff0000u);
            }
#pragma unroll
            for (int k = 0; k < 4; ++k) {
                int uv = uvg * 4 + k;
                const float* pf = (uv < 32)
                    ? (PFX + ((size_t)(m * 64 + wq0 + qh) * 32 + uv) * 32)
                    : (PFY + ((size_t)(m * 64 + hq) * 32 + (uv - 32)) * 32);
                float s = 0.f;
#pragma unroll
                for (int d4 = 0; d4 < 8; ++d4) {
                    float4 p = ((const float4*)pf)[d4];
                    s += qv[4 * d4] * p.x + qv[4 * d4 + 1] * p.y
                       + qv[4 * d4 + 2] * p.z + qv[4 * d4 + 3] * p.w;
                }
                if (uv < 32) ext_s[qh][uv] = s;
                else         eyt_s[qh][uv - 32] = s;
            }
        }
        __syncthreads();

        // --- A fragment (same for all waves): A[m=lq][k=quad*8+j]
        bf16x8 afrag = *(const bf16x8*)(Qm + (size_t)lq * 32 + quad * 8);

        float exA[4], exB[4];
#pragma unroll
        for (int j = 0; j < 4; ++j) {
            exA[j] = ext_s[quad * 4 + j][lq];
            exB[j] = ext_s[quad * 4 + j][16 + lq];
        }

        // --- QK^T for this wave's 256 kv: 16 MFMAs
        f32x4 acc[16];
#pragma unroll
        for (int t = 0; t < 16; ++t) acc[t] = (f32x4){0.f, 0.f, 0.f, 0.f};
        {
            bf16x8 bf[8];
#pragma unroll
            for (int t = 0; t < 8; ++t)
                bf[t] = *(const bf16x8*)(Km + (size_t)(wv * 256 + t * 16 + lq) * 32 + quad * 8);
#pragma unroll
            for (int t = 0; t < 8; ++t)
                acc[t] = __builtin_amdgcn_mfma_f32_16x16x32_bf16(afrag, bf[t], acc[t], 0, 0, 0);
#pragma unroll
            for (int t = 0; t < 8; ++t)
                bf[t] = *(const bf16x8*)(Km + (size_t)(wv * 256 + (t + 8) * 16 + lq) * 32 + quad * 8);
#pragma unroll
            for (int t = 0; t < 8; ++t)
                acc[t + 8] = __builtin_amdgcn_mfma_f32_16x16x32_bf16(afrag, bf[t], acc[t + 8], 0, 0, 0);
        }

        // --- exp + row sums (C layout: row = quad*4+j, col = lq)
        float rs[4] = {0.f, 0.f, 0.f, 0.f};
#pragma unroll
        for (int tp = 0; tp < 8; ++tp) {
            int u = wv * 8 + tp;
            float ey0[4];
#pragma unroll
            for (int j = 0; j < 4; ++j) ey0[j] = eyt_s[quad * 4 + j][u];
#pragma unroll
            for (int half = 0; half < 2; ++half) {
                int t = tp * 2 + half;
#pragma unroll
                for (int j = 0; j < 4; ++j) {
                    float e = __expf(acc[t][j] + (half ? exB[j] : exA[j]) + ey0[j]);
                    rs[j] += e;
                    acc[t][j] = e;
                }
            }
        }
#pragma unroll
        for (int j = 0; j < 4; ++j) {
            rs[j] += __shfl_xor(rs[j], 1, 64);
            rs[j] += __shfl_xor(rs[j], 2, 64);
            rs[j] += __shfl_xor(rs[j], 4, 64);
            rs[j] += __shfl_xor(rs[j], 8, 64);
        }
        if (lq == 0) {
#pragma unroll
            for (int j = 0; j < 4; ++j) ws_s[wv][quad * 4 + j] = rs[j];
        }
        __syncthreads();
        if (tid < 16) ltot_s[tid] = ws_s[0][tid] + ws_s[1][tid] + ws_s[2][tid] + ws_s[3][tid];
        __syncthreads();

        float wm = MIXW[n * MHEAD + m];
        float fct[4];
#pragma unroll
        for (int j = 0; j < 4; ++j) fct[j] = wm / ltot_s[quad * 4 + j];
#pragma unroll
        for (int t = 0; t < 16; ++t)
#pragma unroll
            for (int j = 0; j < 4; ++j) mixed[t][j] += acc[t][j] * fct[j];
    }

    // --- write mixed attention rows (bf16)
    unsigned short* An = ATTNb + ((size_t)n * HW + i0) * PKV;
#pragma unroll
    for (int j = 0; j < 4; ++j) {
        unsigned short* rp = An + (size_t)(quad * 4 + j) * PKV + wv * 256 + lq;
#pragma unroll
        for (int t = 0; t < 16; ++t) rp[t * 16] = f2bf(mixed[t][j]);
    }
}

// ---------------------------------------------------------------------------
extern "C" void kernel_launch(void* const* d_in, const int* in_sizes, int n_in,
                              void* d_out, int out_size, void* d_ws, size_t ws_size,
                              hipStream_t stream) {
    const float* x     = (const float*)d_in[0];
    const float* Wq    = (const float*)d_in[1];
    const float* Wk    = (const float*)d_in[2];
    const float* Wv    = (const float*)d_in[3];
    const float* Wx    = (const float*)d_in[4];
    const float* Wy    = (const float*)d_in[5];
    const float* Wproj = (const float*)d_in[6];
    const float* bproj = (const float*)d_in[7];
    const float* Wc    = (const float*)d_in[8];
    const float* bc    = (const float*)d_in[9];
    const float* gamma = (const float*)d_in[10];
    float* out = (float*)d_out;

    float* ws = (float*)d_ws;
    size_t off = 0;
    unsigned short* Qf = (unsigned short*)(ws + off); off += (size_t)NB * MHEAD * HW * 32 / 2;
    unsigned short* Kf = (unsigned short*)(ws + off); off += (size_t)NB * MHEAD * PKV * 32 / 2;
    unsigned short* Vb = (unsigned short*)(ws + off); off += (size_t)NB * CDIM * PKV / 2;
    unsigned short* Wb = (unsigned short*)(ws + off); off += (size_t)(CDIM * CDIM + 2) / 2;
    float* PFX  = ws + off; off += (size_t)MHEAD * 64 * 32 * 32;
    float* PFY  = ws + off; off += (size_t)MHEAD * 64 * 32 * 32;
    float* MX   = ws + off; off += NB * CDIM;
    float* MIXW = ws + off; off += 32;
    unsigned short* ATTNb = (unsigned short*)(ws + off); off += (size_t)NB * HW * PKV / 2;
    unsigned short* MIDb  = (unsigned short*)(ws + off); off += (size_t)NB * HW * CDIM / 2;

    gemm_q<<<dim3(HW / 128, CDIM / 32, NB), 256, 0, stream>>>(Wq, x, Qf);
    gemm_kv<<<dim3(PKV / 128, CDIM / 32, NB), 256, 0, stream>>>(Wk, Wv, x, Kf, Vb);
    wcvt<<<(CDIM * CDIM + 255) / 256, 256, 0, stream>>>(Wproj, Wb, CDIM * CDIM);
    pf_kernel<<<2 * 64 * 32, 256, 0, stream>>>(Wx, Wy, PFX, PFY);
    meanx_kernel<<<NB * CDIM, 256, 0, stream>>>(x, MX);
    mixw2_kernel<<<1, 256, 0, stream>>>(Wq, MX, Wc, bc, MIXW);
    attn_v3<<<NB * HW / 16, 256, 0, stream>>>(Qf, Kf, PFX, PFY, MIXW, ATTNb);
    gemm_av_mfma<<<dim3(HW / 64, CDIM / 48, NB), 256, 0, stream>>>(Vb, ATTNb, MIDb);
    gemm_proj_mfma<<<dim3(HW / 256, CDIM / 16, NB), 256, 0, stream>>>(Wb, MIDb, bproj, x, gamma, out);
}

// Round 5
// 304.417 us; speedup vs baseline: 3.9281x; 1.3088x over previous
//
#include <hip/hip_runtime.h>
#include <math.h>

// n=2, C=288, h=w=64 -> hw=4096; kv stride 2 -> 32x32 -> pkv=1024; M=9 heads, d=32
#define NB     2
#define CDIM   288
#define HW     4096
#define PKV    1024
#define MHEAD  9
#define DHEAD  32

typedef __attribute__((ext_vector_type(8))) short bf16x8;
typedef __attribute__((ext_vector_type(4))) float f32x4;

__device__ inline unsigned short f2bf(float x) {
    unsigned int u = __float_as_uint(x);
    u = (u + 0x7fffu + ((u >> 16) & 1u)) >> 16;
    return (unsigned short)u;
}

// ---------------------------------------------------------------------------
// gemm_q: Qf[(n*9+m)*4096 + j][d] (bf16) = sum_c Wq[m*32+d][c] * X[n][c][j]
__global__ __launch_bounds__(256) void gemm_q(const float* __restrict__ W,
        const float* __restrict__ X, unsigned short* __restrict__ Qf) {
    int n  = blockIdx.z;
    int o0 = blockIdx.y * 32;
    int j0 = blockIdx.x * 128;
    int tid = threadIdx.x;
    int a = tid >> 5, b = tid & 31;
    __shared__ float Wt[16][36];
    __shared__ float Xt[16][128];
    const float* Xn = X + (size_t)n * CDIM * HW;
    float acc[4][4] = {};
    int wr = tid >> 3, wc = tid & 7;
    int xk = tid >> 4, xc = (tid & 15) * 8;
    for (int c0 = 0; c0 < CDIM; c0 += 16) {
        float2 wv = *(const float2*)&W[(o0 + wr) * CDIM + c0 + 2 * wc];
        Wt[2 * wc][wr] = wv.x; Wt[2 * wc + 1][wr] = wv.y;
        const float* xs = &Xn[(size_t)(c0 + xk) * HW + j0 + xc];
        *(float4*)&Xt[xk][xc]     = *(const float4*)&xs[0];
        *(float4*)&Xt[xk][xc + 4] = *(const float4*)&xs[4];
        __syncthreads();
#pragma unroll
        for (int kk = 0; kk < 16; ++kk) {
            float4 w4 = *(const float4*)&Wt[kk][4 * a];
            float4 x4 = *(const float4*)&Xt[kk][4 * b];
            acc[0][0] += w4.x * x4.x; acc[0][1] += w4.x * x4.y; acc[0][2] += w4.x * x4.z; acc[0][3] += w4.x * x4.w;
            acc[1][0] += w4.y * x4.x; acc[1][1] += w4.y * x4.y; acc[1][2] += w4.y * x4.z; acc[1][3] += w4.y * x4.w;
            acc[2][0] += w4.z * x4.x; acc[2][1] += w4.z * x4.y; acc[2][2] += w4.z * x4.z; acc[2][3] += w4.z * x4.w;
            acc[3][0] += w4.w * x4.x; acc[3][1] += w4.w * x4.y; acc[3][2] += w4.w * x4.z; acc[3][3] += w4.w * x4.w;
        }
        __syncthreads();
    }
#pragma unroll
    for (int i2 = 0; i2 < 4; ++i2) {
        int o = o0 + 4 * a + i2;
        int m = o >> 5, d = o & 31;
        size_t base = ((size_t)(n * MHEAD + m) * HW + j0 + 4 * b) * 32 + d;
#pragma unroll
        for (int jj = 0; jj < 4; ++jj)
            Qf[base + (size_t)jj * 32] = f2bf(acc[i2][jj]);
    }
}

// gemm_kv: Kf bf16 [(n*9+m)*1024 + p][d]; Vb bf16 [n][o][p]. x_kv gather.
__global__ __launch_bounds__(256) void gemm_kv(const float* __restrict__ Wk,
        const float* __restrict__ Wv, const float* __restrict__ X,
        unsigned short* __restrict__ Kf, unsigned short* __restrict__ Vb) {
    int n  = blockIdx.z;
    int o0 = blockIdx.y * 32;
    int j0 = blockIdx.x * 128;
    int tid = threadIdx.x;
    int a = tid >> 5, b = tid & 31;
    __shared__ float Wt[2][16][36];
    __shared__ float Xt[16][128];
    const float* Xn = X + (size_t)n * CDIM * HW;
    float acck[4][4] = {};
    float accv[4][4] = {};
    int wr = tid >> 3, wc = tid & 7;
    int xk = tid >> 4, xc = (tid & 15) * 8;
    for (int c0 = 0; c0 < CDIM; c0 += 16) {
        float2 kw = *(const float2*)&Wk[(o0 + wr) * CDIM + c0 + 2 * wc];
        float2 vw = *(const float2*)&Wv[(o0 + wr) * CDIM + c0 + 2 * wc];
        Wt[0][2 * wc][wr] = kw.x; Wt[0][2 * wc + 1][wr] = kw.y;
        Wt[1][2 * wc][wr] = vw.x; Wt[1][2 * wc + 1][wr] = vw.y;
        const float* xrow = &Xn[(size_t)(c0 + xk) * HW];
#pragma unroll
        for (int l = 0; l < 8; ++l) {
            int j = j0 + xc + l;
            int pos = ((j >> 5) << 7) + ((j & 31) << 1);
            Xt[xk][xc + l] = xrow[pos];
        }
        __syncthreads();
#pragma unroll
        for (int kk = 0; kk < 16; ++kk) {
            float4 k4 = *(const float4*)&Wt[0][kk][4 * a];
            float4 v4 = *(const float4*)&Wt[1][kk][4 * a];
            float4 x4 = *(const float4*)&Xt[kk][4 * b];
            acck[0][0] += k4.x * x4.x; acck[0][1] += k4.x * x4.y; acck[0][2] += k4.x * x4.z; acck[0][3] += k4.x * x4.w;
            acck[1][0] += k4.y * x4.x; acck[1][1] += k4.y * x4.y; acck[1][2] += k4.y * x4.z; acck[1][3] += k4.y * x4.w;
            acck[2][0] += k4.z * x4.x; acck[2][1] += k4.z * x4.y; acck[2][2] += k4.z * x4.z; acck[2][3] += k4.z * x4.w;
            acck[3][0] += k4.w * x4.x; acck[3][1] += k4.w * x4.y; acck[3][2] += k4.w * x4.z; acck[3][3] += k4.w * x4.w;
            accv[0][0] += v4.x * x4.x; accv[0][1] += v4.x * x4.y; accv[0][2] += v4.x * x4.z; accv[0][3] += v4.x * x4.w;
            accv[1][0] += v4.y * x4.x; accv[1][1] += v4.y * x4.y; accv[1][2] += v4.y * x4.z; accv[1][3] += v4.y * x4.w;
            accv[2][0] += v4.z * x4.x; accv[2][1] += v4.z * x4.y; accv[2][2] += v4.z * x4.z; accv[2][3] += v4.z * x4.w;
            accv[3][0] += v4.w * x4.x; accv[3][1] += v4.w * x4.y; accv[3][2] += v4.w * x4.z; accv[3][3] += v4.w * x4.w;
        }
        __syncthreads();
    }
#pragma unroll
    for (int i2 = 0; i2 < 4; ++i2) {
        int o = o0 + 4 * a + i2;
        int m = o >> 5, d = o & 31;
        size_t kbase = ((size_t)(n * MHEAD + m) * PKV + j0 + 4 * b) * 32 + d;
#pragma unroll
        for (int jj = 0; jj < 4; ++jj)
            Kf[kbase + (size_t)jj * 32] = f2bf(acck[i2][jj]);
        size_t vrow = ((size_t)(n * CDIM) + o) * PKV + j0 + 4 * b;
        ushort4 sv = { f2bf(accv[i2][0]), f2bf(accv[i2][1]), f2bf(accv[i2][2]), f2bf(accv[i2][3]) };
        *(ushort4*)&Vb[vrow] = sv;
    }
}

// ---------------------------------------------------------------------------
// gemm_av MFMA: MIDb[n][i][o] (bf16, o contig) = sum_p ATTNb[i][p] * Vb[o][p]
__global__ __launch_bounds__(256) void gemm_av_mfma(const unsigned short* __restrict__ Vb,
        const unsigned short* __restrict__ Ab, unsigned short* __restrict__ MIDb) {
    int n    = blockIdx.z;
    int o0   = blockIdx.y * 48;
    int i0   = blockIdx.x * 64 + (threadIdx.x >> 6) * 16;
    int lane = threadIdx.x & 63;
    int lq = lane & 15, quad = lane >> 4;
    const unsigned short* Arow = Ab + ((size_t)(n * HW) + i0 + lq) * PKV + quad * 8;
    const unsigned short* V0   = Vb + ((size_t)(n * CDIM) + o0 + lq) * PKV + quad * 8;
    f32x4 acc[3] = {};
#pragma unroll 2
    for (int p0 = 0; p0 < PKV; p0 += 32) {
        bf16x8 af = *(const bf16x8*)(Arow + p0);
        bf16x8 b0 = *(const bf16x8*)(V0 + p0);
        bf16x8 b1 = *(const bf16x8*)(V0 + (size_t)16 * PKV + p0);
        bf16x8 b2 = *(const bf16x8*)(V0 + (size_t)32 * PKV + p0);
        acc[0] = __builtin_amdgcn_mfma_f32_16x16x32_bf16(af, b0, acc[0], 0, 0, 0);
        acc[1] = __builtin_amdgcn_mfma_f32_16x16x32_bf16(af, b1, acc[1], 0, 0, 0);
        acc[2] = __builtin_amdgcn_mfma_f32_16x16x32_bf16(af, b2, acc[2], 0, 0, 0);
    }
#pragma unroll
    for (int ot = 0; ot < 3; ++ot)
#pragma unroll
        for (int r = 0; r < 4; ++r) {
            int i = i0 + quad * 4 + r;
            int o = o0 + ot * 16 + lq;
            MIDb[((size_t)(n * HW) + i) * CDIM + o] = f2bf(acc[ot][r]);
        }
}

// gemm_proj MFMA: OUT[n][o][j] = g*(sum_c Wb[o][c]*MIDb[j][c] + bproj[o]) + x[n][o][j]
__global__ __launch_bounds__(256) void gemm_proj_mfma(const unsigned short* __restrict__ Wb,
        const unsigned short* __restrict__ MIDb, const float* __restrict__ bproj,
        const float* __restrict__ x, const float* __restrict__ gamma,
        float* __restrict__ OUT) {
    int n    = blockIdx.z;
    int o0   = blockIdx.y * 16;
    int j0   = blockIdx.x * 256 + (threadIdx.x >> 6) * 64;
    int lane = threadIdx.x & 63;
    int lq = lane & 15, quad = lane >> 4;
    const unsigned short* Wrow = Wb + (size_t)(o0 + lq) * CDIM + quad * 8;
    const unsigned short* M0   = MIDb + ((size_t)(n * HW) + j0 + lq) * CDIM + quad * 8;
    f32x4 acc[4] = {};
#pragma unroll
    for (int c0 = 0; c0 < CDIM; c0 += 32) {
        bf16x8 af = *(const bf16x8*)(Wrow + c0);
        bf16x8 b0 = *(const bf16x8*)(M0 + c0);
        bf16x8 b1 = *(const bf16x8*)(M0 + (size_t)16 * CDIM + c0);
        bf16x8 b2 = *(const bf16x8*)(M0 + (size_t)32 * CDIM + c0);
        bf16x8 b3 = *(const bf16x8*)(M0 + (size_t)48 * CDIM + c0);
        acc[0] = __builtin_amdgcn_mfma_f32_16x16x32_bf16(af, b0, acc[0], 0, 0, 0);
        acc[1] = __builtin_amdgcn_mfma_f32_16x16x32_bf16(af, b1, acc[1], 0, 0, 0);
        acc[2] = __builtin_amdgcn_mfma_f32_16x16x32_bf16(af, b2, acc[2], 0, 0, 0);
        acc[3] = __builtin_amdgcn_mfma_f32_16x16x32_bf16(af, b3, acc[3], 0, 0, 0);
    }
    float g = gamma[0];
#pragma unroll
    for (int jt = 0; jt < 4; ++jt)
#pragma unroll
        for (int r = 0; r < 4; ++r) {
            int o = o0 + quad * 4 + r;
            size_t idx = ((size_t)(n * CDIM) + o) * HW + j0 + jt * 16 + lq;
            OUT[idx] = g * (acc[jt][r] + bproj[o]) + x[idx];
        }
}

// fp32 -> bf16 convert (for Wproj)
__global__ void wcvt(const float* __restrict__ W, unsigned short* __restrict__ Wb, int nEl) {
    int i = blockIdx.x * 256 + threadIdx.x;
    if (i < nEl) Wb[i] = f2bf(W[i]);
}

// ---------------------------------------------------------------------------
// Transpose Wx/Wy (288x144 -> 144x288) so pff reads coalesced.
__global__ void wtrans(const float* __restrict__ Wx, const float* __restrict__ Wy,
                       float* __restrict__ WTx, float* __restrict__ WTy) {
    __shared__ float t[16][17];
    const float* W = blockIdx.z ? Wy : Wx;
    float* WT      = blockIdx.z ? WTy : WTx;
    int f0 = blockIdx.x * 16, o0 = blockIdx.y * 16;
    int tx = threadIdx.x, ty = threadIdx.y;
    t[ty][tx] = W[(o0 + ty) * 144 + f0 + tx];
    __syncthreads();
    WT[(f0 + ty) * 288 + o0 + tx] = t[tx][ty];
}

// F[m][dif][d] = inv_sqrt2 * sum_f emb(dif-62)[f] * W[m*32+d][f]; 126 distinct diffs.
__global__ __launch_bounds__(320) void pff_kernel(const float* __restrict__ WTx,
        const float* __restrict__ WTy, float* __restrict__ FX, float* __restrict__ FY) {
    int blk  = blockIdx.x;          // 252: axis*126 + dif
    int axis = blk / 126;
    int dif  = blk % 126;
    __shared__ float emb[144];
    int tid = threadIdx.x;
    float diff = (float)(dif - 62);
    if (tid < 72) {
        float dm = expf(6.9077552789821368f * ((float)tid * (1.f / 72.f)));
        float t  = diff / dm;
        emb[tid]      = sinf(t);
        emb[72 + tid] = cosf(t);
    }
    __syncthreads();
    if (tid < 288) {
        const float* WT = axis ? WTy : WTx;
        float s = 0.f;
#pragma unroll 8
        for (int f = 0; f < 144; ++f) s += emb[f] * WT[f * 288 + tid];
        int m = tid >> 5, d = tid & 31;
        float* F = axis ? FY : FX;
        F[((size_t)m * 126 + dif) * 32 + d] = s * 0.70710678118654752f;
    }
}

// ---------------------------------------------------------------------------
// EX[n][m][i=(h,w)][v] = sum_d Q[i][d] * FX[m][w-2v+62][d]  (axis 0, g=w fixed)
// EY[n][m][i=(h,w)][u] = sum_d Q[i][d] * FY[m][h-2u+62][d]  (axis 1, g=h fixed)
__global__ __launch_bounds__(256) void exey_kernel(const unsigned short* __restrict__ Qf,
        const float* __restrict__ FX, const float* __restrict__ FY,
        float* __restrict__ EX, float* __restrict__ EY) {
    int axis = blockIdx.x >> 6;
    int g    = blockIdx.x & 63;
    int m    = blockIdx.y;
    int n    = blockIdx.z;
    int tid  = threadIdx.x;
    size_t Qbase = (size_t)(n * MHEAD + m) * HW;

    __shared__ float fS[32][36];        // fS[v][d] = F[m][g+62-2v][d]
    __shared__ unsigned int qSu[64][20]; // bf16-pair packed Q rows

    {   // stage F rows (32 rows x 32, float4 each thread)
        const float* F = axis ? FY : FX;
        int v = tid >> 3, d0 = (tid & 7) * 4;
        *(float4*)&fS[v][d0] = *(const float4*)&F[((size_t)m * 126 + g + 62 - 2 * v) * 32 + d0];
    }
#pragma unroll
    for (int l = 0; l < 4; ++l) {   // stage Q tile: 64 rows x 16 uints
        int idx = tid + l * 256;
        int r = idx >> 4, c = idx & 15;
        int i = axis ? (g * 64 + r) : (r * 64 + g);
        qSu[r][c] = *(const unsigned int*)&Qf[(Qbase + i) * 32 + 2 * c];
    }
    __syncthreads();

    int r  = tid >> 2;
    int vg = tid & 3;
    float qv[32];
#pragma unroll
    for (int k = 0; k < 4; ++k) {
        uint4 qa = *(const uint4*)&qSu[r][k * 4];
        unsigned int uu[4] = { qa.x, qa.y, qa.z, qa.w };
#pragma unroll
        for (int e = 0; e < 4; ++e) {
            qv[k * 8 + 2 * e]     = __uint_as_float(uu[e] << 16);
            qv[k * 8 + 2 * e + 1] = __uint_as_float(uu[e] & 0xffff0000u);
        }
    }
    float acc8[8] = {};
#pragma unroll
    for (int k4 = 0; k4 < 8; ++k4) {
        float qx = qv[4 * k4], qy = qv[4 * k4 + 1], qz = qv[4 * k4 + 2], qw = qv[4 * k4 + 3];
#pragma unroll
        for (int t = 0; t < 8; ++t) {
            float4 f4 = *(const float4*)&fS[vg * 8 + t][k4 * 4];
            acc8[t] += qx * f4.x + qy * f4.y + qz * f4.z + qw * f4.w;
        }
    }
    int i = axis ? (g * 64 + r) : (r * 64 + g);
    float* out = axis ? EY : EX;
    size_t obase = (Qbase + i) * 32 + vg * 8;
    float4 s0 = { acc8[0], acc8[1], acc8[2], acc8[3] };
    float4 s1 = { acc8[4], acc8[5], acc8[6], acc8[7] };
    *(float4*)&out[obase]     = s0;
    *(float4*)&out[obase + 4] = s1;
}

// ---------------------------------------------------------------------------
// meanx[n][c] = mean over hw of x   (context = Wq @ meanx, mean commutes)
__global__ void meanx_kernel(const float* __restrict__ X, float* __restrict__ MX) {
    int bid = blockIdx.x;
    const float* xr = X + (size_t)bid * HW;
    int tid = threadIdx.x;
    float s = 0.f;
    for (int j = tid; j < HW; j += 256) s += xr[j];
    for (int off = 32; off > 0; off >>= 1) s += __shfl_xor(s, off, 64);
    __shared__ float red[4];
    if ((tid & 63) == 0) red[tid >> 6] = s;
    __syncthreads();
    if (tid == 0) MX[bid] = (red[0] + red[1] + red[2] + red[3]) * (1.f / 4096.f);
}

// single block: ctx = Wq @ meanx; logits = ctx @ Wc^T + bc; softmax -> MIXW
__global__ void mixw2_kernel(const float* __restrict__ Wq, const float* __restrict__ MX,
                             const float* __restrict__ Wc, const float* __restrict__ bc,
                             float* __restrict__ MIXW) {
    __shared__ float ctx_s[NB * CDIM];
    __shared__ float lg[18];
    int tid = threadIdx.x;   // 256
    for (int p = tid; p < NB * CDIM; p += 256) {
        int n = p / CDIM, o = p % CDIM;
        const float* wr = Wq + (size_t)o * CDIM;
        const float* mx = MX + n * CDIM;
        float s = 0.f;
        for (int c = 0; c < CDIM; c += 4) {
            float4 w4 = *(const float4*)&wr[c];
            float4 m4 = *(const float4*)&mx[c];
            s += w4.x * m4.x + w4.y * m4.y + w4.z * m4.z + w4.w * m4.w;
        }
        ctx_s[p] = s;
    }
    __syncthreads();
    if (tid < 18) {
        int n = tid / 9, j = tid % 9;
        float s = bc[j];
        for (int o = 0; o < CDIM; ++o) s += ctx_s[n * CDIM + o] * Wc[j * CDIM + o];
        lg[tid] = s;
    }
    __syncthreads();
    if (tid < 2) {
        float mx = -1e30f;
        for (int j = 0; j < 9; ++j) mx = fmaxf(mx, lg[tid * 9 + j]);
        float e[9], sm = 0.f;
        for (int j = 0; j < 9; ++j) { e[j] = __expf(lg[tid * 9 + j] - mx); sm += e[j]; }
        for (int j = 0; j < 9; ++j) MIXW[tid * 9 + j] = e[j] / sm;
    }
}

// ---------------------------------------------------------------------------
// MFMA attention v4: 16 queries/block, 8 waves (wave = 128 kv), EX/EY precomputed.
__global__ __launch_bounds__(512, 4) void attn_v4(
        const unsigned short* __restrict__ Qf, const unsigned short* __restrict__ Kf,
        const float* __restrict__ EX, const float* __restrict__ EY,
        const float* __restrict__ MIXW, unsigned short* __restrict__ ATTNb) {
    int n    = blockIdx.x >> 8;
    int i0   = (blockIdx.x & 255) * 16;
    int tid  = threadIdx.x;
    int wv   = tid >> 6;          // 0..7
    int lane = tid & 63;
    int lq   = lane & 15;
    int quad = lane >> 4;

    __shared__ float ext_s[16][33];
    __shared__ float eyt_s[16][33];
    __shared__ float ws_s[8][16];
    __shared__ float ltot_s[16];

    float mixed[8][4];
#pragma unroll
    for (int t = 0; t < 8; ++t)
#pragma unroll
        for (int j = 0; j < 4; ++j) mixed[t][j] = 0.f;

    int sq = tid >> 5, sv = tid & 31;

    for (int m = 0; m < MHEAD; ++m) {
        const unsigned short* Qm = Qf + ((size_t)(n * MHEAD + m) * HW + i0) * 32;
        const unsigned short* Km = Kf + (size_t)(n * MHEAD + m) * PKV * 32;
        size_t ebase = ((size_t)(n * MHEAD + m) * HW + i0 + sq) * 32 + sv;
        __syncthreads();
        ext_s[sq][sv] = EX[ebase];
        eyt_s[sq][sv] = EY[ebase];
        __syncthreads();

        bf16x8 afrag = *(const bf16x8*)(Qm + (size_t)lq * 32 + quad * 8);
        float exA[4], exB[4];
#pragma unroll
        for (int j = 0; j < 4; ++j) {
            exA[j] = ext_s[quad * 4 + j][lq];
            exB[j] = ext_s[quad * 4 + j][16 + lq];
        }

        bf16x8 bf[8];
#pragma unroll
        for (int t = 0; t < 8; ++t)
            bf[t] = *(const bf16x8*)(Km + (size_t)(wv * 128 + t * 16 + lq) * 32 + quad * 8);
        f32x4 acc[8];
#pragma unroll
        for (int t = 0; t < 8; ++t) acc[t] = (f32x4){0.f, 0.f, 0.f, 0.f};
#pragma unroll
        for (int t = 0; t < 8; ++t)
            acc[t] = __builtin_amdgcn_mfma_f32_16x16x32_bf16(afrag, bf[t], acc[t], 0, 0, 0);

        float rs[4] = {0.f, 0.f, 0.f, 0.f};
#pragma unroll
        for (int t = 0; t < 8; ++t) {
            int u = wv * 4 + (t >> 1);
            bool hi = t & 1;
#pragma unroll
            for (int j = 0; j < 4; ++j) {
                float e = __expf(acc[t][j] + (hi ? exB[j] : exA[j]) + eyt_s[quad * 4 + j][u]);
                rs[j] += e;
                acc[t][j] = e;
            }
        }
#pragma unroll
        for (int j = 0; j < 4; ++j) {
            rs[j] += __shfl_xor(rs[j], 1, 64);
            rs[j] += __shfl_xor(rs[j], 2, 64);
            rs[j] += __shfl_xor(rs[j], 4, 64);
            rs[j] += __shfl_xor(rs[j], 8, 64);
        }
        if (lq == 0) {
#pragma unroll
            for (int j = 0; j < 4; ++j) ws_s[wv][quad * 4 + j] = rs[j];
        }
        __syncthreads();
        if (tid < 16) {
            float s = 0.f;
#pragma unroll
            for (int w = 0; w < 8; ++w) s += ws_s[w][tid];
            ltot_s[tid] = s;
        }
        __syncthreads();

        float wm = MIXW[n * MHEAD + m];
        float fct[4];
#pragma unroll
        for (int j = 0; j < 4; ++j) fct[j] = wm / ltot_s[quad * 4 + j];
#pragma unroll
        for (int t = 0; t < 8; ++t)
#pragma unroll
            for (int j = 0; j < 4; ++j) mixed[t][j] += acc[t][j] * fct[j];
    }

    unsigned short* An = ATTNb + ((size_t)n * HW + i0) * PKV;
#pragma unroll
    for (int j = 0; j < 4; ++j) {
        unsigned short* rp = An + (size_t)(quad * 4 + j) * PKV + wv * 128 + lq;
#pragma unroll
        for (int t = 0; t < 8; ++t) rp[t * 16] = f2bf(mixed[t][j]);
    }
}

// ---------------------------------------------------------------------------
extern "C" void kernel_launch(void* const* d_in, const int* in_sizes, int n_in,
                              void* d_out, int out_size, void* d_ws, size_t ws_size,
                              hipStream_t stream) {
    const float* x     = (const float*)d_in[0];
    const float* Wq    = (const float*)d_in[1];
    const float* Wk    = (const float*)d_in[2];
    const float* Wv    = (const float*)d_in[3];
    const float* Wx    = (const float*)d_in[4];
    const float* Wy    = (const float*)d_in[5];
    const float* Wproj = (const float*)d_in[6];
    const float* bproj = (const float*)d_in[7];
    const float* Wc    = (const float*)d_in[8];
    const float* bc    = (const float*)d_in[9];
    const float* gamma = (const float*)d_in[10];
    float* out = (float*)d_out;

    float* ws = (float*)d_ws;
    size_t off = 0;
    unsigned short* Qf = (unsigned short*)(ws + off); off += (size_t)NB * MHEAD * HW * 32 / 2;
    unsigned short* Kf = (unsigned short*)(ws + off); off += (size_t)NB * MHEAD * PKV * 32 / 2;
    unsigned short* Vb = (unsigned short*)(ws + off); off += (size_t)NB * CDIM * PKV / 2;
    unsigned short* Wb = (unsigned short*)(ws + off); off += (size_t)(CDIM * CDIM + 2) / 2;
    float* WTx  = ws + off; off += 144 * 288;
    float* WTy  = ws + off; off += 144 * 288;
    float* FX   = ws + off; off += (size_t)MHEAD * 126 * 32;
    float* FY   = ws + off; off += (size_t)MHEAD * 126 * 32;
    float* EX   = ws + off; off += (size_t)NB * MHEAD * HW * 32;
    float* EY   = ws + off; off += (size_t)NB * MHEAD * HW * 32;
    float* MX   = ws + off; off += NB * CDIM;
    float* MIXW = ws + off; off += 32;
    unsigned short* ATTNb = (unsigned short*)(ws + off); off += (size_t)NB * HW * PKV / 2;
    unsigned short* MIDb  = (unsigned short*)(ws + off); off += (size_t)NB * HW * CDIM / 2;

    wtrans<<<dim3(9, 18, 2), dim3(16, 16), 0, stream>>>(Wx, Wy, WTx, WTy);
    pff_kernel<<<252, 320, 0, stream>>>(WTx, WTy, FX, FY);
    gemm_q<<<dim3(HW / 128, CDIM / 32, NB), 256, 0, stream>>>(Wq, x, Qf);
    gemm_kv<<<dim3(PKV / 128, CDIM / 32, NB), 256, 0, stream>>>(Wk, Wv, x, Kf, Vb);
    wcvt<<<(CDIM * CDIM + 255) / 256, 256, 0, stream>>>(Wproj, Wb, CDIM * CDIM);
    meanx_kernel<<<NB * CDIM, 256, 0, stream>>>(x, MX);
    mixw2_kernel<<<1, 256, 0, stream>>>(Wq, MX, Wc, bc, MIXW);
    exey_kernel<<<dim3(128, MHEAD, NB), 256, 0, stream>>>(Qf, FX, FY, EX, EY);
    attn_v4<<<NB * HW / 16, 512, 0, stream>>>(Qf, Kf, EX, EY, MIXW, ATTNb);
    gemm_av_mfma<<<dim3(HW / 64, CDIM / 48, NB), 256, 0, stream>>>(Vb, ATTNb, MIDb);
    gemm_proj_mfma<<<dim3(HW / 256, CDIM / 16, NB), 256, 0, stream>>>(Wb, MIDb, bproj, x, gamma, out);
}

// Round 6
// 224.504 us; speedup vs baseline: 5.3263x; 1.3560x over previous
//
#include <hip/hip_runtime.h>
#include <math.h>

// n=2, C=288, h=w=64 -> hw=4096; kv stride 2 -> 32x32 -> pkv=1024; M=9 heads, d=32
#define NB     2
#define CDIM   288
#define HW     4096
#define PKV    1024
#define MHEAD  9
#define DHEAD  32

typedef __attribute__((ext_vector_type(8))) short bf16x8;
typedef __attribute__((ext_vector_type(4))) float f32x4;

__device__ inline unsigned short f2bf(float x) {
    unsigned int u = __float_as_uint(x);
    u = (u + 0x7fffu + ((u >> 16) & 1u)) >> 16;
    return (unsigned short)u;
}

// ---------------------------------------------------------------------------
// Fragment-major layout helpers (16x16x32 bf16 MFMA):
//  A/B frag: lane = (row&15) + 16*((k>>3)&3), elem = k&7; tile = 512 elems (1 KB).
//  KF per (n,m): tile pt=p>>4 (k-dim = d, 32 wide) -> base pt*512
//  VF per n:     tile (ot=o>>4, pc=p>>5) -> base (ot*32+pc)*512   (k-dim = p)
//  AF per n:     tile (it=i>>4, pc=p>>5) -> base (it*32+pc)*512   (k-dim = p)

// ---------------------------------------------------------------------------
// xtrans: x[n][c][j] fp32 -> XTb[n][j][c] bf16
__global__ __launch_bounds__(256) void xtrans(const float* __restrict__ X,
                                              unsigned short* __restrict__ XTb) {
    int n = blockIdx.z, j0 = blockIdx.x * 32, c0 = blockIdx.y * 32;
    __shared__ float t[32][33];
    int tx = threadIdx.x & 31, ty = threadIdx.x >> 5;
#pragma unroll
    for (int l = 0; l < 4; ++l) {
        int c = c0 + ty + l * 8;
        t[ty + l * 8][tx] = X[((size_t)n * CDIM + c) * HW + j0 + tx];
    }
    __syncthreads();
#pragma unroll
    for (int l = 0; l < 4; ++l) {
        int j = j0 + ty + l * 8;
        XTb[((size_t)n * HW + j) * CDIM + c0 + tx] = f2bf(t[tx][ty + l * 8]);
    }
}

// convert the four 288x288 weights to bf16
__global__ void wcvt4(const float* __restrict__ A, const float* __restrict__ B,
                      const float* __restrict__ C, const float* __restrict__ D,
                      unsigned short* __restrict__ oA, unsigned short* __restrict__ oB,
                      unsigned short* __restrict__ oC, unsigned short* __restrict__ oD) {
    int i = blockIdx.x * 256 + threadIdx.x;
    if (i < CDIM * CDIM) {
        oA[i] = f2bf(A[i]); oB[i] = f2bf(B[i]);
        oC[i] = f2bf(C[i]); oD[i] = f2bf(D[i]);
    }
}

// ---------------------------------------------------------------------------
// gemm_q MFMA: Qf[(n*9+m)*HW + j][d] = sum_c Wq[o=m*32+d][c] * XT[j][c]
__global__ __launch_bounds__(256) void gemm_q_mfma(const unsigned short* __restrict__ Wqb,
        const unsigned short* __restrict__ XTb, unsigned short* __restrict__ Qf) {
    int n    = blockIdx.z;
    int o0   = blockIdx.y * 16;
    int j0   = blockIdx.x * 256 + (threadIdx.x >> 6) * 64;
    int lane = threadIdx.x & 63;
    int lq = lane & 15, quad = lane >> 4;
    const unsigned short* Wrow = Wqb + (size_t)(o0 + lq) * CDIM + quad * 8;
    const unsigned short* X0   = XTb + ((size_t)n * HW + j0 + lq) * CDIM + quad * 8;
    f32x4 acc[4] = {};
#pragma unroll
    for (int c0 = 0; c0 < CDIM; c0 += 32) {
        bf16x8 af = *(const bf16x8*)(Wrow + c0);
        bf16x8 b0 = *(const bf16x8*)(X0 + c0);
        bf16x8 b1 = *(const bf16x8*)(X0 + (size_t)16 * CDIM + c0);
        bf16x8 b2 = *(const bf16x8*)(X0 + (size_t)32 * CDIM + c0);
        bf16x8 b3 = *(const bf16x8*)(X0 + (size_t)48 * CDIM + c0);
        acc[0] = __builtin_amdgcn_mfma_f32_16x16x32_bf16(af, b0, acc[0], 0, 0, 0);
        acc[1] = __builtin_amdgcn_mfma_f32_16x16x32_bf16(af, b1, acc[1], 0, 0, 0);
        acc[2] = __builtin_amdgcn_mfma_f32_16x16x32_bf16(af, b2, acc[2], 0, 0, 0);
        acc[3] = __builtin_amdgcn_mfma_f32_16x16x32_bf16(af, b3, acc[3], 0, 0, 0);
    }
#pragma unroll
    for (int jt = 0; jt < 4; ++jt)
#pragma unroll
        for (int r = 0; r < 4; ++r) {
            int o = o0 + quad * 4 + r;
            int m = o >> 5, d = o & 31;
            int j = j0 + jt * 16 + lq;
            Qf[((size_t)(n * MHEAD + m) * HW + j) * 32 + d] = f2bf(acc[jt][r]);
        }
}

// gemm_kv MFMA: K,V from gathered x_kv rows of XT. Outputs fragment-major KF, VF.
__global__ __launch_bounds__(256) void gemm_kv_mfma(const unsigned short* __restrict__ Wkb,
        const unsigned short* __restrict__ Wvb, const unsigned short* __restrict__ XTb,
        unsigned short* __restrict__ KF, unsigned short* __restrict__ VF) {
    int n    = blockIdx.z;
    int o0   = blockIdx.y * 16;
    int p0   = blockIdx.x * 256 + (threadIdx.x >> 6) * 64;
    int lane = threadIdx.x & 63;
    int lq = lane & 15, quad = lane >> 4;
    const unsigned short* Wkr = Wkb + (size_t)(o0 + lq) * CDIM + quad * 8;
    const unsigned short* Wvr = Wvb + (size_t)(o0 + lq) * CDIM + quad * 8;
    const unsigned short* Xr[4];
#pragma unroll
    for (int jt = 0; jt < 4; ++jt) {
        int p   = p0 + jt * 16 + lq;
        int pos = ((p >> 5) << 7) + ((p & 31) << 1);
        Xr[jt] = XTb + ((size_t)n * HW + pos) * CDIM + quad * 8;
    }
    f32x4 acck[4] = {};
    f32x4 accv[4] = {};
#pragma unroll
    for (int c0 = 0; c0 < CDIM; c0 += 32) {
        bf16x8 ak = *(const bf16x8*)(Wkr + c0);
        bf16x8 av = *(const bf16x8*)(Wvr + c0);
#pragma unroll
        for (int jt = 0; jt < 4; ++jt) {
            bf16x8 b = *(const bf16x8*)(Xr[jt] + c0);
            acck[jt] = __builtin_amdgcn_mfma_f32_16x16x32_bf16(ak, b, acck[jt], 0, 0, 0);
            accv[jt] = __builtin_amdgcn_mfma_f32_16x16x32_bf16(av, b, accv[jt], 0, 0, 0);
        }
    }
#pragma unroll
    for (int jt = 0; jt < 4; ++jt)
#pragma unroll
        for (int r = 0; r < 4; ++r) {
            int o = o0 + quad * 4 + r;
            int m = o >> 5, d = o & 31;
            int p = p0 + jt * 16 + lq;
            KF[(size_t)(n * MHEAD + m) * (PKV * 32) + (p >> 4) * 512
               + ((p & 15) + ((d >> 3) << 4)) * 8 + (d & 7)] = f2bf(acck[jt][r]);
            VF[(size_t)n * CDIM * PKV + (((o >> 4) * 32) + (p >> 5)) * 512
               + ((o & 15) + (((p >> 3) & 3) << 4)) * 8 + (p & 7)] = f2bf(accv[jt][r]);
        }
}

// ---------------------------------------------------------------------------
// gemm_av2: MIDb[n][i][o] = sum_p ATTN[i][p] * V[o][p]; all frag loads coalesced.
__global__ __launch_bounds__(256) void gemm_av2(const unsigned short* __restrict__ VF,
        const unsigned short* __restrict__ AF, unsigned short* __restrict__ MIDb) {
    int n    = blockIdx.z;
    int it   = blockIdx.x * 4 + (threadIdx.x >> 6);
    int og   = blockIdx.y * 3;
    int lane = threadIdx.x & 63;
    const unsigned short* An = AF + (size_t)n * HW * PKV + (size_t)it * 32 * 512 + lane * 8;
    const unsigned short* Vn = VF + (size_t)n * CDIM * PKV + lane * 8;
    f32x4 acc[3] = {};
#pragma unroll 4
    for (int pc = 0; pc < 32; ++pc) {
        bf16x8 af = *(const bf16x8*)(An + pc * 512);
        bf16x8 b0 = *(const bf16x8*)(Vn + (size_t)((og + 0) * 32 + pc) * 512);
        bf16x8 b1 = *(const bf16x8*)(Vn + (size_t)((og + 1) * 32 + pc) * 512);
        bf16x8 b2 = *(const bf16x8*)(Vn + (size_t)((og + 2) * 32 + pc) * 512);
        acc[0] = __builtin_amdgcn_mfma_f32_16x16x32_bf16(af, b0, acc[0], 0, 0, 0);
        acc[1] = __builtin_amdgcn_mfma_f32_16x16x32_bf16(af, b1, acc[1], 0, 0, 0);
        acc[2] = __builtin_amdgcn_mfma_f32_16x16x32_bf16(af, b2, acc[2], 0, 0, 0);
    }
    int lq = lane & 15, quad = lane >> 4;
#pragma unroll
    for (int ot = 0; ot < 3; ++ot)
#pragma unroll
        for (int r = 0; r < 4; ++r) {
            int i = it * 16 + quad * 4 + r;
            int o = (og + ot) * 16 + lq;
            MIDb[((size_t)n * HW + i) * CDIM + o] = f2bf(acc[ot][r]);
        }
}

// gemm_proj MFMA: OUT[n][o][j] = g*(sum_c Wb[o][c]*MIDb[j][c] + bproj[o]) + x[n][o][j]
__global__ __launch_bounds__(256) void gemm_proj_mfma(const unsigned short* __restrict__ Wb,
        const unsigned short* __restrict__ MIDb, const float* __restrict__ bproj,
        const float* __restrict__ x, const float* __restrict__ gamma,
        float* __restrict__ OUT) {
    int n    = blockIdx.z;
    int o0   = blockIdx.y * 16;
    int j0   = blockIdx.x * 256 + (threadIdx.x >> 6) * 64;
    int lane = threadIdx.x & 63;
    int lq = lane & 15, quad = lane >> 4;
    const unsigned short* Wrow = Wb + (size_t)(o0 + lq) * CDIM + quad * 8;
    const unsigned short* M0   = MIDb + ((size_t)(n * HW) + j0 + lq) * CDIM + quad * 8;
    f32x4 acc[4] = {};
#pragma unroll
    for (int c0 = 0; c0 < CDIM; c0 += 32) {
        bf16x8 af = *(const bf16x8*)(Wrow + c0);
        bf16x8 b0 = *(const bf16x8*)(M0 + c0);
        bf16x8 b1 = *(const bf16x8*)(M0 + (size_t)16 * CDIM + c0);
        bf16x8 b2 = *(const bf16x8*)(M0 + (size_t)32 * CDIM + c0);
        bf16x8 b3 = *(const bf16x8*)(M0 + (size_t)48 * CDIM + c0);
        acc[0] = __builtin_amdgcn_mfma_f32_16x16x32_bf16(af, b0, acc[0], 0, 0, 0);
        acc[1] = __builtin_amdgcn_mfma_f32_16x16x32_bf16(af, b1, acc[1], 0, 0, 0);
        acc[2] = __builtin_amdgcn_mfma_f32_16x16x32_bf16(af, b2, acc[2], 0, 0, 0);
        acc[3] = __builtin_amdgcn_mfma_f32_16x16x32_bf16(af, b3, acc[3], 0, 0, 0);
    }
    float g = gamma[0];
#pragma unroll
    for (int jt = 0; jt < 4; ++jt)
#pragma unroll
        for (int r = 0; r < 4; ++r) {
            int o = o0 + quad * 4 + r;
            size_t idx = ((size_t)(n * CDIM) + o) * HW + j0 + jt * 16 + lq;
            OUT[idx] = g * (acc[jt][r] + bproj[o]) + x[idx];
        }
}

// ---------------------------------------------------------------------------
// Transpose Wx/Wy (288x144 -> 144x288) so pff reads coalesced.
__global__ void wtrans(const float* __restrict__ Wx, const float* __restrict__ Wy,
                       float* __restrict__ WTx, float* __restrict__ WTy) {
    __shared__ float t[16][17];
    const float* W = blockIdx.z ? Wy : Wx;
    float* WT      = blockIdx.z ? WTy : WTx;
    int f0 = blockIdx.x * 16, o0 = blockIdx.y * 16;
    int tx = threadIdx.x, ty = threadIdx.y;
    t[ty][tx] = W[(o0 + ty) * 144 + f0 + tx];
    __syncthreads();
    WT[(f0 + ty) * 288 + o0 + tx] = t[tx][ty];
}

// F[m][dif][d] = inv_sqrt2 * sum_f emb(dif-62)[f] * W[m*32+d][f]; 126 distinct diffs.
__global__ __launch_bounds__(320) void pff_kernel(const float* __restrict__ WTx,
        const float* __restrict__ WTy, float* __restrict__ FX, float* __restrict__ FY) {
    int blk  = blockIdx.x;          // 252: axis*126 + dif
    int axis = blk / 126;
    int dif  = blk % 126;
    __shared__ float emb[144];
    int tid = threadIdx.x;
    float diff = (float)(dif - 62);
    if (tid < 72) {
        float dm = expf(6.9077552789821368f * ((float)tid * (1.f / 72.f)));
        float t  = diff / dm;
        emb[tid]      = sinf(t);
        emb[72 + tid] = cosf(t);
    }
    __syncthreads();
    if (tid < 288) {
        const float* WT = axis ? WTy : WTx;
        float s = 0.f;
#pragma unroll 8
        for (int f = 0; f < 144; ++f) s += emb[f] * WT[f * 288 + tid];
        int m = tid >> 5, d = tid & 31;
        float* F = axis ? FY : FX;
        F[((size_t)m * 126 + dif) * 32 + d] = s * 0.70710678118654752f;
    }
}

// ---------------------------------------------------------------------------
// EX/EY precompute (fp32), reading Qf[j][d] + F tables.
__global__ __launch_bounds__(256) void exey_kernel(const unsigned short* __restrict__ Qf,
        const float* __restrict__ FX, const float* __restrict__ FY,
        float* __restrict__ EX, float* __restrict__ EY) {
    int axis = blockIdx.x >> 6;
    int g    = blockIdx.x & 63;
    int m    = blockIdx.y;
    int n    = blockIdx.z;
    int tid  = threadIdx.x;
    size_t Qbase = (size_t)(n * MHEAD + m) * HW;

    __shared__ float fS[32][36];
    __shared__ unsigned int qSu[64][20];

    {
        const float* F = axis ? FY : FX;
        int v = tid >> 3, d0 = (tid & 7) * 4;
        *(float4*)&fS[v][d0] = *(const float4*)&F[((size_t)m * 126 + g + 62 - 2 * v) * 32 + d0];
    }
#pragma unroll
    for (int l = 0; l < 4; ++l) {
        int idx = tid + l * 256;
        int r = idx >> 4, c = idx & 15;
        int i = axis ? (g * 64 + r) : (r * 64 + g);
        qSu[r][c] = *(const unsigned int*)&Qf[(Qbase + i) * 32 + 2 * c];
    }
    __syncthreads();

    int r  = tid >> 2;
    int vg = tid & 3;
    float qv[32];
#pragma unroll
    for (int k = 0; k < 4; ++k) {
        uint4 qa = *(const uint4*)&qSu[r][k * 4];
        unsigned int uu[4] = { qa.x, qa.y, qa.z, qa.w };
#pragma unroll
        for (int e = 0; e < 4; ++e) {
            qv[k * 8 + 2 * e]     = __uint_as_float(uu[e] << 16);
            qv[k * 8 + 2 * e + 1] = __uint_as_float(uu[e] & 0xffff0000u);
        }
    }
    float acc8[8] = {};
#pragma unroll
    for (int k4 = 0; k4 < 8; ++k4) {
        float qx = qv[4 * k4], qy = qv[4 * k4 + 1], qz = qv[4 * k4 + 2], qw = qv[4 * k4 + 3];
#pragma unroll
        for (int t = 0; t < 8; ++t) {
            float4 f4 = *(const float4*)&fS[vg * 8 + t][k4 * 4];
            acc8[t] += qx * f4.x + qy * f4.y + qz * f4.z + qw * f4.w;
        }
    }
    int i = axis ? (g * 64 + r) : (r * 64 + g);
    float* out = axis ? EY : EX;
    size_t obase = (Qbase + i) * 32 + vg * 8;
    float4 s0 = { acc8[0], acc8[1], acc8[2], acc8[3] };
    float4 s1 = { acc8[4], acc8[5], acc8[6], acc8[7] };
    *(float4*)&out[obase]     = s0;
    *(float4*)&out[obase + 4] = s1;
}

// ---------------------------------------------------------------------------
__global__ void meanx_kernel(const float* __restrict__ X, float* __restrict__ MX) {
    int bid = blockIdx.x;
    const float* xr = X + (size_t)bid * HW;
    int tid = threadIdx.x;
    float s = 0.f;
    for (int j = tid; j < HW; j += 256) s += xr[j];
    for (int off = 32; off > 0; off >>= 1) s += __shfl_xor(s, off, 64);
    __shared__ float red[4];
    if ((tid & 63) == 0) red[tid >> 6] = s;
    __syncthreads();
    if (tid == 0) MX[bid] = (red[0] + red[1] + red[2] + red[3]) * (1.f / 4096.f);
}

__global__ void mixw2_kernel(const float* __restrict__ Wq, const float* __restrict__ MX,
                             const float* __restrict__ Wc, const float* __restrict__ bc,
                             float* __restrict__ MIXW) {
    __shared__ float ctx_s[NB * CDIM];
    __shared__ float lg[18];
    int tid = threadIdx.x;
    for (int p = tid; p < NB * CDIM; p += 256) {
        int n = p / CDIM, o = p % CDIM;
        const float* wr = Wq + (size_t)o * CDIM;
        const float* mx = MX + n * CDIM;
        float s = 0.f;
        for (int c = 0; c < CDIM; c += 4) {
            float4 w4 = *(const float4*)&wr[c];
            float4 m4 = *(const float4*)&mx[c];
            s += w4.x * m4.x + w4.y * m4.y + w4.z * m4.z + w4.w * m4.w;
        }
        ctx_s[p] = s;
    }
    __syncthreads();
    if (tid < 18) {
        int n = tid / 9, j = tid % 9;
        float s = bc[j];
        for (int o = 0; o < CDIM; ++o) s += ctx_s[n * CDIM + o] * Wc[j * CDIM + o];
        lg[tid] = s;
    }
    __syncthreads();
    if (tid < 2) {
        float mx = -1e30f;
        for (int j = 0; j < 9; ++j) mx = fmaxf(mx, lg[tid * 9 + j]);
        float e[9], sm = 0.f;
        for (int j = 0; j < 9; ++j) { e[j] = __expf(lg[tid * 9 + j] - mx); sm += e[j]; }
        for (int j = 0; j < 9; ++j) MIXW[tid * 9 + j] = e[j] / sm;
    }
}

// ---------------------------------------------------------------------------
// MFMA attention v5: 16 q/block, 8 waves, KF fragment-major (coalesced loads),
// epilogue LDS-transposes mixed rows into fragment-major AF.
__global__ __launch_bounds__(512, 4) void attn_v5(
        const unsigned short* __restrict__ Qf, const unsigned short* __restrict__ KF,
        const float* __restrict__ EX, const float* __restrict__ EY,
        const float* __restrict__ MIXW, unsigned short* __restrict__ AF) {
    int n    = blockIdx.x >> 8;
    int i0   = (blockIdx.x & 255) * 16;
    int tid  = threadIdx.x;
    int wv   = tid >> 6;          // 0..7
    int lane = tid & 63;
    int lq   = lane & 15;
    int quad = lane >> 4;

    __shared__ float ext_s[16][33];
    __shared__ float eyt_s[16][33];
    __shared__ float ws_s[8][16];
    __shared__ float ltot_s[16];
    __shared__ unsigned short tr[16][1032];   // padded: row stride 2064 B

    float mixed[8][4];
#pragma unroll
    for (int t = 0; t < 8; ++t)
#pragma unroll
        for (int j = 0; j < 4; ++j) mixed[t][j] = 0.f;

    int sq = tid >> 5, sv = tid & 31;

    for (int m = 0; m < MHEAD; ++m) {
        const unsigned short* Qm  = Qf + ((size_t)(n * MHEAD + m) * HW + i0) * 32;
        const unsigned short* KmF = KF + (size_t)(n * MHEAD + m) * (PKV * 32);
        size_t ebase = ((size_t)(n * MHEAD + m) * HW + i0 + sq) * 32 + sv;
        __syncthreads();
        ext_s[sq][sv] = EX[ebase];
        eyt_s[sq][sv] = EY[ebase];
        __syncthreads();

        bf16x8 afrag = *(const bf16x8*)(Qm + (size_t)lq * 32 + quad * 8);
        float exA[4], exB[4];
#pragma unroll
        for (int j = 0; j < 4; ++j) {
            exA[j] = ext_s[quad * 4 + j][lq];
            exB[j] = ext_s[quad * 4 + j][16 + lq];
        }

        bf16x8 bf[8];
#pragma unroll
        for (int t = 0; t < 8; ++t)
            bf[t] = *(const bf16x8*)(KmF + (size_t)(wv * 8 + t) * 512 + lane * 8);
        f32x4 acc[8];
#pragma unroll
        for (int t = 0; t < 8; ++t) acc[t] = (f32x4){0.f, 0.f, 0.f, 0.f};
#pragma unroll
        for (int t = 0; t < 8; ++t)
            acc[t] = __builtin_amdgcn_mfma_f32_16x16x32_bf16(afrag, bf[t], acc[t], 0, 0, 0);

        float rs[4] = {0.f, 0.f, 0.f, 0.f};
#pragma unroll
        for (int t = 0; t < 8; ++t) {
            int u = wv * 4 + (t >> 1);
            bool hi = t & 1;
#pragma unroll
            for (int j = 0; j < 4; ++j) {
                float e = __expf(acc[t][j] + (hi ? exB[j] : exA[j]) + eyt_s[quad * 4 + j][u]);
                rs[j] += e;
                acc[t][j] = e;
            }
        }
#pragma unroll
        for (int j = 0; j < 4; ++j) {
            rs[j] += __shfl_xor(rs[j], 1, 64);
            rs[j] += __shfl_xor(rs[j], 2, 64);
            rs[j] += __shfl_xor(rs[j], 4, 64);
            rs[j] += __shfl_xor(rs[j], 8, 64);
        }
        if (lq == 0) {
#pragma unroll
            for (int j = 0; j < 4; ++j) ws_s[wv][quad * 4 + j] = rs[j];
        }
        __syncthreads();
        if (tid < 16) {
            float s = 0.f;
#pragma unroll
            for (int w = 0; w < 8; ++w) s += ws_s[w][tid];
            ltot_s[tid] = s;
        }
        __syncthreads();

        float wm = MIXW[n * MHEAD + m];
        float fct[4];
#pragma unroll
        for (int j = 0; j < 4; ++j) fct[j] = wm / ltot_s[quad * 4 + j];
#pragma unroll
        for (int t = 0; t < 8; ++t)
#pragma unroll
            for (int j = 0; j < 4; ++j) mixed[t][j] += acc[t][j] * fct[j];
    }

    // --- epilogue: transpose C-layout rows into fragment-major AF tiles
#pragma unroll
    for (int t = 0; t < 8; ++t)
#pragma unroll
        for (int j = 0; j < 4; ++j)
            tr[quad * 4 + j][wv * 128 + t * 16 + lq] = f2bf(mixed[t][j]);
    __syncthreads();
    unsigned short* AFn = AF + (size_t)n * HW * PKV + (size_t)(i0 >> 4) * 32 * 512;
#pragma unroll
    for (int pc2 = 0; pc2 < 4; ++pc2) {
        int pc = wv * 4 + pc2;
        bf16x8 v = *(const bf16x8*)&tr[lane & 15][pc * 32 + (lane >> 4) * 8];
        *(bf16x8*)(AFn + (size_t)pc * 512 + lane * 8) = v;
    }
}

// ---------------------------------------------------------------------------
extern "C" void kernel_launch(void* const* d_in, const int* in_sizes, int n_in,
                              void* d_out, int out_size, void* d_ws, size_t ws_size,
                              hipStream_t stream) {
    const float* x     = (const float*)d_in[0];
    const float* Wq    = (const float*)d_in[1];
    const float* Wk    = (const float*)d_in[2];
    const float* Wv    = (const float*)d_in[3];
    const float* Wx    = (const float*)d_in[4];
    const float* Wy    = (const float*)d_in[5];
    const float* Wproj = (const float*)d_in[6];
    const float* bproj = (const float*)d_in[7];
    const float* Wc    = (const float*)d_in[8];
    const float* bc    = (const float*)d_in[9];
    const float* gamma = (const float*)d_in[10];
    float* out = (float*)d_out;

    float* ws = (float*)d_ws;
    size_t off = 0;
    unsigned short* Qf  = (unsigned short*)(ws + off); off += (size_t)NB * MHEAD * HW * 32 / 2;
    unsigned short* KF  = (unsigned short*)(ws + off); off += (size_t)NB * MHEAD * PKV * 32 / 2;
    unsigned short* VF  = (unsigned short*)(ws + off); off += (size_t)NB * CDIM * PKV / 2;
    unsigned short* Wqb = (unsigned short*)(ws + off); off += (size_t)CDIM * CDIM / 2;
    unsigned short* Wkb = (unsigned short*)(ws + off); off += (size_t)CDIM * CDIM / 2;
    unsigned short* Wvb = (unsigned short*)(ws + off); off += (size_t)CDIM * CDIM / 2;
    unsigned short* Wpb = (unsigned short*)(ws + off); off += (size_t)CDIM * CDIM / 2;
    unsigned short* XTb = (unsigned short*)(ws + off); off += (size_t)NB * HW * CDIM / 2;
    float* WTx  = ws + off; off += 144 * 288;
    float* WTy  = ws + off; off += 144 * 288;
    float* FX   = ws + off; off += (size_t)MHEAD * 126 * 32;
    float* FY   = ws + off; off += (size_t)MHEAD * 126 * 32;
    float* EX   = ws + off; off += (size_t)NB * MHEAD * HW * 32;
    float* EY   = ws + off; off += (size_t)NB * MHEAD * HW * 32;
    float* MX   = ws + off; off += NB * CDIM;
    float* MIXW = ws + off; off += 32;
    unsigned short* AF   = (unsigned short*)(ws + off); off += (size_t)NB * HW * PKV / 2;
    unsigned short* MIDb = (unsigned short*)(ws + off); off += (size_t)NB * HW * CDIM / 2;

    wcvt4<<<(CDIM * CDIM + 255) / 256, 256, 0, stream>>>(Wq, Wk, Wv, Wproj, Wqb, Wkb, Wvb, Wpb);
    xtrans<<<dim3(HW / 32, CDIM / 32, NB), 256, 0, stream>>>(x, XTb);
    wtrans<<<dim3(9, 18, 2), dim3(16, 16), 0, stream>>>(Wx, Wy, WTx, WTy);
    pff_kernel<<<252, 320, 0, stream>>>(WTx, WTy, FX, FY);
    gemm_q_mfma<<<dim3(HW / 256, CDIM / 16, NB), 256, 0, stream>>>(Wqb, XTb, Qf);
    gemm_kv_mfma<<<dim3(PKV / 256, CDIM / 16, NB), 256, 0, stream>>>(Wkb, Wvb, XTb, KF, VF);
    meanx_kernel<<<NB * CDIM, 256, 0, stream>>>(x, MX);
    mixw2_kernel<<<1, 256, 0, stream>>>(Wq, MX, Wc, bc, MIXW);
    exey_kernel<<<dim3(128, MHEAD, NB), 256, 0, stream>>>(Qf, FX, FY, EX, EY);
    attn_v5<<<NB * HW / 16, 512, 0, stream>>>(Qf, KF, EX, EY, MIXW, AF);
    gemm_av2<<<dim3(HW / 64, CDIM / 48, NB), 256, 0, stream>>>(VF, AF, MIDb);
    gemm_proj_mfma<<<dim3(HW / 256, CDIM / 16, NB), 256, 0, stream>>>(Wpb, MIDb, bproj, x, gamma, out);
}

// Round 7
// 212.619 us; speedup vs baseline: 5.6241x; 1.0559x over previous
//
#include <hip/hip_runtime.h>
#include <math.h>

// n=2, C=288, h=w=64 -> hw=4096; kv stride 2 -> 32x32 -> pkv=1024; M=9 heads, d=32
#define NB     2
#define CDIM   288
#define HW     4096
#define PKV    1024
#define MHEAD  9
#define DHEAD  32

typedef __attribute__((ext_vector_type(8))) short bf16x8;
typedef __attribute__((ext_vector_type(4))) float f32x4;

__device__ inline unsigned short f2bf(float x) {
    unsigned int u = __float_as_uint(x);
    u = (u + 0x7fffu + ((u >> 16) & 1u)) >> 16;
    return (unsigned short)u;
}

// ---------------------------------------------------------------------------
// Fragment-major tile (16 rows r, 32 k): elem(r,k) = ((r&15)+16*((k>>3)&3))*8 + (k&7)
// A wave's fragment load is then exactly `tilebase + lane*8` (1 KB contiguous).
//  WF  (A-side, rows=o, k=c):  tiles (ot=o>>4, cc=c>>5) -> (ot*9+cc)*512
//  XF  (B-side, rows=j, k=c):  per n, tiles (jt, cc)    -> (jt*9+cc)*512
//  KF  (B-side, rows=p, k=d):  per (n,m), tile pt       -> pt*512
//  VF  (B-side, rows=o, k=p):  per n, tiles (ot, pc)    -> (ot*32+pc)*512
//  AF  (A-side, rows=i, k=p):  per n, tiles (it, pc)    -> (it*32+pc)*512
//  MF  (B-side, rows=j, k=c):  per n, tiles (jt, cc)    -> (jt*9+cc)*512

// ---------------------------------------------------------------------------
// Convert 4 weight matrices (288x288 fp32 row-major) into fragment-major WF.
__global__ __launch_bounds__(64) void wcvtF(const float* __restrict__ A, const float* __restrict__ B,
        const float* __restrict__ C, const float* __restrict__ D,
        unsigned short* __restrict__ oA, unsigned short* __restrict__ oB,
        unsigned short* __restrict__ oC, unsigned short* __restrict__ oD) {
    int t  = blockIdx.x;                 // 162 tiles
    int ot = t / 9, cc = t % 9;
    const float* W = (blockIdx.y == 0) ? A : (blockIdx.y == 1) ? B : (blockIdx.y == 2) ? C : D;
    unsigned short* O = ((blockIdx.y == 0) ? oA : (blockIdx.y == 1) ? oB : (blockIdx.y == 2) ? oC : oD)
                        + (size_t)t * 512;
    int lane = threadIdx.x;
    int o  = ot * 16 + (lane & 15);
    int c0 = cc * 32 + (lane >> 4) * 8;
    const float* src = W + (size_t)o * CDIM + c0;
    float4 f0 = *(const float4*)src, f1 = *(const float4*)(src + 4);
    unsigned int v0 = f2bf(f0.x) | ((unsigned int)f2bf(f0.y) << 16);
    unsigned int v1 = f2bf(f0.z) | ((unsigned int)f2bf(f0.w) << 16);
    unsigned int v2 = f2bf(f1.x) | ((unsigned int)f2bf(f1.y) << 16);
    unsigned int v3 = f2bf(f1.z) | ((unsigned int)f2bf(f1.w) << 16);
    uint4 pk = { v0, v1, v2, v3 };
    *(uint4*)(O + lane * 8) = pk;
}

// x[n][c][j] fp32 -> XF fragment-major bf16 (B-side rows=j, k=c)
__global__ __launch_bounds__(256) void xtransF(const float* __restrict__ X,
                                               unsigned short* __restrict__ XF) {
    int n = blockIdx.z, j0 = blockIdx.x * 32, c0 = blockIdx.y * 32;
    __shared__ float t[32][33];
    int tx = threadIdx.x & 31, ty = threadIdx.x >> 5;    // ty 0..7
#pragma unroll
    for (int l = 0; l < 4; ++l) {
        int c = ty + l * 8;
        t[c][tx] = X[((size_t)n * CDIM + c0 + c) * HW + j0 + tx];
    }
    __syncthreads();
    int s = threadIdx.x >> 7;            // which j-tile (0/1)
    int u = threadIdx.x & 127;
    int lane = u >> 1, e0 = (u & 1) * 4;
    int jl = s * 16 + (lane & 15);
    int cb = (lane >> 4) * 8 + e0;
    unsigned int w0 = f2bf(t[cb + 0][jl]) | ((unsigned int)f2bf(t[cb + 1][jl]) << 16);
    unsigned int w1 = f2bf(t[cb + 2][jl]) | ((unsigned int)f2bf(t[cb + 3][jl]) << 16);
    int jt = (j0 >> 4) + s, cc = c0 >> 5;
    unsigned short* O = XF + (size_t)n * HW * CDIM + ((size_t)jt * 9 + cc) * 512 + lane * 8 + e0;
    uint2 pk = { w0, w1 };
    *(uint2*)O = pk;
}

// ---------------------------------------------------------------------------
// gemm_q_F: Qf[(n*9+m)*HW + j][d] = sum_c Wq[m*32+d][c] * X^T[j][c]. All frag
// loads coalesced; epilogue LDS-transpose -> full 64B-row Qf stores.
__global__ __launch_bounds__(256) void gemm_q_F(const unsigned short* __restrict__ WF,
        const unsigned short* __restrict__ XF, unsigned short* __restrict__ Qf) {
    int n  = blockIdx.z;
    int m  = blockIdx.y;                 // o0 = m*32
    int j0 = blockIdx.x * 128;
    int wv = threadIdx.x >> 6, lane = threadIdx.x & 63;
    int jw = j0 + wv * 32;
    const unsigned short* Wb = WF + ((size_t)(m * 2) * 9) * 512 + lane * 8;
    const unsigned short* Xb = XF + (size_t)n * HW * CDIM + ((size_t)(jw >> 4) * 9) * 512 + lane * 8;
    f32x4 acc[2][2] = {};
#pragma unroll
    for (int cc = 0; cc < 9; ++cc) {
        bf16x8 a0 = *(const bf16x8*)(Wb + (size_t)cc * 512);
        bf16x8 a1 = *(const bf16x8*)(Wb + (size_t)(9 + cc) * 512);
        bf16x8 b0 = *(const bf16x8*)(Xb + (size_t)cc * 512);
        bf16x8 b1 = *(const bf16x8*)(Xb + (size_t)(9 + cc) * 512);
        acc[0][0] = __builtin_amdgcn_mfma_f32_16x16x32_bf16(a0, b0, acc[0][0], 0, 0, 0);
        acc[0][1] = __builtin_amdgcn_mfma_f32_16x16x32_bf16(a0, b1, acc[0][1], 0, 0, 0);
        acc[1][0] = __builtin_amdgcn_mfma_f32_16x16x32_bf16(a1, b0, acc[1][0], 0, 0, 0);
        acc[1][1] = __builtin_amdgcn_mfma_f32_16x16x32_bf16(a1, b1, acc[1][1], 0, 0, 0);
    }
    __shared__ __attribute__((aligned(16))) unsigned short trq[4][32][40];
    int lq = lane & 15, quad = lane >> 4;
#pragma unroll
    for (int oi = 0; oi < 2; ++oi)
#pragma unroll
        for (int ji = 0; ji < 2; ++ji)
#pragma unroll
            for (int r = 0; r < 4; ++r)
                trq[wv][ji * 16 + lq][oi * 16 + quad * 4 + r] = f2bf(acc[oi][ji][r]);
    int jl = lane & 31, half = lane >> 5;
    bf16x8 v0 = *(const bf16x8*)&trq[wv][jl][half * 16];
    bf16x8 v1 = *(const bf16x8*)&trq[wv][jl][half * 16 + 8];
    unsigned short* Qm = Qf + ((size_t)(n * MHEAD + m) * HW + jw + jl) * 32 + half * 16;
    *(bf16x8*)Qm = v0;
    *(bf16x8*)(Qm + 8) = v1;
}

// gemm_kv_F: K,V projections; B rows gathered from XF (16B granules); outputs
// fragment-major KF (k=d) and VF (k=p) via LDS-transpose epilogues.
__global__ __launch_bounds__(256) void gemm_kv_F(const unsigned short* __restrict__ WkF,
        const unsigned short* __restrict__ WvF, const unsigned short* __restrict__ XF,
        unsigned short* __restrict__ KF, unsigned short* __restrict__ VF) {
    int n  = blockIdx.z;
    int m  = blockIdx.y;                 // o0 = m*32
    int p0 = blockIdx.x * 128;           // grid.x = 8
    int wv = threadIdx.x >> 6, lane = threadIdx.x & 63;
    int pw = p0 + wv * 32;
    int lq = lane & 15, quad = lane >> 4;
    const unsigned short* XFn = XF + (size_t)n * HW * CDIM;
    size_t bidx[2];
#pragma unroll
    for (int pi = 0; pi < 2; ++pi) {
        int p   = pw + pi * 16 + lq;
        int pos = ((p >> 5) << 7) + ((p & 31) << 1);
        bidx[pi] = ((size_t)(pos >> 4) * 9) * 512 + ((pos & 15) + 16 * quad) * 8;
    }
    const unsigned short* Wkb = WkF + ((size_t)(m * 2) * 9) * 512 + lane * 8;
    const unsigned short* Wvb = WvF + ((size_t)(m * 2) * 9) * 512 + lane * 8;
    f32x4 ak[2][2] = {}, av[2][2] = {};
#pragma unroll
    for (int cc = 0; cc < 9; ++cc) {
        bf16x8 a0k = *(const bf16x8*)(Wkb + (size_t)cc * 512);
        bf16x8 a1k = *(const bf16x8*)(Wkb + (size_t)(9 + cc) * 512);
        bf16x8 a0v = *(const bf16x8*)(Wvb + (size_t)cc * 512);
        bf16x8 a1v = *(const bf16x8*)(Wvb + (size_t)(9 + cc) * 512);
        bf16x8 b0  = *(const bf16x8*)(XFn + bidx[0] + (size_t)cc * 512);
        bf16x8 b1  = *(const bf16x8*)(XFn + bidx[1] + (size_t)cc * 512);
        ak[0][0] = __builtin_amdgcn_mfma_f32_16x16x32_bf16(a0k, b0, ak[0][0], 0, 0, 0);
        ak[0][1] = __builtin_amdgcn_mfma_f32_16x16x32_bf16(a0k, b1, ak[0][1], 0, 0, 0);
        ak[1][0] = __builtin_amdgcn_mfma_f32_16x16x32_bf16(a1k, b0, ak[1][0], 0, 0, 0);
        ak[1][1] = __builtin_amdgcn_mfma_f32_16x16x32_bf16(a1k, b1, ak[1][1], 0, 0, 0);
        av[0][0] = __builtin_amdgcn_mfma_f32_16x16x32_bf16(a0v, b0, av[0][0], 0, 0, 0);
        av[0][1] = __builtin_amdgcn_mfma_f32_16x16x32_bf16(a0v, b1, av[0][1], 0, 0, 0);
        av[1][0] = __builtin_amdgcn_mfma_f32_16x16x32_bf16(a1v, b0, av[1][0], 0, 0, 0);
        av[1][1] = __builtin_amdgcn_mfma_f32_16x16x32_bf16(a1v, b1, av[1][1], 0, 0, 0);
    }
    __shared__ __attribute__((aligned(16))) unsigned short tr[4][32][40];
    // --- K: tr[p_local][d]
#pragma unroll
    for (int oi = 0; oi < 2; ++oi)
#pragma unroll
        for (int pi = 0; pi < 2; ++pi)
#pragma unroll
            for (int r = 0; r < 4; ++r)
                tr[wv][pi * 16 + lq][oi * 16 + quad * 4 + r] = f2bf(ak[oi][pi][r]);
    unsigned short* KFm = KF + (size_t)(n * MHEAD + m) * (PKV * 32);
#pragma unroll
    for (int pi = 0; pi < 2; ++pi) {
        bf16x8 v = *(const bf16x8*)&tr[wv][pi * 16 + lq][quad * 8];
        *(bf16x8*)(KFm + (size_t)((pw >> 4) + pi) * 512 + lane * 8) = v;
    }
    // --- V: tr[o_local][p_local]  (reuse buffer; wave-local, no barrier needed)
#pragma unroll
    for (int oi = 0; oi < 2; ++oi)
#pragma unroll
        for (int pi = 0; pi < 2; ++pi)
#pragma unroll
            for (int r = 0; r < 4; ++r)
                tr[wv][oi * 16 + quad * 4 + r][pi * 16 + lq] = f2bf(av[oi][pi][r]);
    unsigned short* VFn = VF + (size_t)n * CDIM * PKV;
#pragma unroll
    for (int oi = 0; oi < 2; ++oi) {
        bf16x8 v = *(const bf16x8*)&tr[wv][oi * 16 + lq][quad * 8];
        *(bf16x8*)(VFn + (size_t)((m * 2 + oi) * 32 + (pw >> 5)) * 512 + lane * 8) = v;
    }
}

// ---------------------------------------------------------------------------
// gemm_av_F: MID = ATTN @ V^T -> MF fragment-major (rows=i, k=o).
__global__ __launch_bounds__(256) void gemm_av_F(const unsigned short* __restrict__ VF,
        const unsigned short* __restrict__ AF, unsigned short* __restrict__ MF) {
    int n  = blockIdx.z;
    int oc = blockIdx.y;                 // o0 = oc*32
    int wv = threadIdx.x >> 6, lane = threadIdx.x & 63;
    int it = blockIdx.x * 4 + wv;        // grid.x = 64
    const unsigned short* An = AF + (size_t)n * HW * PKV + (size_t)it * 32 * 512 + lane * 8;
    const unsigned short* Vn = VF + (size_t)n * CDIM * PKV + lane * 8;
    f32x4 acc[2] = {};
#pragma unroll 4
    for (int pc = 0; pc < 32; ++pc) {
        bf16x8 a  = *(const bf16x8*)(An + (size_t)pc * 512);
        bf16x8 b0 = *(const bf16x8*)(Vn + (size_t)((oc * 2 + 0) * 32 + pc) * 512);
        bf16x8 b1 = *(const bf16x8*)(Vn + (size_t)((oc * 2 + 1) * 32 + pc) * 512);
        acc[0] = __builtin_amdgcn_mfma_f32_16x16x32_bf16(a, b0, acc[0], 0, 0, 0);
        acc[1] = __builtin_amdgcn_mfma_f32_16x16x32_bf16(a, b1, acc[1], 0, 0, 0);
    }
    __shared__ __attribute__((aligned(16))) unsigned short trm[4][16][40];
    int lq = lane & 15, quad = lane >> 4;
#pragma unroll
    for (int oi = 0; oi < 2; ++oi)
#pragma unroll
        for (int r = 0; r < 4; ++r)
            trm[wv][quad * 4 + r][oi * 16 + lq] = f2bf(acc[oi][r]);
    bf16x8 v = *(const bf16x8*)&trm[wv][lq][quad * 8];
    unsigned short* O = MF + (size_t)n * HW * CDIM + ((size_t)it * 9 + oc) * 512 + lane * 8;
    *(bf16x8*)O = v;
}

// gemm_proj_F: OUT = gamma*(Wproj@MID + b) + x ; A=WFp, B=MF, all coalesced.
__global__ __launch_bounds__(256) void gemm_proj_F(const unsigned short* __restrict__ WFp,
        const unsigned short* __restrict__ MF, const float* __restrict__ bproj,
        const float* __restrict__ x, const float* __restrict__ gamma,
        float* __restrict__ OUT) {
    int n  = blockIdx.z;
    int o0 = blockIdx.y * 32;
    int j0 = blockIdx.x * 128;
    int wv = threadIdx.x >> 6, lane = threadIdx.x & 63;
    int jw = j0 + wv * 32;
    const unsigned short* Wb = WFp + ((size_t)(o0 >> 4) * 9) * 512 + lane * 8;
    const unsigned short* Mb = MF + (size_t)n * HW * CDIM + ((size_t)(jw >> 4) * 9) * 512 + lane * 8;
    f32x4 acc[2][2] = {};
#pragma unroll
    for (int cc = 0; cc < 9; ++cc) {
        bf16x8 a0 = *(const bf16x8*)(Wb + (size_t)cc * 512);
        bf16x8 a1 = *(const bf16x8*)(Wb + (size_t)(9 + cc) * 512);
        bf16x8 b0 = *(const bf16x8*)(Mb + (size_t)cc * 512);
        bf16x8 b1 = *(const bf16x8*)(Mb + (size_t)(9 + cc) * 512);
        acc[0][0] = __builtin_amdgcn_mfma_f32_16x16x32_bf16(a0, b0, acc[0][0], 0, 0, 0);
        acc[0][1] = __builtin_amdgcn_mfma_f32_16x16x32_bf16(a0, b1, acc[0][1], 0, 0, 0);
        acc[1][0] = __builtin_amdgcn_mfma_f32_16x16x32_bf16(a1, b0, acc[1][0], 0, 0, 0);
        acc[1][1] = __builtin_amdgcn_mfma_f32_16x16x32_bf16(a1, b1, acc[1][1], 0, 0, 0);
    }
    float g = gamma[0];
    int lq = lane & 15, quad = lane >> 4;
#pragma unroll
    for (int oi = 0; oi < 2; ++oi)
#pragma unroll
        for (int ji = 0; ji < 2; ++ji)
#pragma unroll
            for (int r = 0; r < 4; ++r) {
                int o = o0 + oi * 16 + quad * 4 + r;
                size_t idx = ((size_t)(n * CDIM) + o) * HW + jw + ji * 16 + lq;
                OUT[idx] = g * (acc[oi][ji][r] + bproj[o]) + x[idx];
            }
}

// ---------------------------------------------------------------------------
// Transpose Wx/Wy (288x144 -> 144x288) so pff reads coalesced.
__global__ void wtrans(const float* __restrict__ Wx, const float* __restrict__ Wy,
                       float* __restrict__ WTx, float* __restrict__ WTy) {
    __shared__ float t[16][17];
    const float* W = blockIdx.z ? Wy : Wx;
    float* WT      = blockIdx.z ? WTy : WTx;
    int f0 = blockIdx.x * 16, o0 = blockIdx.y * 16;
    int tx = threadIdx.x, ty = threadIdx.y;
    t[ty][tx] = W[(o0 + ty) * 144 + f0 + tx];
    __syncthreads();
    WT[(f0 + ty) * 288 + o0 + tx] = t[tx][ty];
}

// F[m][dif][d] = inv_sqrt2 * sum_f emb(dif-62)[f] * W[m*32+d][f]; 126 distinct diffs.
__global__ __launch_bounds__(320) void pff_kernel(const float* __restrict__ WTx,
        const float* __restrict__ WTy, float* __restrict__ FX, float* __restrict__ FY) {
    int blk  = blockIdx.x;          // 252: axis*126 + dif
    int axis = blk / 126;
    int dif  = blk % 126;
    __shared__ float emb[144];
    int tid = threadIdx.x;
    float diff = (float)(dif - 62);
    if (tid < 72) {
        float dm = expf(6.9077552789821368f * ((float)tid * (1.f / 72.f)));
        float t  = diff / dm;
        emb[tid]      = sinf(t);
        emb[72 + tid] = cosf(t);
    }
    __syncthreads();
    if (tid < 288) {
        const float* WT = axis ? WTy : WTx;
        float s = 0.f;
#pragma unroll 8
        for (int f = 0; f < 144; ++f) s += emb[f] * WT[f * 288 + tid];
        int m = tid >> 5, d = tid & 31;
        float* F = axis ? FY : FX;
        F[((size_t)m * 126 + dif) * 32 + d] = s * 0.70710678118654752f;
    }
}

// ---------------------------------------------------------------------------
// EX/EY precompute (fp32), reading Qf[j][d] + F tables.
__global__ __launch_bounds__(256) void exey_kernel(const unsigned short* __restrict__ Qf,
        const float* __restrict__ FX, const float* __restrict__ FY,
        float* __restrict__ EX, float* __restrict__ EY) {
    int axis = blockIdx.x >> 6;
    int g    = blockIdx.x & 63;
    int m    = blockIdx.y;
    int n    = blockIdx.z;
    int tid  = threadIdx.x;
    size_t Qbase = (size_t)(n * MHEAD + m) * HW;

    __shared__ float fS[32][36];
    __shared__ unsigned int qSu[64][20];

    {
        const float* F = axis ? FY : FX;
        int v = tid >> 3, d0 = (tid & 7) * 4;
        *(float4*)&fS[v][d0] = *(const float4*)&F[((size_t)m * 126 + g + 62 - 2 * v) * 32 + d0];
    }
#pragma unroll
    for (int l = 0; l < 4; ++l) {
        int idx = tid + l * 256;
        int r = idx >> 4, c = idx & 15;
        int i = axis ? (g * 64 + r) : (r * 64 + g);
        qSu[r][c] = *(const unsigned int*)&Qf[(Qbase + i) * 32 + 2 * c];
    }
    __syncthreads();

    int r  = tid >> 2;
    int vg = tid & 3;
    float qv[32];
#pragma unroll
    for (int k = 0; k < 4; ++k) {
        uint4 qa = *(const uint4*)&qSu[r][k * 4];
        unsigned int uu[4] = { qa.x, qa.y, qa.z, qa.w };
#pragma unroll
        for (int e = 0; e < 4; ++e) {
            qv[k * 8 + 2 * e]     = __uint_as_float(uu[e] << 16);
            qv[k * 8 + 2 * e + 1] = __uint_as_float(uu[e] & 0xffff0000u);
        }
    }
    float acc8[8] = {};
#pragma unroll
    for (int k4 = 0; k4 < 8; ++k4) {
        float qx = qv[4 * k4], qy = qv[4 * k4 + 1], qz = qv[4 * k4 + 2], qw = qv[4 * k4 + 3];
#pragma unroll
        for (int t = 0; t < 8; ++t) {
            float4 f4 = *(const float4*)&fS[vg * 8 + t][k4 * 4];
            acc8[t] += qx * f4.x + qy * f4.y + qz * f4.z + qw * f4.w;
        }
    }
    int i = axis ? (g * 64 + r) : (r * 64 + g);
    float* out = axis ? EY : EX;
    size_t obase = (Qbase + i) * 32 + vg * 8;
    float4 s0 = { acc8[0], acc8[1], acc8[2], acc8[3] };
    float4 s1 = { acc8[4], acc8[5], acc8[6], acc8[7] };
    *(float4*)&out[obase]     = s0;
    *(float4*)&out[obase + 4] = s1;
}

// ---------------------------------------------------------------------------
__global__ void meanx_kernel(const float* __restrict__ X, float* __restrict__ MX) {
    int bid = blockIdx.x;
    const float* xr = X + (size_t)bid * HW;
    int tid = threadIdx.x;
    float s = 0.f;
    for (int j = tid; j < HW; j += 256) s += xr[j];
    for (int off = 32; off > 0; off >>= 1) s += __shfl_xor(s, off, 64);
    __shared__ float red[4];
    if ((tid & 63) == 0) red[tid >> 6] = s;
    __syncthreads();
    if (tid == 0) MX[bid] = (red[0] + red[1] + red[2] + red[3]) * (1.f / 4096.f);
}

__global__ void mixw2_kernel(const float* __restrict__ Wq, const float* __restrict__ MX,
                             const float* __restrict__ Wc, const float* __restrict__ bc,
                             float* __restrict__ MIXW) {
    __shared__ float ctx_s[NB * CDIM];
    __shared__ float lg[18];
    int tid = threadIdx.x;
    for (int p = tid; p < NB * CDIM; p += 256) {
        int n = p / CDIM, o = p % CDIM;
        const float* wr = Wq + (size_t)o * CDIM;
        const float* mx = MX + n * CDIM;
        float s = 0.f;
        for (int c = 0; c < CDIM; c += 4) {
            float4 w4 = *(const float4*)&wr[c];
            float4 m4 = *(const float4*)&mx[c];
            s += w4.x * m4.x + w4.y * m4.y + w4.z * m4.z + w4.w * m4.w;
        }
        ctx_s[p] = s;
    }
    __syncthreads();
    if (tid < 18) {
        int n = tid / 9, j = tid % 9;
        float s = bc[j];
        for (int o = 0; o < CDIM; ++o) s += ctx_s[n * CDIM + o] * Wc[j * CDIM + o];
        lg[tid] = s;
    }
    __syncthreads();
    if (tid < 2) {
        float mx = -1e30f;
        for (int j = 0; j < 9; ++j) mx = fmaxf(mx, lg[tid * 9 + j]);
        float e[9], sm = 0.f;
        for (int j = 0; j < 9; ++j) { e[j] = __expf(lg[tid * 9 + j] - mx); sm += e[j]; }
        for (int j = 0; j < 9; ++j) MIXW[tid * 9 + j] = e[j] / sm;
    }
}

// ---------------------------------------------------------------------------
// MFMA attention v5: 16 q/block, 8 waves, KF fragment-major (coalesced loads),
// epilogue LDS-transposes mixed rows into fragment-major AF.
__global__ __launch_bounds__(512, 4) void attn_v5(
        const unsigned short* __restrict__ Qf, const unsigned short* __restrict__ KF,
        const float* __restrict__ EX, const float* __restrict__ EY,
        const float* __restrict__ MIXW, unsigned short* __restrict__ AF) {
    int n    = blockIdx.x >> 8;
    int i0   = (blockIdx.x & 255) * 16;
    int tid  = threadIdx.x;
    int wv   = tid >> 6;          // 0..7
    int lane = tid & 63;
    int lq   = lane & 15;
    int quad = lane >> 4;

    __shared__ float ext_s[16][33];
    __shared__ float eyt_s[16][33];
    __shared__ float ws_s[8][16];
    __shared__ float ltot_s[16];
    __shared__ __attribute__((aligned(16))) unsigned short tr[16][1032];

    float mixed[8][4];
#pragma unroll
    for (int t = 0; t < 8; ++t)
#pragma unroll
        for (int j = 0; j < 4; ++j) mixed[t][j] = 0.f;

    int sq = tid >> 5, sv = tid & 31;

    for (int m = 0; m < MHEAD; ++m) {
        const unsigned short* Qm  = Qf + ((size_t)(n * MHEAD + m) * HW + i0) * 32;
        const unsigned short* KmF = KF + (size_t)(n * MHEAD + m) * (PKV * 32);
        size_t ebase = ((size_t)(n * MHEAD + m) * HW + i0 + sq) * 32 + sv;
        __syncthreads();
        ext_s[sq][sv] = EX[ebase];
        eyt_s[sq][sv] = EY[ebase];
        __syncthreads();

        bf16x8 afrag = *(const bf16x8*)(Qm + (size_t)lq * 32 + quad * 8);
        float exA[4], exB[4];
#pragma unroll
        for (int j = 0; j < 4; ++j) {
            exA[j] = ext_s[quad * 4 + j][lq];
            exB[j] = ext_s[quad * 4 + j][16 + lq];
        }

        bf16x8 bf[8];
#pragma unroll
        for (int t = 0; t < 8; ++t)
            bf[t] = *(const bf16x8*)(KmF + (size_t)(wv * 8 + t) * 512 + lane * 8);
        f32x4 acc[8];
#pragma unroll
        for (int t = 0; t < 8; ++t) acc[t] = (f32x4){0.f, 0.f, 0.f, 0.f};
#pragma unroll
        for (int t = 0; t < 8; ++t)
            acc[t] = __builtin_amdgcn_mfma_f32_16x16x32_bf16(afrag, bf[t], acc[t], 0, 0, 0);

        float rs[4] = {0.f, 0.f, 0.f, 0.f};
#pragma unroll
        for (int t = 0; t < 8; ++t) {
            int u = wv * 4 + (t >> 1);
            bool hi = t & 1;
#pragma unroll
            for (int j = 0; j < 4; ++j) {
                float e = __expf(acc[t][j] + (hi ? exB[j] : exA[j]) + eyt_s[quad * 4 + j][u]);
                rs[j] += e;
                acc[t][j] = e;
            }
        }
#pragma unroll
        for (int j = 0; j < 4; ++j) {
            rs[j] += __shfl_xor(rs[j], 1, 64);
            rs[j] += __shfl_xor(rs[j], 2, 64);
            rs[j] += __shfl_xor(rs[j], 4, 64);
            rs[j] += __shfl_xor(rs[j], 8, 64);
        }
        if (lq == 0) {
#pragma unroll
            for (int j = 0; j < 4; ++j) ws_s[wv][quad * 4 + j] = rs[j];
        }
        __syncthreads();
        if (tid < 16) {
            float s = 0.f;
#pragma unroll
            for (int w = 0; w < 8; ++w) s += ws_s[w][tid];
            ltot_s[tid] = s;
        }
        __syncthreads();

        float wm = MIXW[n * MHEAD + m];
        float fct[4];
#pragma unroll
        for (int j = 0; j < 4; ++j) fct[j] = wm / ltot_s[quad * 4 + j];
#pragma unroll
        for (int t = 0; t < 8; ++t)
#pragma unroll
            for (int j = 0; j < 4; ++j) mixed[t][j] += acc[t][j] * fct[j];
    }

    // --- epilogue: transpose C-layout rows into fragment-major AF tiles
#pragma unroll
    for (int t = 0; t < 8; ++t)
#pragma unroll
        for (int j = 0; j < 4; ++j)
            tr[quad * 4 + j][wv * 128 + t * 16 + lq] = f2bf(mixed[t][j]);
    __syncthreads();
    unsigned short* AFn = AF + (size_t)n * HW * PKV + (size_t)(i0 >> 4) * 32 * 512;
#pragma unroll
    for (int pc2 = 0; pc2 < 4; ++pc2) {
        int pc = wv * 4 + pc2;
        bf16x8 v = *(const bf16x8*)&tr[lane & 15][pc * 32 + (lane >> 4) * 8];
        *(bf16x8*)(AFn + (size_t)pc * 512 + lane * 8) = v;
    }
}

// ---------------------------------------------------------------------------
extern "C" void kernel_launch(void* const* d_in, const int* in_sizes, int n_in,
                              void* d_out, int out_size, void* d_ws, size_t ws_size,
                              hipStream_t stream) {
    const float* x     = (const float*)d_in[0];
    const float* Wq    = (const float*)d_in[1];
    const float* Wk    = (const float*)d_in[2];
    const float* Wv    = (const float*)d_in[3];
    const float* Wx    = (const float*)d_in[4];
    const float* Wy    = (const float*)d_in[5];
    const float* Wproj = (const float*)d_in[6];
    const float* bproj = (const float*)d_in[7];
    const float* Wc    = (const float*)d_in[8];
    const float* bc    = (const float*)d_in[9];
    const float* gamma = (const float*)d_in[10];
    float* out = (float*)d_out;

    float* ws = (float*)d_ws;
    size_t off = 0;
    unsigned short* Qf  = (unsigned short*)(ws + off); off += (size_t)NB * MHEAD * HW * 32 / 2;
    unsigned short* KF  = (unsigned short*)(ws + off); off += (size_t)NB * MHEAD * PKV * 32 / 2;
    unsigned short* VF  = (unsigned short*)(ws + off); off += (size_t)NB * CDIM * PKV / 2;
    unsigned short* WFq = (unsigned short*)(ws + off); off += (size_t)CDIM * CDIM / 2;
    unsigned short* WFk = (unsigned short*)(ws + off); off += (size_t)CDIM * CDIM / 2;
    unsigned short* WFv = (unsigned short*)(ws + off); off += (size_t)CDIM * CDIM / 2;
    unsigned short* WFp = (unsigned short*)(ws + off); off += (size_t)CDIM * CDIM / 2;
    unsigned short* XF  = (unsigned short*)(ws + off); off += (size_t)NB * HW * CDIM / 2;
    float* WTx  = ws + off; off += 144 * 288;
    float* WTy  = ws + off; off += 144 * 288;
    float* FX   = ws + off; off += (size_t)MHEAD * 126 * 32;
    float* FY   = ws + off; off += (size_t)MHEAD * 126 * 32;
    float* EX   = ws + off; off += (size_t)NB * MHEAD * HW * 32;
    float* EY   = ws + off; off += (size_t)NB * MHEAD * HW * 32;
    float* MX   = ws + off; off += NB * CDIM;
    float* MIXW = ws + off; off += 32;
    unsigned short* AF = (unsigned short*)(ws + off); off += (size_t)NB * HW * PKV / 2;
    unsigned short* MF = (unsigned short*)(ws + off); off += (size_t)NB * HW * CDIM / 2;

    wcvtF<<<dim3(162, 4), 64, 0, stream>>>(Wq, Wk, Wv, Wproj, WFq, WFk, WFv, WFp);
    xtransF<<<dim3(HW / 32, CDIM / 32, NB), 256, 0, stream>>>(x, XF);
    wtrans<<<dim3(9, 18, 2), dim3(16, 16), 0, stream>>>(Wx, Wy, WTx, WTy);
    pff_kernel<<<252, 320, 0, stream>>>(WTx, WTy, FX, FY);
    gemm_q_F<<<dim3(HW / 128, CDIM / 32, NB), 256, 0, stream>>>(WFq, XF, Qf);
    gemm_kv_F<<<dim3(PKV / 128, CDIM / 32, NB), 256, 0, stream>>>(WFk, WFv, XF, KF, VF);
    meanx_kernel<<<NB * CDIM, 256, 0, stream>>>(x, MX);
    mixw2_kernel<<<1, 256, 0, stream>>>(Wq, MX, Wc, bc, MIXW);
    exey_kernel<<<dim3(128, MHEAD, NB), 256, 0, stream>>>(Qf, FX, FY, EX, EY);
    attn_v5<<<NB * HW / 16, 512, 0, stream>>>(Qf, KF, EX, EY, MIXW, AF);
    gemm_av_F<<<dim3(HW / 64, CDIM / 32, NB), 256, 0, stream>>>(VF, AF, MF);
    gemm_proj_F<<<dim3(HW / 128, CDIM / 32, NB), 256, 0, stream>>>(WFp, MF, bproj, x, gamma, out);
}

// Round 8
// 205.137 us; speedup vs baseline: 5.8292x; 1.0365x over previous
//
#include <hip/hip_runtime.h>
#include <math.h>

// n=2, C=288, h=w=64 -> hw=4096; kv stride 2 -> 32x32 -> pkv=1024; M=9 heads, d=32
#define NB     2
#define CDIM   288
#define HW     4096
#define PKV    1024
#define MHEAD  9
#define DHEAD  32

typedef __attribute__((ext_vector_type(8))) short bf16x8;
typedef __attribute__((ext_vector_type(4))) float f32x4;

__device__ inline unsigned short f2bf(float x) {
    unsigned int u = __float_as_uint(x);
    u = (u + 0x7fffu + ((u >> 16) & 1u)) >> 16;
    return (unsigned short)u;
}

// ---------------------------------------------------------------------------
// Fragment-major tile (16 rows r, 32 k): elem(r,k) = ((r&15)+16*((k>>3)&3))*8 + (k&7)
//  WF (A-side, rows=o, k=c): tiles (ot,cc) -> (ot*9+cc)*512
//  XF (B-side, rows=j, k=c): per n, (jt,cc) -> (jt*9+cc)*512
//  KF (B-side, rows=p, k=d): per (n,m), pt -> pt*512
//  VF (B-side, rows=o, k=p): per n, (ot,pc) -> (ot*32+pc)*512

// ---------------------------------------------------------------------------
// prep: fused xtransF + wtrans + wcvtF + meanx (all depend only on inputs)
__global__ __launch_bounds__(256) void prep(const float* __restrict__ X,
        const float* __restrict__ Wq, const float* __restrict__ Wk,
        const float* __restrict__ Wv, const float* __restrict__ Wproj,
        const float* __restrict__ Wx, const float* __restrict__ Wy,
        unsigned short* __restrict__ XF, unsigned short* __restrict__ WFq,
        unsigned short* __restrict__ WFk, unsigned short* __restrict__ WFv,
        unsigned short* __restrict__ WFp, float* __restrict__ WTx,
        float* __restrict__ WTy, float* __restrict__ MX) {
    __shared__ float t32[32][33];
    __shared__ float t16[16][17];
    __shared__ float red[4];
    int b = blockIdx.x;
    int tid = threadIdx.x;
    if (b < 2304) {
        // ---- xtransF: x[n][c][j] -> XF fragment-major bf16
        int bx = b % 128, by = (b / 128) % 9, n = b / 1152;
        int j0 = bx * 32, c0 = by * 32;
        int tx = tid & 31, ty = tid >> 5;
#pragma unroll
        for (int l = 0; l < 4; ++l) {
            int c = ty + l * 8;
            t32[c][tx] = X[((size_t)n * CDIM + c0 + c) * HW + j0 + tx];
        }
        __syncthreads();
        int s = tid >> 7;
        int u = tid & 127;
        int lane = u >> 1, e0 = (u & 1) * 4;
        int jl = s * 16 + (lane & 15);
        int cb = (lane >> 4) * 8 + e0;
        unsigned int w0 = f2bf(t32[cb + 0][jl]) | ((unsigned int)f2bf(t32[cb + 1][jl]) << 16);
        unsigned int w1 = f2bf(t32[cb + 2][jl]) | ((unsigned int)f2bf(t32[cb + 3][jl]) << 16);
        int jt = (j0 >> 4) + s, cc = c0 >> 5;
        unsigned short* O = XF + (size_t)n * HW * CDIM + ((size_t)jt * 9 + cc) * 512 + lane * 8 + e0;
        uint2 pk = { w0, w1 };
        *(uint2*)O = pk;
    } else if (b < 2628) {
        // ---- wtrans: Wx/Wy (288x144) -> WT (144x288)
        int u = b - 2304;
        int bx = u % 9, by = (u / 9) % 18, bz = u / 162;
        const float* W = bz ? Wy : Wx;
        float* WT      = bz ? WTy : WTx;
        int f0 = bx * 16, o0 = by * 16;
        int tx = tid & 15, ty = tid >> 4;
        t16[ty][tx] = W[(o0 + ty) * 144 + f0 + tx];
        __syncthreads();
        WT[(f0 + ty) * 288 + o0 + tx] = t16[tx][ty];
    } else if (b < 2790) {
        // ---- wcvtF: 4 weight matrices -> fragment-major bf16 (4 x 64 lanes)
        int t = b - 2628;                 // 162 tiles
        int sub = tid >> 6, lane = tid & 63;
        int ot = t / 9, cc = t % 9;
        const float* W = (sub == 0) ? Wq : (sub == 1) ? Wk : (sub == 2) ? Wv : Wproj;
        unsigned short* O = ((sub == 0) ? WFq : (sub == 1) ? WFk : (sub == 2) ? WFv : WFp)
                            + (size_t)t * 512;
        int o  = ot * 16 + (lane & 15);
        int c0 = cc * 32 + (lane >> 4) * 8;
        const float* src = W + (size_t)o * CDIM + c0;
        float4 f0 = *(const float4*)src, f1 = *(const float4*)(src + 4);
        unsigned int v0 = f2bf(f0.x) | ((unsigned int)f2bf(f0.y) << 16);
        unsigned int v1 = f2bf(f0.z) | ((unsigned int)f2bf(f0.w) << 16);
        unsigned int v2 = f2bf(f1.x) | ((unsigned int)f2bf(f1.y) << 16);
        unsigned int v3 = f2bf(f1.z) | ((unsigned int)f2bf(f1.w) << 16);
        uint4 pk = { v0, v1, v2, v3 };
        *(uint4*)(O + lane * 8) = pk;
    } else {
        // ---- meanx
        int bid = b - 2790;               // 576
        const float* xr = X + (size_t)bid * HW;
        float s = 0.f;
        for (int j = tid; j < HW; j += 256) s += xr[j];
        for (int off = 32; off > 0; off >>= 1) s += __shfl_xor(s, off, 64);
        if ((tid & 63) == 0) red[tid >> 6] = s;
        __syncthreads();
        if (tid == 0) MX[bid] = (red[0] + red[1] + red[2] + red[3]) * (1.f / 4096.f);
    }
}

// ---------------------------------------------------------------------------
// qkv_F: fused Q / K+V projection GEMMs (block-range split).
__global__ __launch_bounds__(256) void qkv_F(const unsigned short* __restrict__ WFq,
        const unsigned short* __restrict__ WFk, const unsigned short* __restrict__ WFv,
        const unsigned short* __restrict__ XF, unsigned short* __restrict__ Qf,
        unsigned short* __restrict__ KF, unsigned short* __restrict__ VF) {
    __shared__ __attribute__((aligned(16))) unsigned short tr[4][32][40];
    int n  = blockIdx.z;
    int m  = blockIdx.y;
    int wv = threadIdx.x >> 6, lane = threadIdx.x & 63;
    int lq = lane & 15, quad = lane >> 4;
    if (blockIdx.x < 32) {
        // ---------------- gemm_q path
        int j0 = blockIdx.x * 128;
        int jw = j0 + wv * 32;
        const unsigned short* Wb = WFq + ((size_t)(m * 2) * 9) * 512 + lane * 8;
        const unsigned short* Xb = XF + (size_t)n * HW * CDIM + ((size_t)(jw >> 4) * 9) * 512 + lane * 8;
        f32x4 acc[2][2] = {};
#pragma unroll
        for (int cc = 0; cc < 9; ++cc) {
            bf16x8 a0 = *(const bf16x8*)(Wb + (size_t)cc * 512);
            bf16x8 a1 = *(const bf16x8*)(Wb + (size_t)(9 + cc) * 512);
            bf16x8 b0 = *(const bf16x8*)(Xb + (size_t)cc * 512);
            bf16x8 b1 = *(const bf16x8*)(Xb + (size_t)(9 + cc) * 512);
            acc[0][0] = __builtin_amdgcn_mfma_f32_16x16x32_bf16(a0, b0, acc[0][0], 0, 0, 0);
            acc[0][1] = __builtin_amdgcn_mfma_f32_16x16x32_bf16(a0, b1, acc[0][1], 0, 0, 0);
            acc[1][0] = __builtin_amdgcn_mfma_f32_16x16x32_bf16(a1, b0, acc[1][0], 0, 0, 0);
            acc[1][1] = __builtin_amdgcn_mfma_f32_16x16x32_bf16(a1, b1, acc[1][1], 0, 0, 0);
        }
#pragma unroll
        for (int oi = 0; oi < 2; ++oi)
#pragma unroll
            for (int ji = 0; ji < 2; ++ji)
#pragma unroll
                for (int r = 0; r < 4; ++r)
                    tr[wv][ji * 16 + lq][oi * 16 + quad * 4 + r] = f2bf(acc[oi][ji][r]);
        int jl = lane & 31, half = lane >> 5;
        bf16x8 v0 = *(const bf16x8*)&tr[wv][jl][half * 16];
        bf16x8 v1 = *(const bf16x8*)&tr[wv][jl][half * 16 + 8];
        unsigned short* Qm = Qf + ((size_t)(n * MHEAD + m) * HW + jw + jl) * 32 + half * 16;
        *(bf16x8*)Qm = v0;
        *(bf16x8*)(Qm + 8) = v1;
    } else {
        // ---------------- gemm_kv path
        int p0 = (blockIdx.x - 32) * 128;
        int pw = p0 + wv * 32;
        const unsigned short* XFn = XF + (size_t)n * HW * CDIM;
        size_t bidx[2];
#pragma unroll
        for (int pi = 0; pi < 2; ++pi) {
            int p   = pw + pi * 16 + lq;
            int pos = ((p >> 5) << 7) + ((p & 31) << 1);
            bidx[pi] = ((size_t)(pos >> 4) * 9) * 512 + ((pos & 15) + 16 * quad) * 8;
        }
        const unsigned short* Wkb = WFk + ((size_t)(m * 2) * 9) * 512 + lane * 8;
        const unsigned short* Wvb = WFv + ((size_t)(m * 2) * 9) * 512 + lane * 8;
        f32x4 ak[2][2] = {}, av[2][2] = {};
#pragma unroll
        for (int cc = 0; cc < 9; ++cc) {
            bf16x8 a0k = *(const bf16x8*)(Wkb + (size_t)cc * 512);
            bf16x8 a1k = *(const bf16x8*)(Wkb + (size_t)(9 + cc) * 512);
            bf16x8 a0v = *(const bf16x8*)(Wvb + (size_t)cc * 512);
            bf16x8 a1v = *(const bf16x8*)(Wvb + (size_t)(9 + cc) * 512);
            bf16x8 b0  = *(const bf16x8*)(XFn + bidx[0] + (size_t)cc * 512);
            bf16x8 b1  = *(const bf16x8*)(XFn + bidx[1] + (size_t)cc * 512);
            ak[0][0] = __builtin_amdgcn_mfma_f32_16x16x32_bf16(a0k, b0, ak[0][0], 0, 0, 0);
            ak[0][1] = __builtin_amdgcn_mfma_f32_16x16x32_bf16(a0k, b1, ak[0][1], 0, 0, 0);
            ak[1][0] = __builtin_amdgcn_mfma_f32_16x16x32_bf16(a1k, b0, ak[1][0], 0, 0, 0);
            ak[1][1] = __builtin_amdgcn_mfma_f32_16x16x32_bf16(a1k, b1, ak[1][1], 0, 0, 0);
            av[0][0] = __builtin_amdgcn_mfma_f32_16x16x32_bf16(a0v, b0, av[0][0], 0, 0, 0);
            av[0][1] = __builtin_amdgcn_mfma_f32_16x16x32_bf16(a0v, b1, av[0][1], 0, 0, 0);
            av[1][0] = __builtin_amdgcn_mfma_f32_16x16x32_bf16(a1v, b0, av[1][0], 0, 0, 0);
            av[1][1] = __builtin_amdgcn_mfma_f32_16x16x32_bf16(a1v, b1, av[1][1], 0, 0, 0);
        }
        // K: tr[p_local][d]
#pragma unroll
        for (int oi = 0; oi < 2; ++oi)
#pragma unroll
            for (int pi = 0; pi < 2; ++pi)
#pragma unroll
                for (int r = 0; r < 4; ++r)
                    tr[wv][pi * 16 + lq][oi * 16 + quad * 4 + r] = f2bf(ak[oi][pi][r]);
        unsigned short* KFm = KF + (size_t)(n * MHEAD + m) * (PKV * 32);
#pragma unroll
        for (int pi = 0; pi < 2; ++pi) {
            bf16x8 v = *(const bf16x8*)&tr[wv][pi * 16 + lq][quad * 8];
            *(bf16x8*)(KFm + (size_t)((pw >> 4) + pi) * 512 + lane * 8) = v;
        }
        // V: tr[o_local][p_local]  (wave-local reuse, no barrier needed)
#pragma unroll
        for (int oi = 0; oi < 2; ++oi)
#pragma unroll
            for (int pi = 0; pi < 2; ++pi)
#pragma unroll
                for (int r = 0; r < 4; ++r)
                    tr[wv][oi * 16 + quad * 4 + r][pi * 16 + lq] = f2bf(av[oi][pi][r]);
        unsigned short* VFn = VF + (size_t)n * CDIM * PKV;
#pragma unroll
        for (int oi = 0; oi < 2; ++oi) {
            bf16x8 v = *(const bf16x8*)&tr[wv][oi * 16 + lq][quad * 8];
            *(bf16x8*)(VFn + (size_t)((m * 2 + oi) * 32 + (pw >> 5)) * 512 + lane * 8) = v;
        }
    }
}

// ---------------------------------------------------------------------------
// F[m][dif][d] = inv_sqrt2 * sum_f emb(dif-62)[f] * W[m*32+d][f]; 126 distinct diffs.
__global__ __launch_bounds__(320) void pff_kernel(const float* __restrict__ WTx,
        const float* __restrict__ WTy, float* __restrict__ FX, float* __restrict__ FY) {
    int blk  = blockIdx.x;          // 252: axis*126 + dif
    int axis = blk / 126;
    int dif  = blk % 126;
    __shared__ float emb[144];
    int tid = threadIdx.x;
    float diff = (float)(dif - 62);
    if (tid < 72) {
        float dm = expf(6.9077552789821368f * ((float)tid * (1.f / 72.f)));
        float t  = diff / dm;
        emb[tid]      = sinf(t);
        emb[72 + tid] = cosf(t);
    }
    __syncthreads();
    if (tid < 288) {
        const float* WT = axis ? WTy : WTx;
        float s = 0.f;
#pragma unroll 8
        for (int f = 0; f < 144; ++f) s += emb[f] * WT[f * 288 + tid];
        int m = tid >> 5, d = tid & 31;
        float* F = axis ? FY : FX;
        F[((size_t)m * 126 + dif) * 32 + d] = s * 0.70710678118654752f;
    }
}

// ---------------------------------------------------------------------------
// EX/EY precompute (fp32), reading Qf[j][d] + F tables.
__global__ __launch_bounds__(256) void exey_kernel(const unsigned short* __restrict__ Qf,
        const float* __restrict__ FX, const float* __restrict__ FY,
        float* __restrict__ EX, float* __restrict__ EY) {
    int axis = blockIdx.x >> 6;
    int g    = blockIdx.x & 63;
    int m    = blockIdx.y;
    int n    = blockIdx.z;
    int tid  = threadIdx.x;
    size_t Qbase = (size_t)(n * MHEAD + m) * HW;

    __shared__ float fS[32][36];
    __shared__ unsigned int qSu[64][20];

    {
        const float* F = axis ? FY : FX;
        int v = tid >> 3, d0 = (tid & 7) * 4;
        *(float4*)&fS[v][d0] = *(const float4*)&F[((size_t)m * 126 + g + 62 - 2 * v) * 32 + d0];
    }
#pragma unroll
    for (int l = 0; l < 4; ++l) {
        int idx = tid + l * 256;
        int r = idx >> 4, c = idx & 15;
        int i = axis ? (g * 64 + r) : (r * 64 + g);
        qSu[r][c] = *(const unsigned int*)&Qf[(Qbase + i) * 32 + 2 * c];
    }
    __syncthreads();

    int r  = tid >> 2;
    int vg = tid & 3;
    float qv[32];
#pragma unroll
    for (int k = 0; k < 4; ++k) {
        uint4 qa = *(const uint4*)&qSu[r][k * 4];
        unsigned int uu[4] = { qa.x, qa.y, qa.z, qa.w };
#pragma unroll
        for (int e = 0; e < 4; ++e) {
            qv[k * 8 + 2 * e]     = __uint_as_float(uu[e] << 16);
            qv[k * 8 + 2 * e + 1] = __uint_as_float(uu[e] & 0xffff0000u);
        }
    }
    float acc8[8] = {};
#pragma unroll
    for (int k4 = 0; k4 < 8; ++k4) {
        float qx = qv[4 * k4], qy = qv[4 * k4 + 1], qz = qv[4 * k4 + 2], qw = qv[4 * k4 + 3];
#pragma unroll
        for (int t = 0; t < 8; ++t) {
            float4 f4 = *(const float4*)&fS[vg * 8 + t][k4 * 4];
            acc8[t] += qx * f4.x + qy * f4.y + qz * f4.z + qw * f4.w;
        }
    }
    int i = axis ? (g * 64 + r) : (r * 64 + g);
    float* out = axis ? EY : EX;
    size_t obase = (Qbase + i) * 32 + vg * 8;
    float4 s0 = { acc8[0], acc8[1], acc8[2], acc8[3] };
    float4 s1 = { acc8[4], acc8[5], acc8[6], acc8[7] };
    *(float4*)&out[obase]     = s0;
    *(float4*)&out[obase + 4] = s1;
}

// ---------------------------------------------------------------------------
__global__ void mixw2_kernel(const float* __restrict__ Wq, const float* __restrict__ MX,
                             const float* __restrict__ Wc, const float* __restrict__ bc,
                             float* __restrict__ MIXW) {
    __shared__ float ctx_s[NB * CDIM];
    __shared__ float lg[18];
    int tid = threadIdx.x;
    for (int p = tid; p < NB * CDIM; p += 256) {
        int n = p / CDIM, o = p % CDIM;
        const float* wr = Wq + (size_t)o * CDIM;
        const float* mx = MX + n * CDIM;
        float s = 0.f;
        for (int c = 0; c < CDIM; c += 4) {
            float4 w4 = *(const float4*)&wr[c];
            float4 m4 = *(const float4*)&mx[c];
            s += w4.x * m4.x + w4.y * m4.y + w4.z * m4.z + w4.w * m4.w;
        }
        ctx_s[p] = s;
    }
    __syncthreads();
    if (tid < 18) {
        int n = tid / 9, j = tid % 9;
        float s = bc[j];
        for (int o = 0; o < CDIM; ++o) s += ctx_s[n * CDIM + o] * Wc[j * CDIM + o];
        lg[tid] = s;
    }
    __syncthreads();
    if (tid < 2) {
        float mx = -1e30f;
        for (int j = 0; j < 9; ++j) mx = fmaxf(mx, lg[tid * 9 + j]);
        float e[9], sm = 0.f;
        for (int j = 0; j < 9; ++j) { e[j] = __expf(lg[tid * 9 + j] - mx); sm += e[j]; }
        for (int j = 0; j < 9; ++j) MIXW[tid * 9 + j] = e[j] / sm;
    }
}

// ---------------------------------------------------------------------------
// attn_fused: attention (9 heads, no-max softmax, mix-weighted) + P@V^T + Wproj
// epilogue, one block per 16 queries. P kept in LDS; MID kept in LDS.
__global__ __launch_bounds__(512, 4) void attn_fused(
        const unsigned short* __restrict__ Qf, const unsigned short* __restrict__ KF,
        const unsigned short* __restrict__ VF, const unsigned short* __restrict__ WFp,
        const float* __restrict__ EX, const float* __restrict__ EY,
        const float* __restrict__ MIXW, const float* __restrict__ bproj,
        const float* __restrict__ x, const float* __restrict__ gamma,
        float* __restrict__ OUT) {
    int n    = blockIdx.x >> 8;
    int i0   = (blockIdx.x & 255) * 16;
    int tid  = threadIdx.x;
    int wv   = tid >> 6;          // 0..7
    int lane = tid & 63;
    int lq   = lane & 15;
    int quad = lane >> 4;

    __shared__ float ext_s[16][33];
    __shared__ float eyt_s[16][33];
    __shared__ float ws_s[8][16];
    __shared__ float ltot_s[16];
    __shared__ __attribute__((aligned(16))) unsigned short tr[16][1032];
    __shared__ __attribute__((aligned(16))) unsigned short Mt[16][296];

    float mixed[8][4];
#pragma unroll
    for (int t = 0; t < 8; ++t)
#pragma unroll
        for (int j = 0; j < 4; ++j) mixed[t][j] = 0.f;

    int sq = tid >> 5, sv = tid & 31;

    for (int m = 0; m < MHEAD; ++m) {
        const unsigned short* Qm  = Qf + ((size_t)(n * MHEAD + m) * HW + i0) * 32;
        const unsigned short* KmF = KF + (size_t)(n * MHEAD + m) * (PKV * 32);
        size_t ebase = ((size_t)(n * MHEAD + m) * HW + i0 + sq) * 32 + sv;
        __syncthreads();
        ext_s[sq][sv] = EX[ebase];
        eyt_s[sq][sv] = EY[ebase];
        __syncthreads();

        bf16x8 afrag = *(const bf16x8*)(Qm + (size_t)lq * 32 + quad * 8);
        float exA[4], exB[4];
#pragma unroll
        for (int j = 0; j < 4; ++j) {
            exA[j] = ext_s[quad * 4 + j][lq];
            exB[j] = ext_s[quad * 4 + j][16 + lq];
        }

        bf16x8 bf[8];
#pragma unroll
        for (int t = 0; t < 8; ++t)
            bf[t] = *(const bf16x8*)(KmF + (size_t)(wv * 8 + t) * 512 + lane * 8);
        f32x4 acc[8];
#pragma unroll
        for (int t = 0; t < 8; ++t) acc[t] = (f32x4){0.f, 0.f, 0.f, 0.f};
#pragma unroll
        for (int t = 0; t < 8; ++t)
            acc[t] = __builtin_amdgcn_mfma_f32_16x16x32_bf16(afrag, bf[t], acc[t], 0, 0, 0);

        float rs[4] = {0.f, 0.f, 0.f, 0.f};
#pragma unroll
        for (int t = 0; t < 8; ++t) {
            int u = wv * 4 + (t >> 1);
            bool hi = t & 1;
#pragma unroll
            for (int j = 0; j < 4; ++j) {
                float e = __expf(acc[t][j] + (hi ? exB[j] : exA[j]) + eyt_s[quad * 4 + j][u]);
                rs[j] += e;
                acc[t][j] = e;
            }
        }
#pragma unroll
        for (int j = 0; j < 4; ++j) {
            rs[j] += __shfl_xor(rs[j], 1, 64);
            rs[j] += __shfl_xor(rs[j], 2, 64);
            rs[j] += __shfl_xor(rs[j], 4, 64);
            rs[j] += __shfl_xor(rs[j], 8, 64);
        }
        if (lq == 0) {
#pragma unroll
            for (int j = 0; j < 4; ++j) ws_s[wv][quad * 4 + j] = rs[j];
        }
        __syncthreads();
        if (tid < 16) {
            float s = 0.f;
#pragma unroll
            for (int w = 0; w < 8; ++w) s += ws_s[w][tid];
            ltot_s[tid] = s;
        }
        __syncthreads();

        float wm = MIXW[n * MHEAD + m];
        float fct[4];
#pragma unroll
        for (int j = 0; j < 4; ++j) fct[j] = wm / ltot_s[quad * 4 + j];
#pragma unroll
        for (int t = 0; t < 8; ++t)
#pragma unroll
            for (int j = 0; j < 4; ++j) mixed[t][j] += acc[t][j] * fct[j];
    }

    // --- P (mixed attn) -> LDS in [i][p] layout (each wave owns its p-range)
#pragma unroll
    for (int t = 0; t < 8; ++t)
#pragma unroll
        for (int j = 0; j < 4; ++j)
            tr[quad * 4 + j][wv * 128 + t * 16 + lq] = f2bf(mixed[t][j]);
    __syncthreads();

    // --- PV: O(16x288) = P(16x1024) @ V^T; wave wv owns o-tiles {wv, wv+8, wv+16<18}
    const unsigned short* VFn = VF + (size_t)n * CDIM * PKV;
    f32x4 accpv[3] = {};
#pragma unroll 4
    for (int pc = 0; pc < 32; ++pc) {
        bf16x8 pf = *(const bf16x8*)&tr[lq][pc * 32 + quad * 8];
#pragma unroll
        for (int idx = 0; idx < 3; ++idx) {
            int ot = wv + idx * 8;
            if (ot < 18) {
                bf16x8 vf = *(const bf16x8*)(VFn + (size_t)(ot * 32 + pc) * 512 + lane * 8);
                accpv[idx] = __builtin_amdgcn_mfma_f32_16x16x32_bf16(pf, vf, accpv[idx], 0, 0, 0);
            }
        }
    }
#pragma unroll
    for (int idx = 0; idx < 3; ++idx) {
        int ot = wv + idx * 8;
        if (ot < 18) {
#pragma unroll
            for (int r = 0; r < 4; ++r)
                Mt[quad * 4 + r][ot * 16 + lq] = f2bf(accpv[idx][r]);
        }
    }
    __syncthreads();

    // --- proj: OUT(288x16) = Wproj(288x288) @ MID(288x16) + bias, gamma, residual
    float g = gamma[0];
#pragma unroll
    for (int idx = 0; idx < 3; ++idx) {
        int ot = wv + idx * 8;
        if (ot >= 18) continue;
        f32x4 acc = {};
#pragma unroll
        for (int cc = 0; cc < 9; ++cc) {
            bf16x8 af = *(const bf16x8*)(WFp + (size_t)(ot * 9 + cc) * 512 + lane * 8);
            bf16x8 bfm = *(const bf16x8*)&Mt[lq][cc * 32 + quad * 8];
            acc = __builtin_amdgcn_mfma_f32_16x16x32_bf16(af, bfm, acc, 0, 0, 0);
        }
#pragma unroll
        for (int r = 0; r < 4; ++r) {
            int o = ot * 16 + quad * 4 + r;
            size_t id = ((size_t)(n * CDIM) + o) * HW + i0 + lq;
            OUT[id] = g * (acc[r] + bproj[o]) + x[id];
        }
    }
}

// ---------------------------------------------------------------------------
extern "C" void kernel_launch(void* const* d_in, const int* in_sizes, int n_in,
                              void* d_out, int out_size, void* d_ws, size_t ws_size,
                              hipStream_t stream) {
    const float* x     = (const float*)d_in[0];
    const float* Wq    = (const float*)d_in[1];
    const float* Wk    = (const float*)d_in[2];
    const float* Wv    = (const float*)d_in[3];
    const float* Wx    = (const float*)d_in[4];
    const float* Wy    = (const float*)d_in[5];
    const float* Wproj = (const float*)d_in[6];
    const float* bproj = (const float*)d_in[7];
    const float* Wc    = (const float*)d_in[8];
    const float* bc    = (const float*)d_in[9];
    const float* gamma = (const float*)d_in[10];
    float* out = (float*)d_out;

    float* ws = (float*)d_ws;
    size_t off = 0;
    unsigned short* Qf  = (unsigned short*)(ws + off); off += (size_t)NB * MHEAD * HW * 32 / 2;
    unsigned short* KF  = (unsigned short*)(ws + off); off += (size_t)NB * MHEAD * PKV * 32 / 2;
    unsigned short* VF  = (unsigned short*)(ws + off); off += (size_t)NB * CDIM * PKV / 2;
    unsigned short* WFq = (unsigned short*)(ws + off); off += (size_t)CDIM * CDIM / 2;
    unsigned short* WFk = (unsigned short*)(ws + off); off += (size_t)CDIM * CDIM / 2;
    unsigned short* WFv = (unsigned short*)(ws + off); off += (size_t)CDIM * CDIM / 2;
    unsigned short* WFp = (unsigned short*)(ws + off); off += (size_t)CDIM * CDIM / 2;
    unsigned short* XF  = (unsigned short*)(ws + off); off += (size_t)NB * HW * CDIM / 2;
    float* WTx  = ws + off; off += 144 * 288;
    float* WTy  = ws + off; off += 144 * 288;
    float* FX   = ws + off; off += (size_t)MHEAD * 126 * 32;
    float* FY   = ws + off; off += (size_t)MHEAD * 126 * 32;
    float* EX   = ws + off; off += (size_t)NB * MHEAD * HW * 32;
    float* EY   = ws + off; off += (size_t)NB * MHEAD * HW * 32;
    float* MX   = ws + off; off += NB * CDIM;
    float* MIXW = ws + off; off += 32;

    prep<<<3366, 256, 0, stream>>>(x, Wq, Wk, Wv, Wproj, Wx, Wy,
                                   XF, WFq, WFk, WFv, WFp, WTx, WTy, MX);
    pff_kernel<<<252, 320, 0, stream>>>(WTx, WTy, FX, FY);
    mixw2_kernel<<<1, 256, 0, stream>>>(Wq, MX, Wc, bc, MIXW);
    qkv_F<<<dim3(40, MHEAD, NB), 256, 0, stream>>>(WFq, WFk, WFv, XF, Qf, KF, VF);
    exey_kernel<<<dim3(128, MHEAD, NB), 256, 0, stream>>>(Qf, FX, FY, EX, EY);
    attn_fused<<<NB * HW / 16, 512, 0, stream>>>(Qf, KF, VF, WFp, EX, EY, MIXW,
                                                 bproj, x, gamma, out);
}

// Round 9
// 178.564 us; speedup vs baseline: 6.6966x; 1.1488x over previous
//
#include <hip/hip_runtime.h>
#include <math.h>

// n=2, C=288, h=w=64 -> hw=4096; kv stride 2 -> 32x32 -> pkv=1024; M=9 heads, d=32
#define NB     2
#define CDIM   288
#define HW     4096
#define PKV    1024
#define MHEAD  9
#define DHEAD  32

typedef __attribute__((ext_vector_type(8))) short bf16x8;
typedef __attribute__((ext_vector_type(4))) float f32x4;

__device__ inline unsigned short f2bf(float x) {
    unsigned int u = __float_as_uint(x);
    u = (u + 0x7fffu + ((u >> 16) & 1u)) >> 16;
    return (unsigned short)u;
}

// ---------------------------------------------------------------------------
// Fragment-major tile (16 rows r, 32 k): elem(r,k) = ((r&15)+16*(k>>3))*8 + (k&7)
//  WF (A-side, rows=o, k=c): tiles (ot,cc) -> (ot*9+cc)*512
//  XF (B-side, rows=j, k=c): per n, (jt,cc) -> (jt*9+cc)*512
//  KF (B-side, rows=p, k=d): per (n,m), pt -> pt*512
//  VF (B-side, rows=o, k=p): per n, (ot,pc) -> (ot*32+pc)*512
//  FXb/FYb (B-side, rows=dif[128 padded], k=d): per m, tile t -> (m*8+t)*512

// ---------------------------------------------------------------------------
// prep: fused xtransF + wtrans + wcvtF + meanx (all depend only on inputs)
__global__ __launch_bounds__(256) void prep(const float* __restrict__ X,
        const float* __restrict__ Wq, const float* __restrict__ Wk,
        const float* __restrict__ Wv, const float* __restrict__ Wproj,
        const float* __restrict__ Wx, const float* __restrict__ Wy,
        unsigned short* __restrict__ XF, unsigned short* __restrict__ WFq,
        unsigned short* __restrict__ WFk, unsigned short* __restrict__ WFv,
        unsigned short* __restrict__ WFp, float* __restrict__ WTx,
        float* __restrict__ WTy, float* __restrict__ MX) {
    __shared__ float t32[32][33];
    __shared__ float t16[16][17];
    __shared__ float red[4];
    int b = blockIdx.x;
    int tid = threadIdx.x;
    if (b < 2304) {
        // ---- xtransF: x[n][c][j] -> XF fragment-major bf16
        int bx = b % 128, by = (b / 128) % 9, n = b / 1152;
        int j0 = bx * 32, c0 = by * 32;
        int tx = tid & 31, ty = tid >> 5;
#pragma unroll
        for (int l = 0; l < 4; ++l) {
            int c = ty + l * 8;
            t32[c][tx] = X[((size_t)n * CDIM + c0 + c) * HW + j0 + tx];
        }
        __syncthreads();
        int s = tid >> 7;
        int u = tid & 127;
        int lane = u >> 1, e0 = (u & 1) * 4;
        int jl = s * 16 + (lane & 15);
        int cb = (lane >> 4) * 8 + e0;
        unsigned int w0 = f2bf(t32[cb + 0][jl]) | ((unsigned int)f2bf(t32[cb + 1][jl]) << 16);
        unsigned int w1 = f2bf(t32[cb + 2][jl]) | ((unsigned int)f2bf(t32[cb + 3][jl]) << 16);
        int jt = (j0 >> 4) + s, cc = c0 >> 5;
        unsigned short* O = XF + (size_t)n * HW * CDIM + ((size_t)jt * 9 + cc) * 512 + lane * 8 + e0;
        uint2 pk = { w0, w1 };
        *(uint2*)O = pk;
    } else if (b < 2628) {
        // ---- wtrans: Wx/Wy (288x144) -> WT (144x288)
        int u = b - 2304;
        int bx = u % 9, by = (u / 9) % 18, bz = u / 162;
        const float* W = bz ? Wy : Wx;
        float* WT      = bz ? WTy : WTx;
        int f0 = bx * 16, o0 = by * 16;
        int tx = tid & 15, ty = tid >> 4;
        t16[ty][tx] = W[(o0 + ty) * 144 + f0 + tx];
        __syncthreads();
        WT[(f0 + ty) * 288 + o0 + tx] = t16[tx][ty];
    } else if (b < 2790) {
        // ---- wcvtF: 4 weight matrices -> fragment-major bf16 (4 x 64 lanes)
        int t = b - 2628;                 // 162 tiles
        int sub = tid >> 6, lane = tid & 63;
        int ot = t / 9, cc = t % 9;
        const float* W = (sub == 0) ? Wq : (sub == 1) ? Wk : (sub == 2) ? Wv : Wproj;
        unsigned short* O = ((sub == 0) ? WFq : (sub == 1) ? WFk : (sub == 2) ? WFv : WFp)
                            + (size_t)t * 512;
        int o  = ot * 16 + (lane & 15);
        int c0 = cc * 32 + (lane >> 4) * 8;
        const float* src = W + (size_t)o * CDIM + c0;
        float4 f0 = *(const float4*)src, f1 = *(const float4*)(src + 4);
        unsigned int v0 = f2bf(f0.x) | ((unsigned int)f2bf(f0.y) << 16);
        unsigned int v1 = f2bf(f0.z) | ((unsigned int)f2bf(f0.w) << 16);
        unsigned int v2 = f2bf(f1.x) | ((unsigned int)f2bf(f1.y) << 16);
        unsigned int v3 = f2bf(f1.z) | ((unsigned int)f2bf(f1.w) << 16);
        uint4 pk = { v0, v1, v2, v3 };
        *(uint4*)(O + lane * 8) = pk;
    } else {
        // ---- meanx
        int bid = b - 2790;               // 576
        const float* xr = X + (size_t)bid * HW;
        float s = 0.f;
        for (int j = tid; j < HW; j += 256) s += xr[j];
        for (int off = 32; off > 0; off >>= 1) s += __shfl_xor(s, off, 64);
        if ((tid & 63) == 0) red[tid >> 6] = s;
        __syncthreads();
        if (tid == 0) MX[bid] = (red[0] + red[1] + red[2] + red[3]) * (1.f / 4096.f);
    }
}

// ---------------------------------------------------------------------------
// mid: fused pff (bf16 fragment-major F tables) + mixw2 (+pad-zeroing) + qkv.
__global__ __launch_bounds__(256) void mid(
        const float* __restrict__ WTx, const float* __restrict__ WTy,
        unsigned short* __restrict__ FXb, unsigned short* __restrict__ FYb,
        const float* __restrict__ Wq, const float* __restrict__ MX,
        const float* __restrict__ Wc, const float* __restrict__ bc,
        float* __restrict__ MIXW,
        const unsigned short* __restrict__ WFq, const unsigned short* __restrict__ WFk,
        const unsigned short* __restrict__ WFv, const unsigned short* __restrict__ XF,
        unsigned short* __restrict__ Qf, unsigned short* __restrict__ KF,
        unsigned short* __restrict__ VF) {
    __shared__ float emb[144];
    __shared__ float ctx_s[NB * CDIM];
    __shared__ float lg[18];
    __shared__ __attribute__((aligned(16))) unsigned short tr[4][32][40];
    int b = blockIdx.x;
    int tid = threadIdx.x;

    if (b < 252) {
        // ---- pff: F[m][dif][d] = inv_sqrt2 * emb(dif-62) . W[m*32+d][:], bf16 frag-major
        int axis = b / 126;
        int dif  = b % 126;
        float diff = (float)(dif - 62);
        if (tid < 72) {
            float dm = expf(6.9077552789821368f * ((float)tid * (1.f / 72.f)));
            float t  = diff / dm;
            emb[tid]      = sinf(t);
            emb[72 + tid] = cosf(t);
        }
        __syncthreads();
        const float* WT = axis ? WTy : WTx;
        unsigned short* F = axis ? FYb : FXb;
        for (int o = tid; o < CDIM; o += 256) {
            float s = 0.f;
#pragma unroll 8
            for (int f = 0; f < 144; ++f) s += emb[f] * WT[f * 288 + o];
            int m = o >> 5, d = o & 31;
            F[(size_t)(m * 8 + (dif >> 4)) * 512 + ((dif & 15) + 16 * (d >> 3)) * 8 + (d & 7)]
                = f2bf(s * 0.70710678118654752f);
        }
    } else if (b == 252) {
        // ---- zero the padded rows 126/127 of both F tables
        for (int idx = tid; idx < 1152; idx += 256) {
            int d = idx & 31, rr = (idx >> 5) & 1, mm = (idx >> 6) % 9, ax = idx / 576;
            int dif = 126 + rr;
            unsigned short* F = ax ? FYb : FXb;
            F[(size_t)(mm * 8 + 7) * 512 + ((dif & 15) + 16 * (d >> 3)) * 8 + (d & 7)] = 0;
        }
        // ---- mixw2
        for (int p = tid; p < NB * CDIM; p += 256) {
            int n = p / CDIM, o = p % CDIM;
            const float* wr = Wq + (size_t)o * CDIM;
            const float* mx = MX + n * CDIM;
            float s = 0.f;
            for (int c = 0; c < CDIM; c += 4) {
                float4 w4 = *(const float4*)&wr[c];
                float4 m4 = *(const float4*)&mx[c];
                s += w4.x * m4.x + w4.y * m4.y + w4.z * m4.z + w4.w * m4.w;
            }
            ctx_s[p] = s;
        }
        __syncthreads();
        if (tid < 18) {
            int n = tid / 9, j = tid % 9;
            float s = bc[j];
            for (int o = 0; o < CDIM; ++o) s += ctx_s[n * CDIM + o] * Wc[j * CDIM + o];
            lg[tid] = s;
        }
        __syncthreads();
        if (tid < 2) {
            float mx = -1e30f;
            for (int j = 0; j < 9; ++j) mx = fmaxf(mx, lg[tid * 9 + j]);
            float e[9], sm = 0.f;
            for (int j = 0; j < 9; ++j) { e[j] = __expf(lg[tid * 9 + j] - mx); sm += e[j]; }
            for (int j = 0; j < 9; ++j) MIXW[tid * 9 + j] = e[j] / sm;
        }
    } else {
        // ---- qkv_F
        int bx = b - 253;
        int gx = bx % 40;
        int m  = (bx / 40) % 9;
        int n  = bx / 360;
        int wv = tid >> 6, lane = tid & 63;
        int lq = lane & 15, quad = lane >> 4;
        if (gx < 32) {
            // gemm_q path
            int j0 = gx * 128;
            int jw = j0 + wv * 32;
            const unsigned short* Wb = WFq + ((size_t)(m * 2) * 9) * 512 + lane * 8;
            const unsigned short* Xb = XF + (size_t)n * HW * CDIM + ((size_t)(jw >> 4) * 9) * 512 + lane * 8;
            f32x4 acc[2][2] = {};
#pragma unroll
            for (int cc = 0; cc < 9; ++cc) {
                bf16x8 a0 = *(const bf16x8*)(Wb + (size_t)cc * 512);
                bf16x8 a1 = *(const bf16x8*)(Wb + (size_t)(9 + cc) * 512);
                bf16x8 b0 = *(const bf16x8*)(Xb + (size_t)cc * 512);
                bf16x8 b1 = *(const bf16x8*)(Xb + (size_t)(9 + cc) * 512);
                acc[0][0] = __builtin_amdgcn_mfma_f32_16x16x32_bf16(a0, b0, acc[0][0], 0, 0, 0);
                acc[0][1] = __builtin_amdgcn_mfma_f32_16x16x32_bf16(a0, b1, acc[0][1], 0, 0, 0);
                acc[1][0] = __builtin_amdgcn_mfma_f32_16x16x32_bf16(a1, b0, acc[1][0], 0, 0, 0);
                acc[1][1] = __builtin_amdgcn_mfma_f32_16x16x32_bf16(a1, b1, acc[1][1], 0, 0, 0);
            }
#pragma unroll
            for (int oi = 0; oi < 2; ++oi)
#pragma unroll
                for (int ji = 0; ji < 2; ++ji)
#pragma unroll
                    for (int r = 0; r < 4; ++r)
                        tr[wv][ji * 16 + lq][oi * 16 + quad * 4 + r] = f2bf(acc[oi][ji][r]);
            int jl = lane & 31, half = lane >> 5;
            bf16x8 v0 = *(const bf16x8*)&tr[wv][jl][half * 16];
            bf16x8 v1 = *(const bf16x8*)&tr[wv][jl][half * 16 + 8];
            unsigned short* Qm = Qf + ((size_t)(n * MHEAD + m) * HW + jw + jl) * 32 + half * 16;
            *(bf16x8*)Qm = v0;
            *(bf16x8*)(Qm + 8) = v1;
        } else {
            // gemm_kv path
            int p0 = (gx - 32) * 128;
            int pw = p0 + wv * 32;
            const unsigned short* XFn = XF + (size_t)n * HW * CDIM;
            size_t bidx[2];
#pragma unroll
            for (int pi = 0; pi < 2; ++pi) {
                int p   = pw + pi * 16 + lq;
                int pos = ((p >> 5) << 7) + ((p & 31) << 1);
                bidx[pi] = ((size_t)(pos >> 4) * 9) * 512 + ((pos & 15) + 16 * quad) * 8;
            }
            const unsigned short* Wkb = WFk + ((size_t)(m * 2) * 9) * 512 + lane * 8;
            const unsigned short* Wvb = WFv + ((size_t)(m * 2) * 9) * 512 + lane * 8;
            f32x4 ak[2][2] = {}, av[2][2] = {};
#pragma unroll
            for (int cc = 0; cc < 9; ++cc) {
                bf16x8 a0k = *(const bf16x8*)(Wkb + (size_t)cc * 512);
                bf16x8 a1k = *(const bf16x8*)(Wkb + (size_t)(9 + cc) * 512);
                bf16x8 a0v = *(const bf16x8*)(Wvb + (size_t)cc * 512);
                bf16x8 a1v = *(const bf16x8*)(Wvb + (size_t)(9 + cc) * 512);
                bf16x8 b0  = *(const bf16x8*)(XFn + bidx[0] + (size_t)cc * 512);
                bf16x8 b1  = *(const bf16x8*)(XFn + bidx[1] + (size_t)cc * 512);
                ak[0][0] = __builtin_amdgcn_mfma_f32_16x16x32_bf16(a0k, b0, ak[0][0], 0, 0, 0);
                ak[0][1] = __builtin_amdgcn_mfma_f32_16x16x32_bf16(a0k, b1, ak[0][1], 0, 0, 0);
                ak[1][0] = __builtin_amdgcn_mfma_f32_16x16x32_bf16(a1k, b0, ak[1][0], 0, 0, 0);
                ak[1][1] = __builtin_amdgcn_mfma_f32_16x16x32_bf16(a1k, b1, ak[1][1], 0, 0, 0);
                av[0][0] = __builtin_amdgcn_mfma_f32_16x16x32_bf16(a0v, b0, av[0][0], 0, 0, 0);
                av[0][1] = __builtin_amdgcn_mfma_f32_16x16x32_bf16(a0v, b1, av[0][1], 0, 0, 0);
                av[1][0] = __builtin_amdgcn_mfma_f32_16x16x32_bf16(a1v, b0, av[1][0], 0, 0, 0);
                av[1][1] = __builtin_amdgcn_mfma_f32_16x16x32_bf16(a1v, b1, av[1][1], 0, 0, 0);
            }
            // K: tr[p_local][d]
#pragma unroll
            for (int oi = 0; oi < 2; ++oi)
#pragma unroll
                for (int pi = 0; pi < 2; ++pi)
#pragma unroll
                    for (int r = 0; r < 4; ++r)
                        tr[wv][pi * 16 + lq][oi * 16 + quad * 4 + r] = f2bf(ak[oi][pi][r]);
            unsigned short* KFm = KF + (size_t)(n * MHEAD + m) * (PKV * 32);
#pragma unroll
            for (int pi = 0; pi < 2; ++pi) {
                bf16x8 v = *(const bf16x8*)&tr[wv][pi * 16 + lq][quad * 8];
                *(bf16x8*)(KFm + (size_t)((pw >> 4) + pi) * 512 + lane * 8) = v;
            }
            // V: tr[o_local][p_local]
#pragma unroll
            for (int oi = 0; oi < 2; ++oi)
#pragma unroll
                for (int pi = 0; pi < 2; ++pi)
#pragma unroll
                    for (int r = 0; r < 4; ++r)
                        tr[wv][oi * 16 + quad * 4 + r][pi * 16 + lq] = f2bf(av[oi][pi][r]);
            unsigned short* VFn = VF + (size_t)n * CDIM * PKV;
#pragma unroll
            for (int oi = 0; oi < 2; ++oi) {
                bf16x8 v = *(const bf16x8*)&tr[wv][oi * 16 + lq][quad * 8];
                *(bf16x8*)(VFn + (size_t)((m * 2 + oi) * 32 + (pw >> 5)) * 512 + lane * 8) = v;
            }
        }
    }
}

// ---------------------------------------------------------------------------
// attn_fused2: per-head R = Q@Ftab^T via MFMA (replaces EX/EY), no-max softmax,
// mix-weighted P, then P@V^T and Wproj epilogue. 2 barriers/head.
__global__ __launch_bounds__(512, 4) void attn_fused2(
        const unsigned short* __restrict__ Qf, const unsigned short* __restrict__ KF,
        const unsigned short* __restrict__ VF, const unsigned short* __restrict__ WFp,
        const unsigned short* __restrict__ FXb, const unsigned short* __restrict__ FYb,
        const float* __restrict__ MIXW, const float* __restrict__ bproj,
        const float* __restrict__ x, const float* __restrict__ gamma,
        float* __restrict__ OUT) {
    int n    = blockIdx.x >> 8;
    int i0   = (blockIdx.x & 255) * 16;
    int tid  = threadIdx.x;
    int wv   = tid >> 6;          // 0..7
    int lane = tid & 63;
    int lq   = lane & 15;
    int quad = lane >> 4;

    int bx_t = (i0 & 63) >> 4;    // w0>>4  (w0 = i0&63, multiple of 16)
    int h    = i0 >> 6;
    int by_t = h >> 4;
    int dh   = h & 15;

    __shared__ float Rx_s[16][82];
    __shared__ float Ry_s[16][82];
    __shared__ float ws_s[8][16];
    __shared__ __attribute__((aligned(16))) unsigned short tr[16][1032];
    __shared__ __attribute__((aligned(16))) unsigned short Mt[16][296];

    float mixed[8][4];
#pragma unroll
    for (int t = 0; t < 8; ++t)
#pragma unroll
        for (int j = 0; j < 4; ++j) mixed[t][j] = 0.f;

    for (int m = 0; m < MHEAD; ++m) {
        const unsigned short* Qm  = Qf + ((size_t)(n * MHEAD + m) * HW + i0) * 32;
        const unsigned short* KmF = KF + (size_t)(n * MHEAD + m) * (PKV * 32);
        bf16x8 afrag = *(const bf16x8*)(Qm + (size_t)lq * 32 + quad * 8);

        // ---- R phase: Rx[q][r]=Q.FX[w0+r], Ry[q][r]=Q.FY[hb+r]; 10 tiles / 8 waves
        if (wv < 5) {
            bf16x8 bR = *(const bf16x8*)(FXb + (size_t)(m * 8 + bx_t + wv) * 512 + lane * 8);
            f32x4 r = (f32x4){0.f, 0.f, 0.f, 0.f};
            r = __builtin_amdgcn_mfma_f32_16x16x32_bf16(afrag, bR, r, 0, 0, 0);
#pragma unroll
            for (int reg = 0; reg < 4; ++reg)
                Rx_s[quad * 4 + reg][wv * 16 + lq] = r[reg];
        } else {
            bf16x8 bR = *(const bf16x8*)(FYb + (size_t)(m * 8 + by_t + (wv - 5)) * 512 + lane * 8);
            f32x4 r = (f32x4){0.f, 0.f, 0.f, 0.f};
            r = __builtin_amdgcn_mfma_f32_16x16x32_bf16(afrag, bR, r, 0, 0, 0);
#pragma unroll
            for (int reg = 0; reg < 4; ++reg)
                Ry_s[quad * 4 + reg][(wv - 5) * 16 + lq] = r[reg];
        }
        if (wv < 2) {
            bf16x8 bR = *(const bf16x8*)(FYb + (size_t)(m * 8 + by_t + 3 + wv) * 512 + lane * 8);
            f32x4 r = (f32x4){0.f, 0.f, 0.f, 0.f};
            r = __builtin_amdgcn_mfma_f32_16x16x32_bf16(afrag, bR, r, 0, 0, 0);
#pragma unroll
            for (int reg = 0; reg < 4; ++reg)
                Ry_s[quad * 4 + reg][(3 + wv) * 16 + lq] = r[reg];
        }
        __syncthreads();   // B1: R tables ready

        // ---- QK^T: this wave's 128 kv
        bf16x8 bf[8];
#pragma unroll
        for (int t = 0; t < 8; ++t)
            bf[t] = *(const bf16x8*)(KmF + (size_t)(wv * 8 + t) * 512 + lane * 8);
        f32x4 acc[8];
#pragma unroll
        for (int t = 0; t < 8; ++t) acc[t] = (f32x4){0.f, 0.f, 0.f, 0.f};
#pragma unroll
        for (int t = 0; t < 8; ++t)
            acc[t] = __builtin_amdgcn_mfma_f32_16x16x32_bf16(afrag, bf[t], acc[t], 0, 0, 0);

        float exA[4], exB[4];
#pragma unroll
        for (int j = 0; j < 4; ++j) {
            int q = quad * 4 + j;
            exA[j] = Rx_s[q][q + 62 - 2 * lq];        // v = lq
            exB[j] = Rx_s[q][q + 30 - 2 * lq];        // v = lq + 16
        }

        float rs[4] = {0.f, 0.f, 0.f, 0.f};
#pragma unroll
        for (int tp = 0; tp < 4; ++tp) {
            int u = wv * 4 + tp;
            float ey[4];
#pragma unroll
            for (int j = 0; j < 4; ++j) ey[j] = Ry_s[quad * 4 + j][dh + 62 - 2 * u];
#pragma unroll
            for (int half = 0; half < 2; ++half) {
                int t = tp * 2 + half;
#pragma unroll
                for (int j = 0; j < 4; ++j) {
                    float e = __expf(acc[t][j] + (half ? exB[j] : exA[j]) + ey[j]);
                    rs[j] += e;
                    acc[t][j] = e;
                }
            }
        }
#pragma unroll
        for (int j = 0; j < 4; ++j) {
            rs[j] += __shfl_xor(rs[j], 1, 64);
            rs[j] += __shfl_xor(rs[j], 2, 64);
            rs[j] += __shfl_xor(rs[j], 4, 64);
            rs[j] += __shfl_xor(rs[j], 8, 64);
        }
        if (lq == 0) {
#pragma unroll
            for (int j = 0; j < 4; ++j) ws_s[wv][quad * 4 + j] = rs[j];
        }
        __syncthreads();   // B2: ws ready; also fences all R reads of this head

        float wm = MIXW[n * MHEAD + m];
#pragma unroll
        for (int j = 0; j < 4; ++j) {
            int q = quad * 4 + j;
            float lt = 0.f;
#pragma unroll
            for (int w = 0; w < 8; ++w) lt += ws_s[w][q];
            float fct = wm / lt;
#pragma unroll
            for (int t = 0; t < 8; ++t) mixed[t][j] += acc[t][j] * fct;
        }
    }

    // --- P (mixed attn) -> LDS [i][p]
#pragma unroll
    for (int t = 0; t < 8; ++t)
#pragma unroll
        for (int j = 0; j < 4; ++j)
            tr[quad * 4 + j][wv * 128 + t * 16 + lq] = f2bf(mixed[t][j]);
    __syncthreads();

    // --- PV: O(16x288) = P(16x1024) @ V^T; wave wv owns o-tiles {wv, wv+8, wv+16<18}
    const unsigned short* VFn = VF + (size_t)n * CDIM * PKV;
    f32x4 accpv[3];
#pragma unroll
    for (int idx = 0; idx < 3; ++idx) accpv[idx] = (f32x4){0.f, 0.f, 0.f, 0.f};
#pragma unroll 4
    for (int pc = 0; pc < 32; ++pc) {
        bf16x8 pf = *(const bf16x8*)&tr[lq][pc * 32 + quad * 8];
#pragma unroll
        for (int idx = 0; idx < 3; ++idx) {
            int ot = wv + idx * 8;
            if (ot < 18) {
                bf16x8 vf = *(const bf16x8*)(VFn + (size_t)(ot * 32 + pc) * 512 + lane * 8);
                accpv[idx] = __builtin_amdgcn_mfma_f32_16x16x32_bf16(pf, vf, accpv[idx], 0, 0, 0);
            }
        }
    }
#pragma unroll
    for (int idx = 0; idx < 3; ++idx) {
        int ot = wv + idx * 8;
        if (ot < 18) {
#pragma unroll
            for (int r = 0; r < 4; ++r)
                Mt[quad * 4 + r][ot * 16 + lq] = f2bf(accpv[idx][r]);
        }
    }
    __syncthreads();

    // --- proj: OUT(288x16) = Wproj @ MID + bias, gamma, residual
    float g = gamma[0];
#pragma unroll
    for (int idx = 0; idx < 3; ++idx) {
        int ot = wv + idx * 8;
        if (ot >= 18) continue;
        f32x4 acc = (f32x4){0.f, 0.f, 0.f, 0.f};
#pragma unroll
        for (int cc = 0; cc < 9; ++cc) {
            bf16x8 af = *(const bf16x8*)(WFp + (size_t)(ot * 9 + cc) * 512 + lane * 8);
            bf16x8 bfm = *(const bf16x8*)&Mt[lq][cc * 32 + quad * 8];
            acc = __builtin_amdgcn_mfma_f32_16x16x32_bf16(af, bfm, acc, 0, 0, 0);
        }
#pragma unroll
        for (int r = 0; r < 4; ++r) {
            int o = ot * 16 + quad * 4 + r;
            size_t id = ((size_t)(n * CDIM) + o) * HW + i0 + lq;
            OUT[id] = g * (acc[r] + bproj[o]) + x[id];
        }
    }
}

// ---------------------------------------------------------------------------
extern "C" void kernel_launch(void* const* d_in, const int* in_sizes, int n_in,
                              void* d_out, int out_size, void* d_ws, size_t ws_size,
                              hipStream_t stream) {
    const float* x     = (const float*)d_in[0];
    const float* Wq    = (const float*)d_in[1];
    const float* Wk    = (const float*)d_in[2];
    const float* Wv    = (const float*)d_in[3];
    const float* Wx    = (const float*)d_in[4];
    const float* Wy    = (const float*)d_in[5];
    const float* Wproj = (const float*)d_in[6];
    const float* bproj = (const float*)d_in[7];
    const float* Wc    = (const float*)d_in[8];
    const float* bc    = (const float*)d_in[9];
    const float* gamma = (const float*)d_in[10];
    float* out = (float*)d_out;

    float* ws = (float*)d_ws;
    size_t off = 0;
    unsigned short* Qf  = (unsigned short*)(ws + off); off += (size_t)NB * MHEAD * HW * 32 / 2;
    unsigned short* KF  = (unsigned short*)(ws + off); off += (size_t)NB * MHEAD * PKV * 32 / 2;
    unsigned short* VF  = (unsigned short*)(ws + off); off += (size_t)NB * CDIM * PKV / 2;
    unsigned short* WFq = (unsigned short*)(ws + off); off += (size_t)CDIM * CDIM / 2;
    unsigned short* WFk = (unsigned short*)(ws + off); off += (size_t)CDIM * CDIM / 2;
    unsigned short* WFv = (unsigned short*)(ws + off); off += (size_t)CDIM * CDIM / 2;
    unsigned short* WFp = (unsigned short*)(ws + off); off += (size_t)CDIM * CDIM / 2;
    unsigned short* XF  = (unsigned short*)(ws + off); off += (size_t)NB * HW * CDIM / 2;
    float* WTx  = ws + off; off += 144 * 288;
    float* WTy  = ws + off; off += 144 * 288;
    unsigned short* FXb = (unsigned short*)(ws + off); off += (size_t)MHEAD * 8 * 512 / 2;
    unsigned short* FYb = (unsigned short*)(ws + off); off += (size_t)MHEAD * 8 * 512 / 2;
    float* MX   = ws + off; off += NB * CDIM;
    float* MIXW = ws + off; off += 32;

    prep<<<3366, 256, 0, stream>>>(x, Wq, Wk, Wv, Wproj, Wx, Wy,
                                   XF, WFq, WFk, WFv, WFp, WTx, WTy, MX);
    mid<<<973, 256, 0, stream>>>(WTx, WTy, FXb, FYb, Wq, MX, Wc, bc, MIXW,
                                 WFq, WFk, WFv, XF, Qf, KF, VF);
    attn_fused2<<<NB * HW / 16, 512, 0, stream>>>(Qf, KF, VF, WFp, FXb, FYb, MIXW,
                                                  bproj, x, gamma, out);
}